// Round 1
// baseline (1212.915 us; speedup 1.0000x reference)
//
#include <hip/hip_runtime.h>

constexpr int N_NODES = 100000;
constexpr int F_IN    = 32;
constexpr int H       = 128;
constexpr int OUT_F   = 200;
constexpr int NEDGES  = 1600000;
constexpr float EPS   = 1e-5f;

__device__ __forceinline__ float wave_red(float v) {
#pragma unroll
  for (int m = 32; m > 0; m >>= 1) v += __shfl_xor(v, m, 64);
  return v;
}

__device__ __forceinline__ void fma4(float4& a, float s, const float4& w) {
  a.x = fmaf(s, w.x, a.x); a.y = fmaf(s, w.y, a.y);
  a.z = fmaf(s, w.z, a.z); a.w = fmaf(s, w.w, a.w);
}

// ---------------- CSR build ----------------
__global__ void k_hist(const int* __restrict__ ei, int* __restrict__ deg) {
  int e = blockIdx.x * blockDim.x + threadIdx.x;
  if (e < NEDGES) atomicAdd(&deg[ei[NEDGES + e]], 1);
}

__global__ void k_dinv(const int* __restrict__ deg, float* __restrict__ dinv) {
  int n = blockIdx.x * blockDim.x + threadIdx.x;
  if (n < N_NODES) dinv[n] = rsqrtf((float)(deg[n] + 1));  // +1 self-loop
}

__global__ void k_scan_a(const int* __restrict__ deg, int* __restrict__ offs,
                         int* __restrict__ parts) {
  __shared__ int s[256];
  int i = blockIdx.x * 256 + threadIdx.x;
  int d = (i < N_NODES) ? deg[i] : 0;
  s[threadIdx.x] = d;
  __syncthreads();
#pragma unroll
  for (int off = 1; off < 256; off <<= 1) {
    int v = (threadIdx.x >= off) ? s[threadIdx.x - off] : 0;
    __syncthreads();
    s[threadIdx.x] += v;
    __syncthreads();
  }
  if (i < N_NODES) offs[i] = s[threadIdx.x] - d;  // exclusive (block-local)
  if (threadIdx.x == 255) parts[blockIdx.x] = s[255];
}

__global__ void k_scan_b(int* __restrict__ parts, int nparts) {
  __shared__ int s[512];
  int t = threadIdx.x;
  int d = (t < nparts) ? parts[t] : 0;
  s[t] = d;
  __syncthreads();
#pragma unroll
  for (int off = 1; off < 512; off <<= 1) {
    int v = (t >= off) ? s[t - off] : 0;
    __syncthreads();
    s[t] += v;
    __syncthreads();
  }
  if (t < nparts) parts[t] = s[t] - d;  // exclusive across blocks
}

__global__ void k_scan_c(int* __restrict__ offs, const int* __restrict__ parts,
                         int* __restrict__ work) {
  int i = blockIdx.x * 256 + threadIdx.x;
  if (i < N_NODES) {
    int o = offs[i] + parts[blockIdx.x];
    offs[i] = o;
    work[i] = o;
  }
}

__global__ void k_fill(const int* __restrict__ ei, const float* __restrict__ dinv,
                       int* __restrict__ work, int* __restrict__ csr_src,
                       float* __restrict__ csr_norm) {
  int e = blockIdx.x * blockDim.x + threadIdx.x;
  if (e < NEDGES) {
    int src = ei[e], dst = ei[NEDGES + e];
    int pos = atomicAdd(&work[dst], 1);
    csr_src[pos]  = src;
    csr_norm[pos] = dinv[src] * dinv[dst];
  }
}

// ---------------- embed: h = x @ W_emb + b ----------------
__global__ __launch_bounds__(256) void k_embed(const float* __restrict__ x,
                                               const float* __restrict__ W,
                                               const float* __restrict__ b,
                                               float* __restrict__ h) {
  __shared__ float sW[F_IN * H];   // 16 KB
  __shared__ float sX[32 * 36];    // 32 nodes x 32 k (stride 36, 16B-aligned rows)
  int t = threadIdx.x;
#pragma unroll
  for (int p = 0; p < 4; ++p) {
    int fi = t + p * 256;  // over 1024 float4
    ((float4*)sW)[fi] = ((const float4*)W)[fi];
  }
  int n0 = blockIdx.x * 32;
  {
    int row = t >> 3, k4 = (t & 7) * 4;
    int gn = n0 + row; if (gn >= N_NODES) gn = N_NODES - 1;
    *(float4*)(sX + row * 36 + k4) = *(const float4*)(x + (size_t)gn * F_IN + k4);
  }
  __syncthreads();
  int lane32 = t & 31, quad = t >> 5;
  int c = lane32 * 4, nb = quad * 4;
  float4 acc[4] = {make_float4(0,0,0,0), make_float4(0,0,0,0),
                   make_float4(0,0,0,0), make_float4(0,0,0,0)};
#pragma unroll
  for (int kk = 0; kk < F_IN; kk += 4) {
    float4 w0 = *(const float4*)(sW + (kk + 0) * H + c);
    float4 w1 = *(const float4*)(sW + (kk + 1) * H + c);
    float4 w2 = *(const float4*)(sW + (kk + 2) * H + c);
    float4 w3 = *(const float4*)(sW + (kk + 3) * H + c);
#pragma unroll
    for (int i = 0; i < 4; ++i) {
      float4 hv = *(const float4*)(sX + (nb + i) * 36 + kk);
      fma4(acc[i], hv.x, w0); fma4(acc[i], hv.y, w1);
      fma4(acc[i], hv.z, w2); fma4(acc[i], hv.w, w3);
    }
  }
  float4 bv = *(const float4*)(b + c);
#pragma unroll
  for (int i = 0; i < 4; ++i) {
    int n = n0 + nb + i;
    if (n < N_NODES) {
      float4 o = acc[i];
      o.x += bv.x; o.y += bv.y; o.z += bv.z; o.w += bv.w;
      *(float4*)(h + (size_t)n * H + c) = o;
    }
  }
}

// ---------------- main GEMM: C = A @ W (+bias), A:[N,128] W:[128,128] ----------------
// Block tile: 128 nodes x 64 cols (blockIdx.y = col half), k chunked 2x64.
// Per-thread 8n x 4c. sH rows skewed (+4 words per 8-row group) so the 4
// distinct-broadcast addresses per hv read land in distinct banks.
__global__ __launch_bounds__(256) void k_mm(const float* __restrict__ A,
                                            const float* __restrict__ W,
                                            const float* __restrict__ bias,
                                            float* __restrict__ C) {
  __shared__ float sW[64 * 64];  // 16 KB, [k][c] chunk
  __shared__ float sH[8768];     // ~35 KB, row stride 68 + skew
  int t = threadIdx.x;
  int by = blockIdx.y;
  int n0 = blockIdx.x * 128;
  int cg = t & 15, ng = t >> 4;
  int c = cg * 4;
  float4 acc[8];
#pragma unroll
  for (int i = 0; i < 8; ++i) acc[i] = make_float4(0.f, 0.f, 0.f, 0.f);

  for (int kc = 0; kc < 2; ++kc) {
    if (kc) __syncthreads();
#pragma unroll
    for (int p = 0; p < 4; ++p) {  // W chunk 64k x 64c
      int fi = t + p * 256;
      int k = fi >> 4, c4 = (fi & 15) * 4;
      *(float4*)(sW + k * 64 + c4) =
          *(const float4*)(W + (size_t)(kc * 64 + k) * H + by * 64 + c4);
    }
#pragma unroll
    for (int p = 0; p < 8; ++p) {  // H chunk 128n x 64k
      int fi = t + p * 256;
      int row = fi >> 4, k4 = (fi & 15) * 4;
      int gn = n0 + row; if (gn >= N_NODES) gn = N_NODES - 1;
      *(float4*)(sH + row * 68 + (row >> 3) * 4 + k4) =
          *(const float4*)(A + (size_t)gn * H + kc * 64 + k4);
    }
    __syncthreads();
    int hbase = ng * 548;  // ng*(8*68+4)
#pragma unroll
    for (int k4 = 0; k4 < 64; k4 += 4) {
      float4 w0 = *(const float4*)(sW + (k4 + 0) * 64 + c);
      float4 w1 = *(const float4*)(sW + (k4 + 1) * 64 + c);
      float4 w2 = *(const float4*)(sW + (k4 + 2) * 64 + c);
      float4 w3 = *(const float4*)(sW + (k4 + 3) * 64 + c);
#pragma unroll
      for (int i = 0; i < 8; ++i) {
        float4 hv = *(const float4*)(sH + hbase + i * 68 + k4);
        fma4(acc[i], hv.x, w0); fma4(acc[i], hv.y, w1);
        fma4(acc[i], hv.z, w2); fma4(acc[i], hv.w, w3);
      }
    }
  }
  float4 bv = make_float4(0, 0, 0, 0);
  if (bias) bv = *(const float4*)(bias + by * 64 + c);
#pragma unroll
  for (int i = 0; i < 8; ++i) {
    int n = n0 + ng * 8 + i;
    if (n < N_NODES) {
      float4 o = acc[i];
      o.x += bv.x; o.y += bv.y; o.z += bv.z; o.w += bv.w;
      *(float4*)(C + (size_t)n * H + by * 64 + c) = o;
    }
  }
}

// ---------------- aggregate + bias + LN + relu + residual ----------------
// One wave per node; lane holds features (2l, 2l+1) as float2.
__global__ __launch_bounds__(256) void k_agg(
    const float* __restrict__ ht, const float* __restrict__ res,
    const float* __restrict__ dinv, const int* __restrict__ offs,
    const int* __restrict__ deg, const int* __restrict__ csr_src,
    const float* __restrict__ csr_norm, const float* __restrict__ bias,
    const float* __restrict__ g, const float* __restrict__ bb,
    float* __restrict__ hout) {
  int wid = threadIdx.x >> 6, lane = threadIdx.x & 63;
  int node = blockIdx.x * 4 + wid;
  if (node >= N_NODES) return;
  int start = offs[node], cnt = deg[node];
  float di = dinv[node];
  float2 v = *(const float2*)(ht + (size_t)node * H + 2 * lane);
  float sw = di * di;
  float2 acc; acc.x = sw * v.x; acc.y = sw * v.y;  // self-loop
  for (int b0 = 0; b0 < cnt; b0 += 64) {
    int m = min(64, cnt - b0);
    int s = 0; float w = 0.f;
    if (lane < m) {
      s = csr_src[start + b0 + lane];
      w = csr_norm[start + b0 + lane];
    }
#pragma unroll 4
    for (int e = 0; e < m; ++e) {
      int ss = __shfl(s, e, 64);
      float we = __shfl(w, e, 64);
      float2 u = *(const float2*)(ht + (size_t)ss * H + 2 * lane);
      acc.x = fmaf(we, u.x, acc.x);
      acc.y = fmaf(we, u.y, acc.y);
    }
  }
  acc.x += bias[2 * lane]; acc.y += bias[2 * lane + 1];
  float mu = wave_red(acc.x + acc.y) * (1.f / 128.f);
  float dx = acc.x - mu, dy = acc.y - mu;
  float var = wave_red(dx * dx + dy * dy) * (1.f / 128.f);
  float rs = rsqrtf(var + EPS);
  float ox = fmaxf(fmaf(dx * rs, g[2 * lane], bb[2 * lane]), 0.f);
  float oy = fmaxf(fmaf(dy * rs, g[2 * lane + 1], bb[2 * lane + 1]), 0.f);
  float2 r = *(const float2*)(res + (size_t)node * H + 2 * lane);
  float2 o; o.x = ox + r.x; o.y = oy + r.y;
  *(float2*)(hout + (size_t)node * H + 2 * lane) = o;
}

// ---------------- mean pool ----------------
__global__ void k_pool(const float* __restrict__ h, float* __restrict__ pool) {
  int f = threadIdx.x;  // 128
  float acc = 0.f;
  for (int n = blockIdx.x; n < N_NODES; n += gridDim.x)
    acc += h[(size_t)n * H + f];
  atomicAdd(&pool[f], acc);
}

// ---------------- head: LN(mean @ Wfc1 + b) relu @ Wfc2 + b ----------------
__global__ void k_head(const float* __restrict__ pool, const float* __restrict__ Wfc1,
                       const float* __restrict__ bfc1, const float* __restrict__ g,
                       const float* __restrict__ bb, const float* __restrict__ Wfc2,
                       const float* __restrict__ bfc2, float* __restrict__ out) {
  __shared__ float sm[128], s1[128], stats[2];
  int t = threadIdx.x;
  if (t < 128) sm[t] = pool[t] * (1.f / (float)N_NODES);
  __syncthreads();
  if (t < 128) {
    float a = bfc1[t];
    for (int k = 0; k < 128; ++k) a = fmaf(sm[k], Wfc1[k * 128 + t], a);
    s1[t] = a;
  }
  __syncthreads();
  if (t == 0) {
    float mu = 0.f;
    for (int k = 0; k < 128; ++k) mu += s1[k];
    mu *= (1.f / 128.f);
    float var = 0.f;
    for (int k = 0; k < 128; ++k) { float d = s1[k] - mu; var += d * d; }
    var *= (1.f / 128.f);
    stats[0] = mu; stats[1] = rsqrtf(var + EPS);
  }
  __syncthreads();
  if (t < 128) s1[t] = fmaxf((s1[t] - stats[0]) * stats[1] * g[t] + bb[t], 0.f);
  __syncthreads();
  if (t < OUT_F) {
    float a = bfc2[t];
    for (int k = 0; k < 128; ++k) a = fmaf(s1[k], Wfc2[k * OUT_F + t], a);
    out[t] = a;
  }
}

extern "C" void kernel_launch(void* const* d_in, const int* in_sizes, int n_in,
                              void* d_out, int out_size, void* d_ws, size_t ws_size,
                              hipStream_t stream) {
  const float* x      = (const float*)d_in[0];
  const int*   ei     = (const int*)d_in[1];
  const float* W_emb  = (const float*)d_in[2];
  const float* b_emb  = (const float*)d_in[3];
  const float* W_conv = (const float*)d_in[4];
  const float* b_conv = (const float*)d_in[5];
  const float* ln_g   = (const float*)d_in[6];
  const float* ln_b   = (const float*)d_in[7];
  const float* W_res  = (const float*)d_in[8];
  const float* b_res  = (const float*)d_in[9];
  const float* W_fc1  = (const float*)d_in[10];
  const float* b_fc1  = (const float*)d_in[11];
  const float* fcn_g  = (const float*)d_in[12];
  const float* fcn_b  = (const float*)d_in[13];
  const float* W_fc2  = (const float*)d_in[14];
  const float* b_fc2  = (const float*)d_in[15];
  float* out = (float*)d_out;

  char* p = (char*)d_ws;
  auto take = [&](size_t bytes) {
    char* r = p; p += (bytes + 255) & ~(size_t)255; return r;
  };
  float* bufA = (float*)take((size_t)N_NODES * H * 4);
  float* bufB = (float*)take((size_t)N_NODES * H * 4);
  float* bufC = (float*)take((size_t)N_NODES * H * 4);
  int*   deg  = (int*)take(N_NODES * 4);
  int*   offs = (int*)take(N_NODES * 4);
  int*   work = (int*)take(N_NODES * 4);
  int*   parts= (int*)take(512 * 4);
  float* dinv = (float*)take(N_NODES * 4);
  int*   csrc = (int*)take((size_t)NEDGES * 4);
  float* cnrm = (float*)take((size_t)NEDGES * 4);
  float* pool = (float*)take(128 * 4);

  hipMemsetAsync(deg, 0, N_NODES * 4, stream);
  hipMemsetAsync(pool, 0, 128 * 4, stream);

  int nparts = (N_NODES + 255) / 256;
  k_hist<<<(NEDGES + 255) / 256, 256, 0, stream>>>(ei, deg);
  k_dinv<<<nparts, 256, 0, stream>>>(deg, dinv);
  k_scan_a<<<nparts, 256, 0, stream>>>(deg, offs, parts);
  k_scan_b<<<1, 512, 0, stream>>>(parts, nparts);
  k_scan_c<<<nparts, 256, 0, stream>>>(offs, parts, work);
  k_fill<<<(NEDGES + 255) / 256, 256, 0, stream>>>(ei, dinv, work, csrc, cnrm);
  k_embed<<<(N_NODES + 31) / 32, 256, 0, stream>>>(x, W_emb, b_emb, bufA);

  dim3 mmg((N_NODES + 127) / 128, 2);
  int aggg = (N_NODES + 3) / 4;
  // layer 0: h=A -> ht=B -> out=C (res=A)
  k_mm<<<mmg, 256, 0, stream>>>(bufA, W_conv + 0 * H * H, nullptr, bufB);
  k_agg<<<aggg, 256, 0, stream>>>(bufB, bufA, dinv, offs, deg, csrc, cnrm,
                                  b_conv + 0 * H, ln_g + 0 * H, ln_b + 0 * H, bufC);
  // layer 1: h=C -> ht=A -> out=B (res=C)
  k_mm<<<mmg, 256, 0, stream>>>(bufC, W_conv + 1 * H * H, nullptr, bufA);
  k_agg<<<aggg, 256, 0, stream>>>(bufA, bufC, dinv, offs, deg, csrc, cnrm,
                                  b_conv + 1 * H, ln_g + 1 * H, ln_b + 1 * H, bufB);
  // layer 2: h=B; res=C<-B@W_res0+b_res0; ht=A<-B@W2; out=B
  k_mm<<<mmg, 256, 0, stream>>>(bufB, W_res, b_res, bufC);
  k_mm<<<mmg, 256, 0, stream>>>(bufB, W_conv + 2 * H * H, nullptr, bufA);
  k_agg<<<aggg, 256, 0, stream>>>(bufA, bufC, dinv, offs, deg, csrc, cnrm,
                                  b_conv + 2 * H, ln_g + 2 * H, ln_b + 2 * H, bufB);
  // layer 3: h=B -> ht=C -> out=A (res=B)
  k_mm<<<mmg, 256, 0, stream>>>(bufB, W_conv + 3 * H * H, nullptr, bufC);
  k_agg<<<aggg, 256, 0, stream>>>(bufC, bufB, dinv, offs, deg, csrc, cnrm,
                                  b_conv + 3 * H, ln_g + 3 * H, ln_b + 3 * H, bufA);

  k_pool<<<512, 128, 0, stream>>>(bufA, pool);
  k_head<<<1, 256, 0, stream>>>(pool, W_fc1, b_fc1, fcn_g, fcn_b,
                                W_fc2, b_fc2, out);
}

// Round 2
// 1035.964 us; speedup vs baseline: 1.1708x; 1.1708x over previous
//
#include <hip/hip_runtime.h>

constexpr int N_NODES = 100000;
constexpr int F_IN    = 32;
constexpr int H       = 128;
constexpr int OUT_F   = 200;
constexpr int NEDGES  = 1600000;
constexpr float EPS   = 1e-5f;

typedef __attribute__((ext_vector_type(8))) short  short8;
typedef __attribute__((ext_vector_type(4))) float  f32x4;
typedef __attribute__((ext_vector_type(4))) unsigned short us4;

__device__ __forceinline__ float wave_red(float v) {
#pragma unroll
  for (int m = 32; m > 0; m >>= 1) v += __shfl_xor(v, m, 64);
  return v;
}

__device__ __forceinline__ void fma4(float4& a, float s, const float4& w) {
  a.x = fmaf(s, w.x, a.x); a.y = fmaf(s, w.y, a.y);
  a.z = fmaf(s, w.z, a.z); a.w = fmaf(s, w.w, a.w);
}

__device__ __forceinline__ unsigned short f2bf(float f) {  // RNE
  union { float f; unsigned u; } v; v.f = f;
  unsigned r = v.u + 0x7fffu + ((v.u >> 16) & 1u);
  return (unsigned short)(r >> 16);
}
__device__ __forceinline__ float bf2f(unsigned short s) {
  union { unsigned u; float f; } v; v.u = ((unsigned)s) << 16;
  return v.f;
}

// ---------------- CSR build ----------------
__global__ void k_hist(const int* __restrict__ ei, int* __restrict__ deg) {
  int e = blockIdx.x * blockDim.x + threadIdx.x;
  if (e < NEDGES) atomicAdd(&deg[ei[NEDGES + e]], 1);
}

__global__ void k_dinv(const int* __restrict__ deg, float* __restrict__ dinv) {
  int n = blockIdx.x * blockDim.x + threadIdx.x;
  if (n < N_NODES) dinv[n] = rsqrtf((float)(deg[n] + 1));  // +1 self-loop
}

__global__ void k_scan_a(const int* __restrict__ deg, int* __restrict__ offs,
                         int* __restrict__ parts) {
  __shared__ int s[256];
  int i = blockIdx.x * 256 + threadIdx.x;
  int d = (i < N_NODES) ? deg[i] : 0;
  s[threadIdx.x] = d;
  __syncthreads();
#pragma unroll
  for (int off = 1; off < 256; off <<= 1) {
    int v = (threadIdx.x >= off) ? s[threadIdx.x - off] : 0;
    __syncthreads();
    s[threadIdx.x] += v;
    __syncthreads();
  }
  if (i < N_NODES) offs[i] = s[threadIdx.x] - d;
  if (threadIdx.x == 255) parts[blockIdx.x] = s[255];
}

__global__ void k_scan_b(int* __restrict__ parts, int nparts) {
  __shared__ int s[512];
  int t = threadIdx.x;
  int d = (t < nparts) ? parts[t] : 0;
  s[t] = d;
  __syncthreads();
#pragma unroll
  for (int off = 1; off < 512; off <<= 1) {
    int v = (t >= off) ? s[t - off] : 0;
    __syncthreads();
    s[t] += v;
    __syncthreads();
  }
  if (t < nparts) parts[t] = s[t] - d;
}

__global__ void k_scan_c(int* __restrict__ offs, const int* __restrict__ parts,
                         int* __restrict__ work) {
  int i = blockIdx.x * 256 + threadIdx.x;
  if (i < N_NODES) {
    int o = offs[i] + parts[blockIdx.x];
    offs[i] = o;
    work[i] = o;
  }
}

__global__ void k_fill(const int* __restrict__ ei, const float* __restrict__ dinv,
                       int* __restrict__ work, int* __restrict__ csr_src,
                       float* __restrict__ csr_norm) {
  int e = blockIdx.x * blockDim.x + threadIdx.x;
  if (e < NEDGES) {
    int src = ei[e], dst = ei[NEDGES + e];
    int pos = atomicAdd(&work[dst], 1);
    csr_src[pos]  = src;
    csr_norm[pos] = dinv[src] * dinv[dst];
  }
}

// ---------------- W split precompute: WhiT/WloT[mat][n][k] bf16 ----------------
__global__ void k_wsplit(const float* __restrict__ W_conv,
                         const float* __restrict__ W_res,
                         unsigned short* __restrict__ whiT,
                         unsigned short* __restrict__ wloT) {
  int idx = blockIdx.x * blockDim.x + threadIdx.x;
  if (idx >= 5 * H * H) return;
  int m = idx >> 14, r = idx & 16383;
  int k = r >> 7, n = r & 127;
  const float* src = (m < 4) ? (W_conv + m * H * H) : W_res;
  float w = src[k * H + n];
  unsigned short hi = f2bf(w);
  unsigned short lo = f2bf(w - bf2f(hi));
  whiT[m * H * H + n * H + k] = hi;
  wloT[m * H * H + n * H + k] = lo;
}

// ---------------- embed: h = x @ W_emb + b (f32) ----------------
__global__ __launch_bounds__(256) void k_embed(const float* __restrict__ x,
                                               const float* __restrict__ W,
                                               const float* __restrict__ b,
                                               float* __restrict__ h) {
  __shared__ float sW[F_IN * H];
  __shared__ float sX[32 * 36];
  int t = threadIdx.x;
#pragma unroll
  for (int p = 0; p < 4; ++p) {
    int fi = t + p * 256;
    ((float4*)sW)[fi] = ((const float4*)W)[fi];
  }
  int n0 = blockIdx.x * 32;
  {
    int row = t >> 3, k4 = (t & 7) * 4;
    int gn = n0 + row; if (gn >= N_NODES) gn = N_NODES - 1;
    *(float4*)(sX + row * 36 + k4) = *(const float4*)(x + (size_t)gn * F_IN + k4);
  }
  __syncthreads();
  int lane32 = t & 31, quad = t >> 5;
  int c = lane32 * 4, nb = quad * 4;
  float4 acc[4] = {make_float4(0,0,0,0), make_float4(0,0,0,0),
                   make_float4(0,0,0,0), make_float4(0,0,0,0)};
#pragma unroll
  for (int kk = 0; kk < F_IN; kk += 4) {
    float4 w0 = *(const float4*)(sW + (kk + 0) * H + c);
    float4 w1 = *(const float4*)(sW + (kk + 1) * H + c);
    float4 w2 = *(const float4*)(sW + (kk + 2) * H + c);
    float4 w3 = *(const float4*)(sW + (kk + 3) * H + c);
#pragma unroll
    for (int i = 0; i < 4; ++i) {
      float4 hv = *(const float4*)(sX + (nb + i) * 36 + kk);
      fma4(acc[i], hv.x, w0); fma4(acc[i], hv.y, w1);
      fma4(acc[i], hv.z, w2); fma4(acc[i], hv.w, w3);
    }
  }
  float4 bv = *(const float4*)(b + c);
#pragma unroll
  for (int i = 0; i < 4; ++i) {
    int n = n0 + nb + i;
    if (n < N_NODES) {
      float4 o = acc[i];
      o.x += bv.x; o.y += bv.y; o.z += bv.z; o.w += bv.w;
      *(float4*)(h + (size_t)n * H + c) = o;
    }
  }
}

// ---------------- split-bf16 MFMA GEMM: C[N,128] = A[N,128] @ W ----------------
// Block: 256 thr = 4 waves; tile 64 rows x 128 cols. Wave: 32 rows x 64 cols
// = 2 row-tiles x 4 col-tiles of 16x16x32 MFMA. 3-pass split precision:
// Ahi*Whi + Alo*Whi + Ahi*Wlo (~f32 accurate; only Alo*Wlo dropped).
// A staged in LDS pre-split to bf16 (row stride 136 -> conflict-free b128).
// B frags straight from L2 (WT layout: 8 consecutive k = 16B).
template <bool BF16_OUT>
__global__ __launch_bounds__(256) void k_mm(const float* __restrict__ A,
                                            const unsigned short* __restrict__ WhiT,
                                            const unsigned short* __restrict__ WloT,
                                            const float* __restrict__ bias,
                                            void* __restrict__ Cout) {
  __shared__ __align__(16) unsigned short sAhi[64 * 136];
  __shared__ __align__(16) unsigned short sAlo[64 * 136];
  int t = threadIdx.x;
  int n0 = blockIdx.x * 64;
  // stage A -> split bf16 LDS
#pragma unroll
  for (int p = 0; p < 8; ++p) {
    int fi = t + p * 256;           // 2048 float4 units: 64 rows x 32
    int row = fi >> 5, c4 = (fi & 31) * 4;
    int gn = n0 + row; if (gn >= N_NODES) gn = N_NODES - 1;
    float4 v = *(const float4*)(A + (size_t)gn * H + c4);
    us4 hi, lo;
    hi.x = f2bf(v.x); lo.x = f2bf(v.x - bf2f(hi.x));
    hi.y = f2bf(v.y); lo.y = f2bf(v.y - bf2f(hi.y));
    hi.z = f2bf(v.z); lo.z = f2bf(v.z - bf2f(hi.z));
    hi.w = f2bf(v.w); lo.w = f2bf(v.w - bf2f(hi.w));
    *(us4*)(sAhi + row * 136 + c4) = hi;
    *(us4*)(sAlo + row * 136 + c4) = lo;
  }
  __syncthreads();

  int wave = t >> 6, lane = t & 63;
  int wr = wave >> 1, wc = wave & 1;
  int m = lane & 15, quad = (lane >> 4) & 3;

  f32x4 acc[2][4];
#pragma unroll
  for (int i = 0; i < 2; ++i)
#pragma unroll
    for (int j = 0; j < 4; ++j) acc[i][j] = (f32x4){0.f, 0.f, 0.f, 0.f};

#pragma unroll
  for (int q = 0; q < 4; ++q) {  // K chunks of 32
    short8 bh[4], bl[4];
#pragma unroll
    for (int ct = 0; ct < 4; ++ct) {
      int n = wc * 64 + ct * 16 + m;
      const unsigned short* bp = WhiT + n * H + q * 32 + quad * 8;
      const unsigned short* lp = WloT + n * H + q * 32 + quad * 8;
      bh[ct] = *(const short8*)bp;
      bl[ct] = *(const short8*)lp;
    }
    short8 ah[2], al[2];
#pragma unroll
    for (int rt = 0; rt < 2; ++rt) {
      int row = wr * 32 + rt * 16 + m;
      int koff = q * 32 + quad * 8;
      ah[rt] = *(const short8*)(sAhi + row * 136 + koff);
      al[rt] = *(const short8*)(sAlo + row * 136 + koff);
    }
#pragma unroll
    for (int rt = 0; rt < 2; ++rt)
#pragma unroll
      for (int ct = 0; ct < 4; ++ct) {
        acc[rt][ct] = __builtin_amdgcn_mfma_f32_16x16x32_bf16(ah[rt], bh[ct], acc[rt][ct], 0, 0, 0);
        acc[rt][ct] = __builtin_amdgcn_mfma_f32_16x16x32_bf16(al[rt], bh[ct], acc[rt][ct], 0, 0, 0);
        acc[rt][ct] = __builtin_amdgcn_mfma_f32_16x16x32_bf16(ah[rt], bl[ct], acc[rt][ct], 0, 0, 0);
      }
  }

  // epilogue: C/D layout col=lane&15, row=quad*4+reg
#pragma unroll
  for (int rt = 0; rt < 2; ++rt)
#pragma unroll
    for (int ct = 0; ct < 4; ++ct) {
      int col = wc * 64 + ct * 16 + m;
      float bv = 0.f;
      if (!BF16_OUT && bias) bv = bias[col];
#pragma unroll
      for (int r = 0; r < 4; ++r) {
        int gn = n0 + wr * 32 + rt * 16 + quad * 4 + r;
        if (gn < N_NODES) {
          if (BF16_OUT)
            ((unsigned short*)Cout)[(size_t)gn * H + col] = f2bf(acc[rt][ct][r]);
          else
            ((float*)Cout)[(size_t)gn * H + col] = acc[rt][ct][r] + bv;
        }
      }
    }
}

// ---------------- aggregate(bf16 ht) + bias + LN + relu + residual(f32) ----------------
__global__ __launch_bounds__(256) void k_agg(
    const unsigned short* __restrict__ htb, const float* __restrict__ res,
    const float* __restrict__ dinv, const int* __restrict__ offs,
    const int* __restrict__ deg, const int* __restrict__ csr_src,
    const float* __restrict__ csr_norm, const float* __restrict__ bias,
    const float* __restrict__ g, const float* __restrict__ bb,
    float* __restrict__ hout) {
  int wid = threadIdx.x >> 6, lane = threadIdx.x & 63;
  int node = blockIdx.x * 4 + wid;
  if (node >= N_NODES) return;
  int start = offs[node], cnt = deg[node];
  float di = dinv[node];
  unsigned uv = *(const unsigned*)(htb + (size_t)node * H + 2 * lane);
  float vx = bf2f((unsigned short)(uv & 0xffff));
  float vy = bf2f((unsigned short)(uv >> 16));
  float sw = di * di;
  float2 acc; acc.x = sw * vx; acc.y = sw * vy;  // self-loop
  for (int b0 = 0; b0 < cnt; b0 += 64) {
    int mm = min(64, cnt - b0);
    int s = 0; float w = 0.f;
    if (lane < mm) {
      s = csr_src[start + b0 + lane];
      w = csr_norm[start + b0 + lane];
    }
#pragma unroll 4
    for (int e = 0; e < mm; ++e) {
      int ss = __shfl(s, e, 64);
      float we = __shfl(w, e, 64);
      unsigned uu = *(const unsigned*)(htb + (size_t)ss * H + 2 * lane);
      acc.x = fmaf(we, bf2f((unsigned short)(uu & 0xffff)), acc.x);
      acc.y = fmaf(we, bf2f((unsigned short)(uu >> 16)), acc.y);
    }
  }
  acc.x += bias[2 * lane]; acc.y += bias[2 * lane + 1];
  float mu = wave_red(acc.x + acc.y) * (1.f / 128.f);
  float dx = acc.x - mu, dy = acc.y - mu;
  float var = wave_red(dx * dx + dy * dy) * (1.f / 128.f);
  float rs = rsqrtf(var + EPS);
  float ox = fmaxf(fmaf(dx * rs, g[2 * lane], bb[2 * lane]), 0.f);
  float oy = fmaxf(fmaf(dy * rs, g[2 * lane + 1], bb[2 * lane + 1]), 0.f);
  float2 r = *(const float2*)(res + (size_t)node * H + 2 * lane);
  float2 o; o.x = ox + r.x; o.y = oy + r.y;
  *(float2*)(hout + (size_t)node * H + 2 * lane) = o;
}

// ---------------- mean pool ----------------
__global__ void k_pool(const float* __restrict__ h, float* __restrict__ pool) {
  int f = threadIdx.x;  // 128
  float acc = 0.f;
  for (int n = blockIdx.x; n < N_NODES; n += gridDim.x)
    acc += h[(size_t)n * H + f];
  atomicAdd(&pool[f], acc);
}

// ---------------- head ----------------
__global__ void k_head(const float* __restrict__ pool, const float* __restrict__ Wfc1,
                       const float* __restrict__ bfc1, const float* __restrict__ g,
                       const float* __restrict__ bb, const float* __restrict__ Wfc2,
                       const float* __restrict__ bfc2, float* __restrict__ out) {
  __shared__ float sm[128], s1[128], stats[2];
  int t = threadIdx.x;
  if (t < 128) sm[t] = pool[t] * (1.f / (float)N_NODES);
  __syncthreads();
  if (t < 128) {
    float a = bfc1[t];
    for (int k = 0; k < 128; ++k) a = fmaf(sm[k], Wfc1[k * 128 + t], a);
    s1[t] = a;
  }
  __syncthreads();
  if (t == 0) {
    float mu = 0.f;
    for (int k = 0; k < 128; ++k) mu += s1[k];
    mu *= (1.f / 128.f);
    float var = 0.f;
    for (int k = 0; k < 128; ++k) { float d = s1[k] - mu; var += d * d; }
    var *= (1.f / 128.f);
    stats[0] = mu; stats[1] = rsqrtf(var + EPS);
  }
  __syncthreads();
  if (t < 128) s1[t] = fmaxf((s1[t] - stats[0]) * stats[1] * g[t] + bb[t], 0.f);
  __syncthreads();
  if (t < OUT_F) {
    float a = bfc2[t];
    for (int k = 0; k < 128; ++k) a = fmaf(s1[k], Wfc2[k * OUT_F + t], a);
    out[t] = a;
  }
}

extern "C" void kernel_launch(void* const* d_in, const int* in_sizes, int n_in,
                              void* d_out, int out_size, void* d_ws, size_t ws_size,
                              hipStream_t stream) {
  const float* x      = (const float*)d_in[0];
  const int*   ei     = (const int*)d_in[1];
  const float* W_emb  = (const float*)d_in[2];
  const float* b_emb  = (const float*)d_in[3];
  const float* W_conv = (const float*)d_in[4];
  const float* b_conv = (const float*)d_in[5];
  const float* ln_g   = (const float*)d_in[6];
  const float* ln_b   = (const float*)d_in[7];
  const float* W_res  = (const float*)d_in[8];
  const float* b_res  = (const float*)d_in[9];
  const float* W_fc1  = (const float*)d_in[10];
  const float* b_fc1  = (const float*)d_in[11];
  const float* fcn_g  = (const float*)d_in[12];
  const float* fcn_b  = (const float*)d_in[13];
  const float* W_fc2  = (const float*)d_in[14];
  const float* b_fc2  = (const float*)d_in[15];
  float* out = (float*)d_out;

  char* p = (char*)d_ws;
  auto take = [&](size_t bytes) {
    char* r = p; p += (bytes + 255) & ~(size_t)255; return r;
  };
  float*          bufA = (float*)take((size_t)N_NODES * H * 4);
  float*          bufB = (float*)take((size_t)N_NODES * H * 4);
  float*          bufC = (float*)take((size_t)N_NODES * H * 4);
  unsigned short* htb  = (unsigned short*)take((size_t)N_NODES * H * 2);
  unsigned short* whiT = (unsigned short*)take((size_t)5 * H * H * 2);
  unsigned short* wloT = (unsigned short*)take((size_t)5 * H * H * 2);
  int*   deg  = (int*)take(N_NODES * 4);
  int*   offs = (int*)take(N_NODES * 4);
  int*   work = (int*)take(N_NODES * 4);
  int*   parts= (int*)take(512 * 4);
  float* dinv = (float*)take(N_NODES * 4);
  int*   csrc = (int*)take((size_t)NEDGES * 4);
  float* cnrm = (float*)take((size_t)NEDGES * 4);
  float* pool = (float*)take(128 * 4);

  hipMemsetAsync(deg, 0, N_NODES * 4, stream);
  hipMemsetAsync(pool, 0, 128 * 4, stream);

  int nparts = (N_NODES + 255) / 256;
  k_hist<<<(NEDGES + 255) / 256, 256, 0, stream>>>(ei, deg);
  k_dinv<<<nparts, 256, 0, stream>>>(deg, dinv);
  k_scan_a<<<nparts, 256, 0, stream>>>(deg, offs, parts);
  k_scan_b<<<1, 512, 0, stream>>>(parts, nparts);
  k_scan_c<<<nparts, 256, 0, stream>>>(offs, parts, work);
  k_fill<<<(NEDGES + 255) / 256, 256, 0, stream>>>(ei, dinv, work, csrc, cnrm);
  k_wsplit<<<(5 * H * H + 255) / 256, 256, 0, stream>>>(W_conv, W_res, whiT, wloT);
  k_embed<<<(N_NODES + 31) / 32, 256, 0, stream>>>(x, W_emb, b_emb, bufA);

  int mmg = (N_NODES + 63) / 64;
  int aggg = (N_NODES + 3) / 4;
  // L0: h0=A -> htb -> h1=C (res=A)
  k_mm<true><<<mmg, 256, 0, stream>>>(bufA, whiT + 0 * H * H, wloT + 0 * H * H, nullptr, htb);
  k_agg<<<aggg, 256, 0, stream>>>(htb, bufA, dinv, offs, deg, csrc, cnrm,
                                  b_conv + 0 * H, ln_g + 0 * H, ln_b + 0 * H, bufC);
  // L1: h1=C -> htb -> h2=A (res=C)
  k_mm<true><<<mmg, 256, 0, stream>>>(bufC, whiT + 1 * H * H, wloT + 1 * H * H, nullptr, htb);
  k_agg<<<aggg, 256, 0, stream>>>(htb, bufC, dinv, offs, deg, csrc, cnrm,
                                  b_conv + 1 * H, ln_g + 1 * H, ln_b + 1 * H, bufA);
  // L2: h2=A; res=B <- A@W_res+b_res (f32); htb <- A@W2; h3=C
  k_mm<false><<<mmg, 256, 0, stream>>>(bufA, whiT + 4 * H * H, wloT + 4 * H * H, b_res, bufB);
  k_mm<true><<<mmg, 256, 0, stream>>>(bufA, whiT + 2 * H * H, wloT + 2 * H * H, nullptr, htb);
  k_agg<<<aggg, 256, 0, stream>>>(htb, bufB, dinv, offs, deg, csrc, cnrm,
                                  b_conv + 2 * H, ln_g + 2 * H, ln_b + 2 * H, bufC);
  // L3: h3=C -> htb -> h4=A (res=C)
  k_mm<true><<<mmg, 256, 0, stream>>>(bufC, whiT + 3 * H * H, wloT + 3 * H * H, nullptr, htb);
  k_agg<<<aggg, 256, 0, stream>>>(htb, bufC, dinv, offs, deg, csrc, cnrm,
                                  b_conv + 3 * H, ln_g + 3 * H, ln_b + 3 * H, bufA);

  k_pool<<<512, 128, 0, stream>>>(bufA, pool);
  k_head<<<1, 256, 0, stream>>>(pool, W_fc1, b_fc1, fcn_g, fcn_b,
                                W_fc2, b_fc2, out);
}

// Round 3
// 914.307 us; speedup vs baseline: 1.3266x; 1.1331x over previous
//
#include <hip/hip_runtime.h>

constexpr int N_NODES = 100000;
constexpr int F_IN    = 32;
constexpr int H       = 128;
constexpr int OUT_F   = 200;
constexpr int NEDGES  = 1600000;
constexpr float EPS   = 1e-5f;

typedef __attribute__((ext_vector_type(8))) short  short8;
typedef __attribute__((ext_vector_type(4))) float  f32x4;
typedef __attribute__((ext_vector_type(4))) unsigned short us4;

__device__ __forceinline__ void fma4(float4& a, float s, const float4& w) {
  a.x = fmaf(s, w.x, a.x); a.y = fmaf(s, w.y, a.y);
  a.z = fmaf(s, w.z, a.z); a.w = fmaf(s, w.w, a.w);
}

__device__ __forceinline__ unsigned short f2bf(float f) {  // RNE
  union { float f; unsigned u; } v; v.f = f;
  unsigned r = v.u + 0x7fffu + ((v.u >> 16) & 1u);
  return (unsigned short)(r >> 16);
}
__device__ __forceinline__ float bf2f(unsigned short s) {
  union { unsigned u; float f; } v; v.u = ((unsigned)s) << 16;
  return v.f;
}
__device__ __forceinline__ float bflo(unsigned u) { return __uint_as_float(u << 16); }
__device__ __forceinline__ float bfhi(unsigned u) { return __uint_as_float(u & 0xffff0000u); }

// ---------------- CSR build ----------------
__global__ void k_hist(const int* __restrict__ ei, int* __restrict__ deg) {
  int i = blockIdx.x * blockDim.x + threadIdx.x;
  if (i < NEDGES / 4) {
    int4 d4 = *(const int4*)(ei + NEDGES + 4 * i);
    atomicAdd(&deg[d4.x], 1); atomicAdd(&deg[d4.y], 1);
    atomicAdd(&deg[d4.z], 1); atomicAdd(&deg[d4.w], 1);
  }
}

// block-local exclusive scan of deg + dinv (fused)
__global__ void k_scan_a(const int* __restrict__ deg, int* __restrict__ offs,
                         int* __restrict__ parts, float* __restrict__ dinv) {
  __shared__ int s[256];
  int i = blockIdx.x * 256 + threadIdx.x;
  int d = (i < N_NODES) ? deg[i] : 0;
  s[threadIdx.x] = d;
  __syncthreads();
#pragma unroll
  for (int off = 1; off < 256; off <<= 1) {
    int v = (threadIdx.x >= off) ? s[threadIdx.x - off] : 0;
    __syncthreads();
    s[threadIdx.x] += v;
    __syncthreads();
  }
  if (i < N_NODES) {
    offs[i] = s[threadIdx.x] - d;
    dinv[i] = rsqrtf((float)(d + 1));  // +1 self-loop
  }
  if (threadIdx.x == 255) parts[blockIdx.x] = s[255];
}

__global__ void k_scan_b(int* __restrict__ parts, int nparts) {
  __shared__ int s[512];
  int t = threadIdx.x;
  int d = (t < nparts) ? parts[t] : 0;
  s[t] = d;
  __syncthreads();
#pragma unroll
  for (int off = 1; off < 512; off <<= 1) {
    int v = (t >= off) ? s[t - off] : 0;
    __syncthreads();
    s[t] += v;
    __syncthreads();
  }
  if (t < nparts) parts[t] = s[t] - d;
}

__global__ void k_scan_c(int* __restrict__ offs, const int* __restrict__ parts,
                         int* __restrict__ work) {
  int i = blockIdx.x * 256 + threadIdx.x;
  if (i < N_NODES) {
    int o = offs[i] + parts[blockIdx.x];
    offs[i] = o;
    work[i] = o;
  }
}

// 4 edges/thread, single int2 store per edge (one dirtied line, not two)
__global__ void k_fill(const int* __restrict__ ei, const float* __restrict__ dinv,
                       int* __restrict__ work, int2* __restrict__ csr) {
  int i = blockIdx.x * blockDim.x + threadIdx.x;
  if (i < NEDGES / 4) {
    int4 s4 = *(const int4*)(ei + 4 * i);
    int4 d4 = *(const int4*)(ei + NEDGES + 4 * i);
    int p0 = atomicAdd(&work[d4.x], 1);
    int p1 = atomicAdd(&work[d4.y], 1);
    int p2 = atomicAdd(&work[d4.z], 1);
    int p3 = atomicAdd(&work[d4.w], 1);
    csr[p0] = make_int2(s4.x, __float_as_int(dinv[s4.x] * dinv[d4.x]));
    csr[p1] = make_int2(s4.y, __float_as_int(dinv[s4.y] * dinv[d4.y]));
    csr[p2] = make_int2(s4.z, __float_as_int(dinv[s4.z] * dinv[d4.z]));
    csr[p3] = make_int2(s4.w, __float_as_int(dinv[s4.w] * dinv[d4.w]));
  }
}

// ---------------- W split precompute: WhiT/WloT[mat][n][k] bf16 ----------------
__global__ void k_wsplit(const float* __restrict__ W_conv,
                         const float* __restrict__ W_res,
                         unsigned short* __restrict__ whiT,
                         unsigned short* __restrict__ wloT) {
  int idx = blockIdx.x * blockDim.x + threadIdx.x;
  if (idx >= 5 * H * H) return;
  int m = idx >> 14, r = idx & 16383;
  int k = r >> 7, n = r & 127;
  const float* src = (m < 4) ? (W_conv + m * H * H) : W_res;
  float w = src[k * H + n];
  unsigned short hi = f2bf(w);
  unsigned short lo = f2bf(w - bf2f(hi));
  whiT[m * H * H + n * H + k] = hi;
  wloT[m * H * H + n * H + k] = lo;
}

// ---------------- embed: h = x @ W_emb + b (f32) ----------------
__global__ __launch_bounds__(256) void k_embed(const float* __restrict__ x,
                                               const float* __restrict__ W,
                                               const float* __restrict__ b,
                                               float* __restrict__ h) {
  __shared__ float sW[F_IN * H];
  __shared__ float sX[32 * 36];
  int t = threadIdx.x;
#pragma unroll
  for (int p = 0; p < 4; ++p) {
    int fi = t + p * 256;
    ((float4*)sW)[fi] = ((const float4*)W)[fi];
  }
  int n0 = blockIdx.x * 32;
  {
    int row = t >> 3, k4 = (t & 7) * 4;
    int gn = n0 + row; if (gn >= N_NODES) gn = N_NODES - 1;
    *(float4*)(sX + row * 36 + k4) = *(const float4*)(x + (size_t)gn * F_IN + k4);
  }
  __syncthreads();
  int lane32 = t & 31, quad = t >> 5;
  int c = lane32 * 4, nb = quad * 4;
  float4 acc[4] = {make_float4(0,0,0,0), make_float4(0,0,0,0),
                   make_float4(0,0,0,0), make_float4(0,0,0,0)};
#pragma unroll
  for (int kk = 0; kk < F_IN; kk += 4) {
    float4 w0 = *(const float4*)(sW + (kk + 0) * H + c);
    float4 w1 = *(const float4*)(sW + (kk + 1) * H + c);
    float4 w2 = *(const float4*)(sW + (kk + 2) * H + c);
    float4 w3 = *(const float4*)(sW + (kk + 3) * H + c);
#pragma unroll
    for (int i = 0; i < 4; ++i) {
      float4 hv = *(const float4*)(sX + (nb + i) * 36 + kk);
      fma4(acc[i], hv.x, w0); fma4(acc[i], hv.y, w1);
      fma4(acc[i], hv.z, w2); fma4(acc[i], hv.w, w3);
    }
  }
  float4 bv = *(const float4*)(b + c);
#pragma unroll
  for (int i = 0; i < 4; ++i) {
    int n = n0 + nb + i;
    if (n < N_NODES) {
      float4 o = acc[i];
      o.x += bv.x; o.y += bv.y; o.z += bv.z; o.w += bv.w;
      *(float4*)(h + (size_t)n * H + c) = o;
    }
  }
}

// ---------------- split-bf16 MFMA GEMM: htb[N,128] = bf16(A[N,128] @ W) ----------------
__global__ __launch_bounds__(256) void k_mm(const float* __restrict__ A,
                                            const unsigned short* __restrict__ WhiT,
                                            const unsigned short* __restrict__ WloT,
                                            unsigned short* __restrict__ htb) {
  __shared__ __align__(16) unsigned short sAhi[64 * 136];
  __shared__ __align__(16) unsigned short sAlo[64 * 136];
  int t = threadIdx.x;
  int n0 = blockIdx.x * 64;
#pragma unroll
  for (int p = 0; p < 8; ++p) {
    int fi = t + p * 256;
    int row = fi >> 5, c4 = (fi & 31) * 4;
    int gn = n0 + row; if (gn >= N_NODES) gn = N_NODES - 1;
    float4 v = *(const float4*)(A + (size_t)gn * H + c4);
    us4 hi, lo;
    hi.x = f2bf(v.x); lo.x = f2bf(v.x - bf2f(hi.x));
    hi.y = f2bf(v.y); lo.y = f2bf(v.y - bf2f(hi.y));
    hi.z = f2bf(v.z); lo.z = f2bf(v.z - bf2f(hi.z));
    hi.w = f2bf(v.w); lo.w = f2bf(v.w - bf2f(hi.w));
    *(us4*)(sAhi + row * 136 + c4) = hi;
    *(us4*)(sAlo + row * 136 + c4) = lo;
  }
  __syncthreads();

  int wave = t >> 6, lane = t & 63;
  int wr = wave >> 1, wc = wave & 1;
  int m = lane & 15, quad = (lane >> 4) & 3;

  f32x4 acc[2][4];
#pragma unroll
  for (int i = 0; i < 2; ++i)
#pragma unroll
    for (int j = 0; j < 4; ++j) acc[i][j] = (f32x4){0.f, 0.f, 0.f, 0.f};

#pragma unroll
  for (int q = 0; q < 4; ++q) {
    short8 bh[4], bl[4];
#pragma unroll
    for (int ct = 0; ct < 4; ++ct) {
      int n = wc * 64 + ct * 16 + m;
      bh[ct] = *(const short8*)(WhiT + n * H + q * 32 + quad * 8);
      bl[ct] = *(const short8*)(WloT + n * H + q * 32 + quad * 8);
    }
    short8 ah[2], al[2];
#pragma unroll
    for (int rt = 0; rt < 2; ++rt) {
      int row = wr * 32 + rt * 16 + m;
      ah[rt] = *(const short8*)(sAhi + row * 136 + q * 32 + quad * 8);
      al[rt] = *(const short8*)(sAlo + row * 136 + q * 32 + quad * 8);
    }
#pragma unroll
    for (int rt = 0; rt < 2; ++rt)
#pragma unroll
      for (int ct = 0; ct < 4; ++ct) {
        acc[rt][ct] = __builtin_amdgcn_mfma_f32_16x16x32_bf16(ah[rt], bh[ct], acc[rt][ct], 0, 0, 0);
        acc[rt][ct] = __builtin_amdgcn_mfma_f32_16x16x32_bf16(al[rt], bh[ct], acc[rt][ct], 0, 0, 0);
        acc[rt][ct] = __builtin_amdgcn_mfma_f32_16x16x32_bf16(ah[rt], bl[ct], acc[rt][ct], 0, 0, 0);
      }
  }
#pragma unroll
  for (int rt = 0; rt < 2; ++rt)
#pragma unroll
    for (int ct = 0; ct < 4; ++ct) {
      int col = wc * 64 + ct * 16 + m;
#pragma unroll
      for (int r = 0; r < 4; ++r) {
        int gn = n0 + wr * 32 + rt * 16 + quad * 4 + r;
        if (gn < N_NODES) htb[(size_t)gn * H + col] = f2bf(acc[rt][ct][r]);
      }
    }
}

// layer-2 fused: htb = bf16(A@Wc), Cres = A@Wr + biasR (shares A staging)
__global__ __launch_bounds__(256) void k_mm2(const float* __restrict__ A,
    const unsigned short* __restrict__ WhiC, const unsigned short* __restrict__ WloC,
    const unsigned short* __restrict__ WhiR, const unsigned short* __restrict__ WloR,
    const float* __restrict__ biasR,
    unsigned short* __restrict__ htb, float* __restrict__ Cres) {
  __shared__ __align__(16) unsigned short sAhi[64 * 136];
  __shared__ __align__(16) unsigned short sAlo[64 * 136];
  int t = threadIdx.x;
  int n0 = blockIdx.x * 64;
#pragma unroll
  for (int p = 0; p < 8; ++p) {
    int fi = t + p * 256;
    int row = fi >> 5, c4 = (fi & 31) * 4;
    int gn = n0 + row; if (gn >= N_NODES) gn = N_NODES - 1;
    float4 v = *(const float4*)(A + (size_t)gn * H + c4);
    us4 hi, lo;
    hi.x = f2bf(v.x); lo.x = f2bf(v.x - bf2f(hi.x));
    hi.y = f2bf(v.y); lo.y = f2bf(v.y - bf2f(hi.y));
    hi.z = f2bf(v.z); lo.z = f2bf(v.z - bf2f(hi.z));
    hi.w = f2bf(v.w); lo.w = f2bf(v.w - bf2f(hi.w));
    *(us4*)(sAhi + row * 136 + c4) = hi;
    *(us4*)(sAlo + row * 136 + c4) = lo;
  }
  __syncthreads();

  int wave = t >> 6, lane = t & 63;
  int wr = wave >> 1, wc = wave & 1;
  int m = lane & 15, quad = (lane >> 4) & 3;

  f32x4 accC[2][4], accR[2][4];
#pragma unroll
  for (int i = 0; i < 2; ++i)
#pragma unroll
    for (int j = 0; j < 4; ++j) {
      accC[i][j] = (f32x4){0.f, 0.f, 0.f, 0.f};
      accR[i][j] = (f32x4){0.f, 0.f, 0.f, 0.f};
    }

#pragma unroll
  for (int q = 0; q < 4; ++q) {
    short8 ah[2], al[2];
#pragma unroll
    for (int rt = 0; rt < 2; ++rt) {
      int row = wr * 32 + rt * 16 + m;
      ah[rt] = *(const short8*)(sAhi + row * 136 + q * 32 + quad * 8);
      al[rt] = *(const short8*)(sAlo + row * 136 + q * 32 + quad * 8);
    }
#pragma unroll
    for (int ct = 0; ct < 4; ++ct) {
      int n = wc * 64 + ct * 16 + m;
      short8 bhC = *(const short8*)(WhiC + n * H + q * 32 + quad * 8);
      short8 blC = *(const short8*)(WloC + n * H + q * 32 + quad * 8);
      short8 bhR = *(const short8*)(WhiR + n * H + q * 32 + quad * 8);
      short8 blR = *(const short8*)(WloR + n * H + q * 32 + quad * 8);
#pragma unroll
      for (int rt = 0; rt < 2; ++rt) {
        accC[rt][ct] = __builtin_amdgcn_mfma_f32_16x16x32_bf16(ah[rt], bhC, accC[rt][ct], 0, 0, 0);
        accC[rt][ct] = __builtin_amdgcn_mfma_f32_16x16x32_bf16(al[rt], bhC, accC[rt][ct], 0, 0, 0);
        accC[rt][ct] = __builtin_amdgcn_mfma_f32_16x16x32_bf16(ah[rt], blC, accC[rt][ct], 0, 0, 0);
        accR[rt][ct] = __builtin_amdgcn_mfma_f32_16x16x32_bf16(ah[rt], bhR, accR[rt][ct], 0, 0, 0);
        accR[rt][ct] = __builtin_amdgcn_mfma_f32_16x16x32_bf16(al[rt], bhR, accR[rt][ct], 0, 0, 0);
        accR[rt][ct] = __builtin_amdgcn_mfma_f32_16x16x32_bf16(ah[rt], blR, accR[rt][ct], 0, 0, 0);
      }
    }
  }
#pragma unroll
  for (int rt = 0; rt < 2; ++rt)
#pragma unroll
    for (int ct = 0; ct < 4; ++ct) {
      int col = wc * 64 + ct * 16 + m;
      float bv = biasR[col];
#pragma unroll
      for (int r = 0; r < 4; ++r) {
        int gn = n0 + wr * 32 + rt * 16 + quad * 4 + r;
        if (gn < N_NODES) {
          htb[(size_t)gn * H + col] = f2bf(accC[rt][ct][r]);
          Cres[(size_t)gn * H + col] = accR[rt][ct][r] + bv;
        }
      }
    }
}

// ---------------- aggregate + bias + LN + relu + residual ----------------
// wave/node; 4 groups x 16 lanes; lane owns 8 feats (uint4 = 8 bf16);
// each group processes a different edge per iteration (ds_bpermute broadcast).
__global__ __launch_bounds__(256) void k_agg(
    const unsigned short* __restrict__ htb, const float* __restrict__ res,
    const float* __restrict__ dinv, const int* __restrict__ offs,
    const int* __restrict__ deg, const int2* __restrict__ csr,
    const float* __restrict__ bias, const float* __restrict__ lng,
    const float* __restrict__ lnb, float* __restrict__ hout) {
  int wid = threadIdx.x >> 6, lane = threadIdx.x & 63;
  int node = blockIdx.x * 4 + wid;
  if (node >= N_NODES) return;
  int grp = lane >> 4, fl = lane & 15;
  int start = offs[node], cnt = deg[node];
  float di = dinv[node];
  const char* hb = (const char*)htb + fl * 16;
  float acc[8];
  {
    uint4 u = *(const uint4*)(hb + (size_t)node * 256);
    float sw = (grp == 0) ? di * di : 0.f;  // count self-loop once
    acc[0] = sw * bflo(u.x); acc[1] = sw * bfhi(u.x);
    acc[2] = sw * bflo(u.y); acc[3] = sw * bfhi(u.y);
    acc[4] = sw * bflo(u.z); acc[5] = sw * bfhi(u.z);
    acc[6] = sw * bflo(u.w); acc[7] = sw * bfhi(u.w);
  }
  for (int b0 = 0; b0 < cnt; b0 += 64) {
    int mm_ = min(64, cnt - b0);
    int s = 0; float w = 0.f;
    if (lane < mm_) {
      int2 ev = csr[start + b0 + lane];
      s = ev.x; w = __int_as_float(ev.y);
    }
#pragma unroll 2
    for (int e = 0; e < mm_; e += 4) {
      int ss = __shfl(s, e + grp, 64);
      float we = __shfl(w, e + grp, 64);
      uint4 u = *(const uint4*)(hb + (size_t)ss * 256);
      acc[0] = fmaf(we, bflo(u.x), acc[0]);
      acc[1] = fmaf(we, bfhi(u.x), acc[1]);
      acc[2] = fmaf(we, bflo(u.y), acc[2]);
      acc[3] = fmaf(we, bfhi(u.y), acc[3]);
      acc[4] = fmaf(we, bflo(u.z), acc[4]);
      acc[5] = fmaf(we, bfhi(u.z), acc[5]);
      acc[6] = fmaf(we, bflo(u.w), acc[6]);
      acc[7] = fmaf(we, bfhi(u.w), acc[7]);
    }
  }
  // merge the 4 groups (lanes with equal fl hold same feature slice)
#pragma unroll
  for (int j = 0; j < 8; ++j) {
    acc[j] += __shfl_xor(acc[j], 16, 64);
    acc[j] += __shfl_xor(acc[j], 32, 64);
  }
  float4 b0v = *(const float4*)(bias + fl * 8);
  float4 b1v = *(const float4*)(bias + fl * 8 + 4);
  acc[0] += b0v.x; acc[1] += b0v.y; acc[2] += b0v.z; acc[3] += b0v.w;
  acc[4] += b1v.x; acc[5] += b1v.y; acc[6] += b1v.z; acc[7] += b1v.w;
  float sl = ((acc[0] + acc[1]) + (acc[2] + acc[3])) +
             ((acc[4] + acc[5]) + (acc[6] + acc[7]));
#pragma unroll
  for (int mk = 1; mk <= 8; mk <<= 1) sl += __shfl_xor(sl, mk, 64);
  float mu = sl * (1.f / 128.f);
  float d[8];
  float vl = 0.f;
#pragma unroll
  for (int j = 0; j < 8; ++j) { d[j] = acc[j] - mu; vl = fmaf(d[j], d[j], vl); }
#pragma unroll
  for (int mk = 1; mk <= 8; mk <<= 1) vl += __shfl_xor(vl, mk, 64);
  float rs = rsqrtf(vl * (1.f / 128.f) + EPS);
  if (grp == 0) {
    float4 g0 = *(const float4*)(lng + fl * 8);
    float4 g1 = *(const float4*)(lng + fl * 8 + 4);
    float4 be0 = *(const float4*)(lnb + fl * 8);
    float4 be1 = *(const float4*)(lnb + fl * 8 + 4);
    float4 r0 = *(const float4*)(res + (size_t)node * 128 + fl * 8);
    float4 r1 = *(const float4*)(res + (size_t)node * 128 + fl * 8 + 4);
    float4 o0, o1;
    o0.x = fmaxf(fmaf(d[0] * rs, g0.x, be0.x), 0.f) + r0.x;
    o0.y = fmaxf(fmaf(d[1] * rs, g0.y, be0.y), 0.f) + r0.y;
    o0.z = fmaxf(fmaf(d[2] * rs, g0.z, be0.z), 0.f) + r0.z;
    o0.w = fmaxf(fmaf(d[3] * rs, g0.w, be0.w), 0.f) + r0.w;
    o1.x = fmaxf(fmaf(d[4] * rs, g1.x, be1.x), 0.f) + r1.x;
    o1.y = fmaxf(fmaf(d[5] * rs, g1.y, be1.y), 0.f) + r1.y;
    o1.z = fmaxf(fmaf(d[6] * rs, g1.z, be1.z), 0.f) + r1.z;
    o1.w = fmaxf(fmaf(d[7] * rs, g1.w, be1.w), 0.f) + r1.w;
    *(float4*)(hout + (size_t)node * 128 + fl * 8) = o0;
    *(float4*)(hout + (size_t)node * 128 + fl * 8 + 4) = o1;
  }
}

// ---------------- mean pool ----------------
__global__ void k_pool(const float* __restrict__ h, float* __restrict__ pool) {
  int f = threadIdx.x;  // 128
  float acc = 0.f;
  for (int n = blockIdx.x; n < N_NODES; n += gridDim.x)
    acc += h[(size_t)n * H + f];
  atomicAdd(&pool[f], acc);
}

// ---------------- head ----------------
__global__ void k_head(const float* __restrict__ pool, const float* __restrict__ Wfc1,
                       const float* __restrict__ bfc1, const float* __restrict__ g,
                       const float* __restrict__ bb, const float* __restrict__ Wfc2,
                       const float* __restrict__ bfc2, float* __restrict__ out) {
  __shared__ float sm[128], s1[128], stats[2];
  int t = threadIdx.x;
  if (t < 128) sm[t] = pool[t] * (1.f / (float)N_NODES);
  __syncthreads();
  if (t < 128) {
    float a = bfc1[t];
    for (int k = 0; k < 128; ++k) a = fmaf(sm[k], Wfc1[k * 128 + t], a);
    s1[t] = a;
  }
  __syncthreads();
  if (t == 0) {
    float mu = 0.f;
    for (int k = 0; k < 128; ++k) mu += s1[k];
    mu *= (1.f / 128.f);
    float var = 0.f;
    for (int k = 0; k < 128; ++k) { float d = s1[k] - mu; var += d * d; }
    var *= (1.f / 128.f);
    stats[0] = mu; stats[1] = rsqrtf(var + EPS);
  }
  __syncthreads();
  if (t < 128) s1[t] = fmaxf((s1[t] - stats[0]) * stats[1] * g[t] + bb[t], 0.f);
  __syncthreads();
  if (t < OUT_F) {
    float a = bfc2[t];
    for (int k = 0; k < 128; ++k) a = fmaf(s1[k], Wfc2[k * OUT_F + t], a);
    out[t] = a;
  }
}

extern "C" void kernel_launch(void* const* d_in, const int* in_sizes, int n_in,
                              void* d_out, int out_size, void* d_ws, size_t ws_size,
                              hipStream_t stream) {
  const float* x      = (const float*)d_in[0];
  const int*   ei     = (const int*)d_in[1];
  const float* W_emb  = (const float*)d_in[2];
  const float* b_emb  = (const float*)d_in[3];
  const float* W_conv = (const float*)d_in[4];
  const float* b_conv = (const float*)d_in[5];
  const float* ln_g   = (const float*)d_in[6];
  const float* ln_b   = (const float*)d_in[7];
  const float* W_res  = (const float*)d_in[8];
  const float* b_res  = (const float*)d_in[9];
  const float* W_fc1  = (const float*)d_in[10];
  const float* b_fc1  = (const float*)d_in[11];
  const float* fcn_g  = (const float*)d_in[12];
  const float* fcn_b  = (const float*)d_in[13];
  const float* W_fc2  = (const float*)d_in[14];
  const float* b_fc2  = (const float*)d_in[15];
  float* out = (float*)d_out;

  char* p = (char*)d_ws;
  auto take = [&](size_t bytes) {
    char* r = p; p += (bytes + 255) & ~(size_t)255; return r;
  };
  float*          bufA = (float*)take((size_t)N_NODES * H * 4);
  float*          bufB = (float*)take((size_t)N_NODES * H * 4);
  float*          bufC = (float*)take((size_t)N_NODES * H * 4);
  unsigned short* htb  = (unsigned short*)take((size_t)N_NODES * H * 2);
  unsigned short* whiT = (unsigned short*)take((size_t)5 * H * H * 2);
  unsigned short* wloT = (unsigned short*)take((size_t)5 * H * H * 2);
  int*   deg  = (int*)take(N_NODES * 4);
  int*   offs = (int*)take(N_NODES * 4);
  int*   work = (int*)take(N_NODES * 4);
  int*   parts= (int*)take(512 * 4);
  float* dinv = (float*)take(N_NODES * 4);
  int2*  csr  = (int2*)take((size_t)NEDGES * 8);
  float* pool = (float*)take(128 * 4);

  hipMemsetAsync(deg, 0, N_NODES * 4, stream);
  hipMemsetAsync(pool, 0, 128 * 4, stream);

  int nparts = (N_NODES + 255) / 256;
  int eg4 = (NEDGES / 4 + 255) / 256;
  k_hist<<<eg4, 256, 0, stream>>>(ei, deg);
  k_scan_a<<<nparts, 256, 0, stream>>>(deg, offs, parts, dinv);
  k_scan_b<<<1, 512, 0, stream>>>(parts, nparts);
  k_scan_c<<<nparts, 256, 0, stream>>>(offs, parts, work);
  k_fill<<<eg4, 256, 0, stream>>>(ei, dinv, work, csr);
  k_wsplit<<<(5 * H * H + 255) / 256, 256, 0, stream>>>(W_conv, W_res, whiT, wloT);
  k_embed<<<(N_NODES + 31) / 32, 256, 0, stream>>>(x, W_emb, b_emb, bufA);

  int mmg = (N_NODES + 63) / 64;
  int aggg = (N_NODES + 3) / 4;
  // L0: h0=A -> htb -> h1=C (res=A)
  k_mm<<<mmg, 256, 0, stream>>>(bufA, whiT + 0 * H * H, wloT + 0 * H * H, htb);
  k_agg<<<aggg, 256, 0, stream>>>(htb, bufA, dinv, offs, deg, csr,
                                  b_conv + 0 * H, ln_g + 0 * H, ln_b + 0 * H, bufC);
  // L1: h1=C -> htb -> h2=A (res=C)
  k_mm<<<mmg, 256, 0, stream>>>(bufC, whiT + 1 * H * H, wloT + 1 * H * H, htb);
  k_agg<<<aggg, 256, 0, stream>>>(htb, bufC, dinv, offs, deg, csr,
                                  b_conv + 1 * H, ln_g + 1 * H, ln_b + 1 * H, bufA);
  // L2: h2=A; fused: htb=A@W2, Bres=A@Wres+bres; agg -> h3=C (res=B)
  k_mm2<<<mmg, 256, 0, stream>>>(bufA, whiT + 2 * H * H, wloT + 2 * H * H,
                                 whiT + 4 * H * H, wloT + 4 * H * H, b_res, htb, bufB);
  k_agg<<<aggg, 256, 0, stream>>>(htb, bufB, dinv, offs, deg, csr,
                                  b_conv + 2 * H, ln_g + 2 * H, ln_b + 2 * H, bufC);
  // L3: h3=C -> htb -> h4=A (res=C)
  k_mm<<<mmg, 256, 0, stream>>>(bufC, whiT + 3 * H * H, wloT + 3 * H * H, htb);
  k_agg<<<aggg, 256, 0, stream>>>(htb, bufC, dinv, offs, deg, csr,
                                  b_conv + 3 * H, ln_g + 3 * H, ln_b + 3 * H, bufA);

  k_pool<<<512, 128, 0, stream>>>(bufA, pool);
  k_head<<<1, 256, 0, stream>>>(pool, W_fc1, b_fc1, fcn_g, fcn_b,
                                W_fc2, b_fc2, out);
}

// Round 4
// 799.476 us; speedup vs baseline: 1.5171x; 1.1436x over previous
//
#include <hip/hip_runtime.h>

constexpr int N_NODES = 100000;
constexpr int F_IN    = 32;
constexpr int H       = 128;
constexpr int OUT_F   = 200;
constexpr int NEDGES  = 1600000;
constexpr float EPS   = 1e-5f;

constexpr int EMB_BLKS  = (N_NODES + 31) / 32;        // 3125
constexpr int HIST_BLKS = (NEDGES / 4 + 255) / 256;   // 1563
constexpr int WS_BLKS   = 80;                         // 5*128*128 / 1024
constexpr int FILL_BLKS = (NEDGES / 4 + 255) / 256;   // 1563
constexpr int MM_BLKS   = (N_NODES + 63) / 64;        // 1563

typedef __attribute__((ext_vector_type(8))) short  short8;
typedef __attribute__((ext_vector_type(4))) float  f32x4;
typedef __attribute__((ext_vector_type(4))) unsigned short us4;

__device__ __forceinline__ void fma4(float4& a, float s, const float4& w) {
  a.x = fmaf(s, w.x, a.x); a.y = fmaf(s, w.y, a.y);
  a.z = fmaf(s, w.z, a.z); a.w = fmaf(s, w.w, a.w);
}

__device__ __forceinline__ unsigned short f2bf(float f) {  // RNE
  union { float f; unsigned u; } v; v.f = f;
  unsigned r = v.u + 0x7fffu + ((v.u >> 16) & 1u);
  return (unsigned short)(r >> 16);
}
__device__ __forceinline__ float bf2f(unsigned short s) {
  union { unsigned u; float f; } v; v.u = ((unsigned)s) << 16;
  return v.f;
}
__device__ __forceinline__ float bflo(unsigned u) { return __uint_as_float(u << 16); }
__device__ __forceinline__ float bfhi(unsigned u) { return __uint_as_float(u & 0xffff0000u); }

// ---------------- fused pre: embed | hist(+rank) | wsplit ----------------
__global__ __launch_bounds__(256) void k_pre(
    const float* __restrict__ x, const float* __restrict__ W_emb,
    const float* __restrict__ b_emb, float* __restrict__ h,
    const int* __restrict__ ei, int* __restrict__ deg,
    unsigned char* __restrict__ ranks,
    const float* __restrict__ W_conv, const float* __restrict__ W_res,
    unsigned short* __restrict__ whiT, unsigned short* __restrict__ wloT) {
  __shared__ __align__(16) float smem[F_IN * H + 32 * 36];
  int t = threadIdx.x;
  if (blockIdx.x < EMB_BLKS) {
    // ---- embed: 32 nodes/block ----
    float* sW = smem;
    float* sX = smem + F_IN * H;
#pragma unroll
    for (int p = 0; p < 4; ++p) {
      int fi = t + p * 256;
      ((float4*)sW)[fi] = ((const float4*)W_emb)[fi];
    }
    int n0 = blockIdx.x * 32;
    {
      int row = t >> 3, k4 = (t & 7) * 4;
      int gn = n0 + row; if (gn >= N_NODES) gn = N_NODES - 1;
      *(float4*)(sX + row * 36 + k4) = *(const float4*)(x + (size_t)gn * F_IN + k4);
    }
    __syncthreads();
    int lane32 = t & 31, quad = t >> 5;
    int c = lane32 * 4, nb = quad * 4;
    float4 acc[4] = {make_float4(0,0,0,0), make_float4(0,0,0,0),
                     make_float4(0,0,0,0), make_float4(0,0,0,0)};
#pragma unroll
    for (int kk = 0; kk < F_IN; kk += 4) {
      float4 w0 = *(const float4*)(sW + (kk + 0) * H + c);
      float4 w1 = *(const float4*)(sW + (kk + 1) * H + c);
      float4 w2 = *(const float4*)(sW + (kk + 2) * H + c);
      float4 w3 = *(const float4*)(sW + (kk + 3) * H + c);
#pragma unroll
      for (int i = 0; i < 4; ++i) {
        float4 hv = *(const float4*)(sX + (nb + i) * 36 + kk);
        fma4(acc[i], hv.x, w0); fma4(acc[i], hv.y, w1);
        fma4(acc[i], hv.z, w2); fma4(acc[i], hv.w, w3);
      }
    }
    float4 bv = *(const float4*)(b_emb + c);
#pragma unroll
    for (int i = 0; i < 4; ++i) {
      int n = n0 + nb + i;
      if (n < N_NODES) {
        float4 o = acc[i];
        o.x += bv.x; o.y += bv.y; o.z += bv.z; o.w += bv.w;
        *(float4*)(h + (size_t)n * H + c) = o;
      }
    }
  } else if (blockIdx.x < EMB_BLKS + HIST_BLKS) {
    // ---- hist + rank capture: 4 edges/thread ----
    int i = (blockIdx.x - EMB_BLKS) * 256 + t;
    if (i < NEDGES / 4) {
      int4 d4 = *(const int4*)(ei + NEDGES + 4 * i);
      uchar4 r;
      r.x = (unsigned char)atomicAdd(&deg[d4.x], 1);
      r.y = (unsigned char)atomicAdd(&deg[d4.y], 1);
      r.z = (unsigned char)atomicAdd(&deg[d4.z], 1);
      r.w = (unsigned char)atomicAdd(&deg[d4.w], 1);
      ((uchar4*)ranks)[i] = r;
    }
  } else {
    // ---- W split: WhiT/WloT[mat][n][k] bf16 ----
    int base = (blockIdx.x - EMB_BLKS - HIST_BLKS) * 1024;
#pragma unroll
    for (int j = 0; j < 4; ++j) {
      int idx = base + j * 256 + t;
      if (idx < 5 * H * H) {
        int m = idx >> 14, rr = idx & 16383;
        int k = rr >> 7, n = rr & 127;
        const float* src = (m < 4) ? (W_conv + m * H * H) : W_res;
        float w = src[k * H + n];
        unsigned short hi = f2bf(w);
        unsigned short lo = f2bf(w - bf2f(hi));
        whiT[m * H * H + n * H + k] = hi;
        wloT[m * H * H + n * H + k] = lo;
      }
    }
  }
}

// ---------------- scans ----------------
__global__ void k_scan_a(const int* __restrict__ deg, int* __restrict__ offs,
                         int* __restrict__ parts, float* __restrict__ dinv) {
  __shared__ int s[256];
  int i = blockIdx.x * 256 + threadIdx.x;
  int d = (i < N_NODES) ? deg[i] : 0;
  s[threadIdx.x] = d;
  __syncthreads();
#pragma unroll
  for (int off = 1; off < 256; off <<= 1) {
    int v = (threadIdx.x >= off) ? s[threadIdx.x - off] : 0;
    __syncthreads();
    s[threadIdx.x] += v;
    __syncthreads();
  }
  if (i < N_NODES) {
    offs[i] = s[threadIdx.x] - d;
    dinv[i] = rsqrtf((float)(d + 1));  // +1 self-loop
  }
  if (threadIdx.x == 255) parts[blockIdx.x] = s[255];
}

__global__ void k_scan_b(int* __restrict__ parts, int nparts) {
  __shared__ int s[512];
  int t = threadIdx.x;
  int d = (t < nparts) ? parts[t] : 0;
  s[t] = d;
  __syncthreads();
#pragma unroll
  for (int off = 1; off < 512; off <<= 1) {
    int v = (t >= off) ? s[t - off] : 0;
    __syncthreads();
    s[t] += v;
    __syncthreads();
  }
  if (t < nparts) parts[t] = s[t] - d;
}

__global__ void k_scan_c(int* __restrict__ offs, const int* __restrict__ parts) {
  int i = blockIdx.x * 256 + threadIdx.x;
  if (i < N_NODES) offs[i] += parts[blockIdx.x];
}

// ---------------- shared mm body (split-bf16 MFMA, 64-row tile) ----------------
__device__ __forceinline__ void mm_body(const float* __restrict__ A,
                                        const unsigned short* __restrict__ WhiT,
                                        const unsigned short* __restrict__ WloT,
                                        unsigned short* __restrict__ htb,
                                        int n0, int t,
                                        unsigned short* sAhi, unsigned short* sAlo) {
#pragma unroll
  for (int p = 0; p < 8; ++p) {
    int fi = t + p * 256;
    int row = fi >> 5, c4 = (fi & 31) * 4;
    int gn = n0 + row; if (gn >= N_NODES) gn = N_NODES - 1;
    float4 v = *(const float4*)(A + (size_t)gn * H + c4);
    us4 hi, lo;
    hi.x = f2bf(v.x); lo.x = f2bf(v.x - bf2f(hi.x));
    hi.y = f2bf(v.y); lo.y = f2bf(v.y - bf2f(hi.y));
    hi.z = f2bf(v.z); lo.z = f2bf(v.z - bf2f(hi.z));
    hi.w = f2bf(v.w); lo.w = f2bf(v.w - bf2f(hi.w));
    *(us4*)(sAhi + row * 136 + c4) = hi;
    *(us4*)(sAlo + row * 136 + c4) = lo;
  }
  __syncthreads();

  int wave = t >> 6, lane = t & 63;
  int wr = wave >> 1, wc = wave & 1;
  int m = lane & 15, quad = (lane >> 4) & 3;

  f32x4 acc[2][4];
#pragma unroll
  for (int i = 0; i < 2; ++i)
#pragma unroll
    for (int j = 0; j < 4; ++j) acc[i][j] = (f32x4){0.f, 0.f, 0.f, 0.f};

#pragma unroll
  for (int q = 0; q < 4; ++q) {
    short8 bh[4], bl[4];
#pragma unroll
    for (int ct = 0; ct < 4; ++ct) {
      int n = wc * 64 + ct * 16 + m;
      bh[ct] = *(const short8*)(WhiT + n * H + q * 32 + quad * 8);
      bl[ct] = *(const short8*)(WloT + n * H + q * 32 + quad * 8);
    }
    short8 ah[2], al[2];
#pragma unroll
    for (int rt = 0; rt < 2; ++rt) {
      int row = wr * 32 + rt * 16 + m;
      ah[rt] = *(const short8*)(sAhi + row * 136 + q * 32 + quad * 8);
      al[rt] = *(const short8*)(sAlo + row * 136 + q * 32 + quad * 8);
    }
#pragma unroll
    for (int rt = 0; rt < 2; ++rt)
#pragma unroll
      for (int ct = 0; ct < 4; ++ct) {
        acc[rt][ct] = __builtin_amdgcn_mfma_f32_16x16x32_bf16(ah[rt], bh[ct], acc[rt][ct], 0, 0, 0);
        acc[rt][ct] = __builtin_amdgcn_mfma_f32_16x16x32_bf16(al[rt], bh[ct], acc[rt][ct], 0, 0, 0);
        acc[rt][ct] = __builtin_amdgcn_mfma_f32_16x16x32_bf16(ah[rt], bl[ct], acc[rt][ct], 0, 0, 0);
      }
  }
#pragma unroll
  for (int rt = 0; rt < 2; ++rt)
#pragma unroll
    for (int ct = 0; ct < 4; ++ct) {
      int col = wc * 64 + ct * 16 + m;
#pragma unroll
      for (int r = 0; r < 4; ++r) {
        int gn = n0 + wr * 32 + rt * 16 + quad * 4 + r;
        if (gn < N_NODES) htb[(size_t)gn * H + col] = f2bf(acc[rt][ct][r]);
      }
    }
}

// ---------------- fused fill | mm_L0 ----------------
__global__ __launch_bounds__(256) void k_fillmm(
    const int* __restrict__ ei, const unsigned char* __restrict__ ranks,
    const int* __restrict__ offs, const float* __restrict__ dinv,
    int2* __restrict__ csr,
    const float* __restrict__ A, const unsigned short* __restrict__ WhiT,
    const unsigned short* __restrict__ WloT, unsigned short* __restrict__ htb) {
  __shared__ __align__(16) unsigned short sAhi[64 * 136];
  __shared__ __align__(16) unsigned short sAlo[64 * 136];
  int t = threadIdx.x;
  if (blockIdx.x < FILL_BLKS) {
    int i = blockIdx.x * 256 + t;
    if (i < NEDGES / 4) {
      int4 s4 = *(const int4*)(ei + 4 * i);
      int4 d4 = *(const int4*)(ei + NEDGES + 4 * i);
      uchar4 r4 = ((const uchar4*)ranks)[i];
      int p0 = offs[d4.x] + r4.x;
      int p1 = offs[d4.y] + r4.y;
      int p2 = offs[d4.z] + r4.z;
      int p3 = offs[d4.w] + r4.w;
      csr[p0] = make_int2(s4.x, __float_as_int(dinv[s4.x] * dinv[d4.x]));
      csr[p1] = make_int2(s4.y, __float_as_int(dinv[s4.y] * dinv[d4.y]));
      csr[p2] = make_int2(s4.z, __float_as_int(dinv[s4.z] * dinv[d4.z]));
      csr[p3] = make_int2(s4.w, __float_as_int(dinv[s4.w] * dinv[d4.w]));
    }
  } else {
    mm_body(A, WhiT, WloT, htb, (blockIdx.x - FILL_BLKS) * 64, t, sAhi, sAlo);
  }
}

// ---------------- plain mm ----------------
__global__ __launch_bounds__(256) void k_mm(const float* __restrict__ A,
                                            const unsigned short* __restrict__ WhiT,
                                            const unsigned short* __restrict__ WloT,
                                            unsigned short* __restrict__ htb) {
  __shared__ __align__(16) unsigned short sAhi[64 * 136];
  __shared__ __align__(16) unsigned short sAlo[64 * 136];
  mm_body(A, WhiT, WloT, htb, blockIdx.x * 64, threadIdx.x, sAhi, sAlo);
}

// layer-2 fused: htb = bf16(A@Wc), Cres = A@Wr + biasR (shares A staging)
__global__ __launch_bounds__(256) void k_mm2(const float* __restrict__ A,
    const unsigned short* __restrict__ WhiC, const unsigned short* __restrict__ WloC,
    const unsigned short* __restrict__ WhiR, const unsigned short* __restrict__ WloR,
    const float* __restrict__ biasR,
    unsigned short* __restrict__ htb, float* __restrict__ Cres) {
  __shared__ __align__(16) unsigned short sAhi[64 * 136];
  __shared__ __align__(16) unsigned short sAlo[64 * 136];
  int t = threadIdx.x;
  int n0 = blockIdx.x * 64;
#pragma unroll
  for (int p = 0; p < 8; ++p) {
    int fi = t + p * 256;
    int row = fi >> 5, c4 = (fi & 31) * 4;
    int gn = n0 + row; if (gn >= N_NODES) gn = N_NODES - 1;
    float4 v = *(const float4*)(A + (size_t)gn * H + c4);
    us4 hi, lo;
    hi.x = f2bf(v.x); lo.x = f2bf(v.x - bf2f(hi.x));
    hi.y = f2bf(v.y); lo.y = f2bf(v.y - bf2f(hi.y));
    hi.z = f2bf(v.z); lo.z = f2bf(v.z - bf2f(hi.z));
    hi.w = f2bf(v.w); lo.w = f2bf(v.w - bf2f(hi.w));
    *(us4*)(sAhi + row * 136 + c4) = hi;
    *(us4*)(sAlo + row * 136 + c4) = lo;
  }
  __syncthreads();

  int wave = t >> 6, lane = t & 63;
  int wr = wave >> 1, wc = wave & 1;
  int m = lane & 15, quad = (lane >> 4) & 3;

  f32x4 accC[2][4], accR[2][4];
#pragma unroll
  for (int i = 0; i < 2; ++i)
#pragma unroll
    for (int j = 0; j < 4; ++j) {
      accC[i][j] = (f32x4){0.f, 0.f, 0.f, 0.f};
      accR[i][j] = (f32x4){0.f, 0.f, 0.f, 0.f};
    }

#pragma unroll
  for (int q = 0; q < 4; ++q) {
    short8 ah[2], al[2];
#pragma unroll
    for (int rt = 0; rt < 2; ++rt) {
      int row = wr * 32 + rt * 16 + m;
      ah[rt] = *(const short8*)(sAhi + row * 136 + q * 32 + quad * 8);
      al[rt] = *(const short8*)(sAlo + row * 136 + q * 32 + quad * 8);
    }
#pragma unroll
    for (int ct = 0; ct < 4; ++ct) {
      int n = wc * 64 + ct * 16 + m;
      short8 bhC = *(const short8*)(WhiC + n * H + q * 32 + quad * 8);
      short8 blC = *(const short8*)(WloC + n * H + q * 32 + quad * 8);
      short8 bhR = *(const short8*)(WhiR + n * H + q * 32 + quad * 8);
      short8 blR = *(const short8*)(WloR + n * H + q * 32 + quad * 8);
#pragma unroll
      for (int rt = 0; rt < 2; ++rt) {
        accC[rt][ct] = __builtin_amdgcn_mfma_f32_16x16x32_bf16(ah[rt], bhC, accC[rt][ct], 0, 0, 0);
        accC[rt][ct] = __builtin_amdgcn_mfma_f32_16x16x32_bf16(al[rt], bhC, accC[rt][ct], 0, 0, 0);
        accC[rt][ct] = __builtin_amdgcn_mfma_f32_16x16x32_bf16(ah[rt], blC, accC[rt][ct], 0, 0, 0);
        accR[rt][ct] = __builtin_amdgcn_mfma_f32_16x16x32_bf16(ah[rt], bhR, accR[rt][ct], 0, 0, 0);
        accR[rt][ct] = __builtin_amdgcn_mfma_f32_16x16x32_bf16(al[rt], bhR, accR[rt][ct], 0, 0, 0);
        accR[rt][ct] = __builtin_amdgcn_mfma_f32_16x16x32_bf16(ah[rt], blR, accR[rt][ct], 0, 0, 0);
      }
    }
  }
#pragma unroll
  for (int rt = 0; rt < 2; ++rt)
#pragma unroll
    for (int ct = 0; ct < 4; ++ct) {
      int col = wc * 64 + ct * 16 + m;
      float bv = biasR[col];
#pragma unroll
      for (int r = 0; r < 4; ++r) {
        int gn = n0 + wr * 32 + rt * 16 + quad * 4 + r;
        if (gn < N_NODES) {
          htb[(size_t)gn * H + col] = f2bf(accC[rt][ct][r]);
          Cres[(size_t)gn * H + col] = accR[rt][ct][r] + bv;
        }
      }
    }
}

// ---------------- aggregate + bias + LN + relu + residual ----------------
__global__ __launch_bounds__(256) void k_agg(
    const unsigned short* __restrict__ htb, const float* __restrict__ res,
    const float* __restrict__ dinv, const int* __restrict__ offs,
    const int* __restrict__ deg, const int2* __restrict__ csr,
    const float* __restrict__ bias, const float* __restrict__ lng,
    const float* __restrict__ lnb, float* __restrict__ hout) {
  int wid = threadIdx.x >> 6, lane = threadIdx.x & 63;
  int node = blockIdx.x * 4 + wid;
  if (node >= N_NODES) return;
  int grp = lane >> 4, fl = lane & 15;
  int start = offs[node], cnt = deg[node];
  float di = dinv[node];
  const char* hb = (const char*)htb + fl * 16;
  float acc[8];
  {
    uint4 u = *(const uint4*)(hb + (size_t)node * 256);
    float sw = (grp == 0) ? di * di : 0.f;  // count self-loop once
    acc[0] = sw * bflo(u.x); acc[1] = sw * bfhi(u.x);
    acc[2] = sw * bflo(u.y); acc[3] = sw * bfhi(u.y);
    acc[4] = sw * bflo(u.z); acc[5] = sw * bfhi(u.z);
    acc[6] = sw * bflo(u.w); acc[7] = sw * bfhi(u.w);
  }
  for (int b0 = 0; b0 < cnt; b0 += 64) {
    int mm_ = min(64, cnt - b0);
    int s = 0; float w = 0.f;
    if (lane < mm_) {
      int2 ev = csr[start + b0 + lane];
      s = ev.x; w = __int_as_float(ev.y);
    }
#pragma unroll 2
    for (int e = 0; e < mm_; e += 4) {
      int ss = __shfl(s, e + grp, 64);
      float we = __shfl(w, e + grp, 64);
      uint4 u = *(const uint4*)(hb + (size_t)ss * 256);
      acc[0] = fmaf(we, bflo(u.x), acc[0]);
      acc[1] = fmaf(we, bfhi(u.x), acc[1]);
      acc[2] = fmaf(we, bflo(u.y), acc[2]);
      acc[3] = fmaf(we, bfhi(u.y), acc[3]);
      acc[4] = fmaf(we, bflo(u.z), acc[4]);
      acc[5] = fmaf(we, bfhi(u.z), acc[5]);
      acc[6] = fmaf(we, bflo(u.w), acc[6]);
      acc[7] = fmaf(we, bfhi(u.w), acc[7]);
    }
  }
#pragma unroll
  for (int j = 0; j < 8; ++j) {
    acc[j] += __shfl_xor(acc[j], 16, 64);
    acc[j] += __shfl_xor(acc[j], 32, 64);
  }
  float4 b0v = *(const float4*)(bias + fl * 8);
  float4 b1v = *(const float4*)(bias + fl * 8 + 4);
  acc[0] += b0v.x; acc[1] += b0v.y; acc[2] += b0v.z; acc[3] += b0v.w;
  acc[4] += b1v.x; acc[5] += b1v.y; acc[6] += b1v.z; acc[7] += b1v.w;
  float sl = ((acc[0] + acc[1]) + (acc[2] + acc[3])) +
             ((acc[4] + acc[5]) + (acc[6] + acc[7]));
#pragma unroll
  for (int mk = 1; mk <= 8; mk <<= 1) sl += __shfl_xor(sl, mk, 64);
  float mu = sl * (1.f / 128.f);
  float d[8];
  float vl = 0.f;
#pragma unroll
  for (int j = 0; j < 8; ++j) { d[j] = acc[j] - mu; vl = fmaf(d[j], d[j], vl); }
#pragma unroll
  for (int mk = 1; mk <= 8; mk <<= 1) vl += __shfl_xor(vl, mk, 64);
  float rs = rsqrtf(vl * (1.f / 128.f) + EPS);
  if (grp == 0) {
    float4 g0 = *(const float4*)(lng + fl * 8);
    float4 g1 = *(const float4*)(lng + fl * 8 + 4);
    float4 be0 = *(const float4*)(lnb + fl * 8);
    float4 be1 = *(const float4*)(lnb + fl * 8 + 4);
    float4 r0 = *(const float4*)(res + (size_t)node * 128 + fl * 8);
    float4 r1 = *(const float4*)(res + (size_t)node * 128 + fl * 8 + 4);
    float4 o0, o1;
    o0.x = fmaxf(fmaf(d[0] * rs, g0.x, be0.x), 0.f) + r0.x;
    o0.y = fmaxf(fmaf(d[1] * rs, g0.y, be0.y), 0.f) + r0.y;
    o0.z = fmaxf(fmaf(d[2] * rs, g0.z, be0.z), 0.f) + r0.z;
    o0.w = fmaxf(fmaf(d[3] * rs, g0.w, be0.w), 0.f) + r0.w;
    o1.x = fmaxf(fmaf(d[4] * rs, g1.x, be1.x), 0.f) + r1.x;
    o1.y = fmaxf(fmaf(d[5] * rs, g1.y, be1.y), 0.f) + r1.y;
    o1.z = fmaxf(fmaf(d[6] * rs, g1.z, be1.z), 0.f) + r1.z;
    o1.w = fmaxf(fmaf(d[7] * rs, g1.w, be1.w), 0.f) + r1.w;
    *(float4*)(hout + (size_t)node * 128 + fl * 8) = o0;
    *(float4*)(hout + (size_t)node * 128 + fl * 8 + 4) = o1;
  }
}

// ---------------- mean pool ----------------
__global__ void k_pool(const float* __restrict__ h, float* __restrict__ pool) {
  int f = threadIdx.x;  // 128
  float acc = 0.f;
  for (int n = blockIdx.x; n < N_NODES; n += gridDim.x)
    acc += h[(size_t)n * H + f];
  atomicAdd(&pool[f], acc);
}

// ---------------- head ----------------
__global__ void k_head(const float* __restrict__ pool, const float* __restrict__ Wfc1,
                       const float* __restrict__ bfc1, const float* __restrict__ g,
                       const float* __restrict__ bb, const float* __restrict__ Wfc2,
                       const float* __restrict__ bfc2, float* __restrict__ out) {
  __shared__ float sm[128], s1[128], stats[2];
  int t = threadIdx.x;
  if (t < 128) sm[t] = pool[t] * (1.f / (float)N_NODES);
  __syncthreads();
  if (t < 128) {
    float a = bfc1[t];
    for (int k = 0; k < 128; ++k) a = fmaf(sm[k], Wfc1[k * 128 + t], a);
    s1[t] = a;
  }
  __syncthreads();
  if (t == 0) {
    float mu = 0.f;
    for (int k = 0; k < 128; ++k) mu += s1[k];
    mu *= (1.f / 128.f);
    float var = 0.f;
    for (int k = 0; k < 128; ++k) { float d = s1[k] - mu; var += d * d; }
    var *= (1.f / 128.f);
    stats[0] = mu; stats[1] = rsqrtf(var + EPS);
  }
  __syncthreads();
  if (t < 128) s1[t] = fmaxf((s1[t] - stats[0]) * stats[1] * g[t] + bb[t], 0.f);
  __syncthreads();
  if (t < OUT_F) {
    float a = bfc2[t];
    for (int k = 0; k < 128; ++k) a = fmaf(s1[k], Wfc2[k * OUT_F + t], a);
    out[t] = a;
  }
}

extern "C" void kernel_launch(void* const* d_in, const int* in_sizes, int n_in,
                              void* d_out, int out_size, void* d_ws, size_t ws_size,
                              hipStream_t stream) {
  const float* x      = (const float*)d_in[0];
  const int*   ei     = (const int*)d_in[1];
  const float* W_emb  = (const float*)d_in[2];
  const float* b_emb  = (const float*)d_in[3];
  const float* W_conv = (const float*)d_in[4];
  const float* b_conv = (const float*)d_in[5];
  const float* ln_g   = (const float*)d_in[6];
  const float* ln_b   = (const float*)d_in[7];
  const float* W_res  = (const float*)d_in[8];
  const float* b_res  = (const float*)d_in[9];
  const float* W_fc1  = (const float*)d_in[10];
  const float* b_fc1  = (const float*)d_in[11];
  const float* fcn_g  = (const float*)d_in[12];
  const float* fcn_b  = (const float*)d_in[13];
  const float* W_fc2  = (const float*)d_in[14];
  const float* b_fc2  = (const float*)d_in[15];
  float* out = (float*)d_out;

  char* p = (char*)d_ws;
  auto take = [&](size_t bytes) {
    char* r = p; p += (bytes + 255) & ~(size_t)255; return r;
  };
  float*          bufA = (float*)take((size_t)N_NODES * H * 4);
  float*          bufB = (float*)take((size_t)N_NODES * H * 4);
  float*          bufC = (float*)take((size_t)N_NODES * H * 4);
  unsigned short* htb  = (unsigned short*)take((size_t)N_NODES * H * 2);
  unsigned short* whiT = (unsigned short*)take((size_t)5 * H * H * 2);
  unsigned short* wloT = (unsigned short*)take((size_t)5 * H * H * 2);
  int*   deg  = (int*)take(N_NODES * 4);
  int*   offs = (int*)take(N_NODES * 4);
  int*   parts= (int*)take(512 * 4);
  float* dinv = (float*)take(N_NODES * 4);
  unsigned char* ranks = (unsigned char*)take(NEDGES);
  int2*  csr  = (int2*)take((size_t)NEDGES * 8);
  float* pool = (float*)take(128 * 4);

  hipMemsetAsync(deg, 0, N_NODES * 4, stream);
  hipMemsetAsync(pool, 0, 128 * 4, stream);

  int nparts = (N_NODES + 255) / 256;
  k_pre<<<EMB_BLKS + HIST_BLKS + WS_BLKS, 256, 0, stream>>>(
      x, W_emb, b_emb, bufA, ei, deg, ranks, W_conv, W_res, whiT, wloT);
  k_scan_a<<<nparts, 256, 0, stream>>>(deg, offs, parts, dinv);
  k_scan_b<<<1, 512, 0, stream>>>(parts, nparts);
  k_scan_c<<<nparts, 256, 0, stream>>>(offs, parts);
  // fill + mm_L0 fused
  k_fillmm<<<FILL_BLKS + MM_BLKS, 256, 0, stream>>>(
      ei, ranks, offs, dinv, csr, bufA, whiT + 0 * H * H, wloT + 0 * H * H, htb);

  int aggg = (N_NODES + 3) / 4;
  // L0: res=A -> h1=C
  k_agg<<<aggg, 256, 0, stream>>>(htb, bufA, dinv, offs, deg, csr,
                                  b_conv + 0 * H, ln_g + 0 * H, ln_b + 0 * H, bufC);
  // L1: h1=C -> htb -> h2=A (res=C)
  k_mm<<<MM_BLKS, 256, 0, stream>>>(bufC, whiT + 1 * H * H, wloT + 1 * H * H, htb);
  k_agg<<<aggg, 256, 0, stream>>>(htb, bufC, dinv, offs, deg, csr,
                                  b_conv + 1 * H, ln_g + 1 * H, ln_b + 1 * H, bufA);
  // L2: h2=A; fused: htb=A@W2, Bres=A@Wres+bres; agg -> h3=C (res=B)
  k_mm2<<<MM_BLKS, 256, 0, stream>>>(bufA, whiT + 2 * H * H, wloT + 2 * H * H,
                                     whiT + 4 * H * H, wloT + 4 * H * H, b_res, htb, bufB);
  k_agg<<<aggg, 256, 0, stream>>>(htb, bufB, dinv, offs, deg, csr,
                                  b_conv + 2 * H, ln_g + 2 * H, ln_b + 2 * H, bufC);
  // L3: h3=C -> htb -> h4=A (res=C)
  k_mm<<<MM_BLKS, 256, 0, stream>>>(bufC, whiT + 3 * H * H, wloT + 3 * H * H, htb);
  k_agg<<<aggg, 256, 0, stream>>>(htb, bufC, dinv, offs, deg, csr,
                                  b_conv + 3 * H, ln_g + 3 * H, ln_b + 3 * H, bufA);

  k_pool<<<512, 128, 0, stream>>>(bufA, pool);
  k_head<<<1, 256, 0, stream>>>(pool, W_fc1, b_fc1, fcn_g, fcn_b,
                                W_fc2, b_fc2, out);
}

// Round 5
// 739.352 us; speedup vs baseline: 1.6405x; 1.0813x over previous
//
#include <hip/hip_runtime.h>

constexpr int N_NODES = 100000;
constexpr int F_IN    = 32;
constexpr int H       = 128;
constexpr int OUT_F   = 200;
constexpr int NEDGES  = 1600000;
constexpr float EPS   = 1e-5f;

constexpr int HIST8_BLKS = (NEDGES / 8 + 255) / 256;  // 782
constexpr int WS_BLKS    = 80;                        // 5*128*128/1024
constexpr int EMB_BLKS   = N_NODES / 32;              // 3125 (exact)
constexpr int NPARTS     = (N_NODES + 255) / 256;     // 391
constexpr int FILL_BLKS  = (NEDGES / 4 + 255) / 256;  // 1563
constexpr int MM_BLKS    = (N_NODES + 63) / 64;       // 1563

typedef __attribute__((ext_vector_type(8))) short  short8;
typedef __attribute__((ext_vector_type(4))) float  f32x4;

__device__ __forceinline__ void fma4(float4& a, float s, const float4& w) {
  a.x = fmaf(s, w.x, a.x); a.y = fmaf(s, w.y, a.y);
  a.z = fmaf(s, w.z, a.z); a.w = fmaf(s, w.w, a.w);
}

__device__ __forceinline__ unsigned short f2bf(float f) {  // RNE
  union { float f; unsigned u; } v; v.f = f;
  unsigned r = v.u + 0x7fffu + ((v.u >> 16) & 1u);
  return (unsigned short)(r >> 16);
}
__device__ __forceinline__ float bf2f(unsigned short s) {
  union { unsigned u; float f; } v; v.u = ((unsigned)s) << 16;
  return v.f;
}
__device__ __forceinline__ float bflo(unsigned u) { return __uint_as_float(u << 16); }
__device__ __forceinline__ float bfhi(unsigned u) { return __uint_as_float(u & 0xffff0000u); }
__device__ __forceinline__ unsigned pack2(float lo, float hi) {
  return (unsigned)f2bf(lo) | ((unsigned)f2bf(hi) << 16);
}
__device__ __forceinline__ void st_bf4(unsigned short* p, float4 v) {
  uint2 o; o.x = pack2(v.x, v.y); o.y = pack2(v.z, v.w);
  *(uint2*)p = o;
}

// ---------------- k_hw: hist(+ranks) | wsplit -- both low-VGPR ----------------
__global__ __launch_bounds__(256) void k_hw(
    const int* __restrict__ ei, int* __restrict__ deg,
    unsigned char* __restrict__ ranks,
    const float* __restrict__ W_conv, const float* __restrict__ W_res,
    unsigned short* __restrict__ whiT, unsigned short* __restrict__ wloT) {
  int t = threadIdx.x;
  if (blockIdx.x < HIST8_BLKS) {
    int i = blockIdx.x * 256 + t;
    if (i < NEDGES / 8) {
      int4 a = *(const int4*)(ei + NEDGES + 8 * i);
      int4 b = *(const int4*)(ei + NEDGES + 8 * i + 4);
      union { unsigned char c[8]; uint2 u; } rr;
      rr.c[0] = (unsigned char)atomicAdd(&deg[a.x], 1);
      rr.c[1] = (unsigned char)atomicAdd(&deg[a.y], 1);
      rr.c[2] = (unsigned char)atomicAdd(&deg[a.z], 1);
      rr.c[3] = (unsigned char)atomicAdd(&deg[a.w], 1);
      rr.c[4] = (unsigned char)atomicAdd(&deg[b.x], 1);
      rr.c[5] = (unsigned char)atomicAdd(&deg[b.y], 1);
      rr.c[6] = (unsigned char)atomicAdd(&deg[b.z], 1);
      rr.c[7] = (unsigned char)atomicAdd(&deg[b.w], 1);
      ((uint2*)ranks)[i] = rr.u;
    }
  } else {
    int base = (blockIdx.x - HIST8_BLKS) * 1024;
#pragma unroll
    for (int j = 0; j < 4; ++j) {
      int idx = base + j * 256 + t;
      if (idx < 5 * H * H) {
        int m = idx >> 14, rr = idx & 16383;
        int k = rr >> 7, n = rr & 127;
        const float* src = (m < 4) ? (W_conv + m * H * H) : W_res;
        float w = src[k * H + n];
        unsigned short hi = f2bf(w);
        unsigned short lo = f2bf(w - bf2f(hi));
        whiT[m * H * H + n * H + k] = hi;
        wloT[m * H * H + n * H + k] = lo;
      }
    }
  }
}

// ---------------- k_embed_scan: embed(bf16 out, low-VGPR) | scan_a ----------------
__global__ __launch_bounds__(256) void k_embed_scan(
    const float* __restrict__ x, const float* __restrict__ W_emb,
    const float* __restrict__ b_emb, unsigned short* __restrict__ h,
    const int* __restrict__ deg, int* __restrict__ offs,
    int* __restrict__ parts, float* __restrict__ dinv) {
  __shared__ __align__(16) float smem[F_IN * H + 32 * 36];
  int t = threadIdx.x;
  if (blockIdx.x < EMB_BLKS) {
    float* sW = smem;
    float* sX = smem + F_IN * H;
#pragma unroll
    for (int p = 0; p < 4; ++p)
      ((float4*)sW)[t + p * 256] = ((const float4*)W_emb)[t + p * 256];
    int n0 = blockIdx.x * 32;
    {
      int row = t >> 3, k4 = (t & 7) * 4;
      *(float4*)(sX + row * 36 + k4) =
          *(const float4*)(x + (size_t)(n0 + row) * F_IN + k4);
    }
    __syncthreads();
    int nr = t >> 3, c = (t & 7) * 4;  // thread: node nr, cols c+{0,32,64,96}
    float4 a0 = make_float4(0,0,0,0), a1 = a0, a2 = a0, a3 = a0;
#pragma unroll 4
    for (int k = 0; k < F_IN; ++k) {
      float xv = sX[nr * 36 + k];
      const float* wp = sW + k * H + c;
      fma4(a0, xv, *(const float4*)(wp));
      fma4(a1, xv, *(const float4*)(wp + 32));
      fma4(a2, xv, *(const float4*)(wp + 64));
      fma4(a3, xv, *(const float4*)(wp + 96));
    }
    float4 b0 = *(const float4*)(b_emb + c);
    float4 b1 = *(const float4*)(b_emb + c + 32);
    float4 b2 = *(const float4*)(b_emb + c + 64);
    float4 b3 = *(const float4*)(b_emb + c + 96);
    a0.x += b0.x; a0.y += b0.y; a0.z += b0.z; a0.w += b0.w;
    a1.x += b1.x; a1.y += b1.y; a1.z += b1.z; a1.w += b1.w;
    a2.x += b2.x; a2.y += b2.y; a2.z += b2.z; a2.w += b2.w;
    a3.x += b3.x; a3.y += b3.y; a3.z += b3.z; a3.w += b3.w;
    unsigned short* hr = h + (size_t)(n0 + nr) * H + c;
    st_bf4(hr, a0); st_bf4(hr + 32, a1);
    st_bf4(hr + 64, a2); st_bf4(hr + 96, a3);
  } else {
    int* s = (int*)smem;
    int i = (blockIdx.x - EMB_BLKS) * 256 + t;
    int d = (i < N_NODES) ? deg[i] : 0;
    s[t] = d;
    __syncthreads();
#pragma unroll
    for (int off = 1; off < 256; off <<= 1) {
      int v = (t >= off) ? s[t - off] : 0;
      __syncthreads();
      s[t] += v;
      __syncthreads();
    }
    if (i < N_NODES) {
      offs[i] = s[t] - d;
      dinv[i] = rsqrtf((float)(d + 1));  // +1 self-loop
    }
    if (t == 255) parts[blockIdx.x - EMB_BLKS] = s[255];
  }
}

__global__ void k_scan_b(int* __restrict__ parts, int nparts) {
  __shared__ int s[512];
  int t = threadIdx.x;
  int d = (t < nparts) ? parts[t] : 0;
  s[t] = d;
  __syncthreads();
#pragma unroll
  for (int off = 1; off < 512; off <<= 1) {
    int v = (t >= off) ? s[t - off] : 0;
    __syncthreads();
    s[t] += v;
    __syncthreads();
  }
  if (t < nparts) parts[t] = s[t] - d;
}

__global__ void k_scan_c(int* __restrict__ offs, const int* __restrict__ parts) {
  int i = blockIdx.x * 256 + threadIdx.x;
  if (i < N_NODES) offs[i] += parts[blockIdx.x];
}

// ---------------- mm body: htb = bf16(A(bf16) @ W), 2-pass split ----------------
__device__ __forceinline__ void mm_body(const unsigned short* __restrict__ A,
                                        const unsigned short* __restrict__ WhiT,
                                        const unsigned short* __restrict__ WloT,
                                        unsigned short* __restrict__ htb,
                                        int n0, int t, unsigned short* sA) {
#pragma unroll
  for (int p = 0; p < 4; ++p) {
    int fi = t + p * 256;
    int row = fi >> 4, c8 = (fi & 15) * 8;
    int gn = n0 + row; if (gn >= N_NODES) gn = N_NODES - 1;
    *(uint4*)(sA + row * 136 + c8) = *(const uint4*)(A + (size_t)gn * H + c8);
  }
  __syncthreads();
  int wave = t >> 6, lane = t & 63;
  int wr = wave >> 1, wc = wave & 1;
  int m = lane & 15, quad = (lane >> 4) & 3;
  f32x4 acc[2][4];
#pragma unroll
  for (int i = 0; i < 2; ++i)
#pragma unroll
    for (int j = 0; j < 4; ++j) acc[i][j] = (f32x4){0.f, 0.f, 0.f, 0.f};
#pragma unroll
  for (int q = 0; q < 4; ++q) {
    short8 bh[4], bl[4];
#pragma unroll
    for (int ct = 0; ct < 4; ++ct) {
      int n = wc * 64 + ct * 16 + m;
      bh[ct] = *(const short8*)(WhiT + n * H + q * 32 + quad * 8);
      bl[ct] = *(const short8*)(WloT + n * H + q * 32 + quad * 8);
    }
    short8 ah[2];
#pragma unroll
    for (int rt = 0; rt < 2; ++rt)
      ah[rt] = *(const short8*)(sA + (wr * 32 + rt * 16 + m) * 136 + q * 32 + quad * 8);
#pragma unroll
    for (int rt = 0; rt < 2; ++rt)
#pragma unroll
      for (int ct = 0; ct < 4; ++ct) {
        acc[rt][ct] = __builtin_amdgcn_mfma_f32_16x16x32_bf16(ah[rt], bh[ct], acc[rt][ct], 0, 0, 0);
        acc[rt][ct] = __builtin_amdgcn_mfma_f32_16x16x32_bf16(ah[rt], bl[ct], acc[rt][ct], 0, 0, 0);
      }
  }
#pragma unroll
  for (int rt = 0; rt < 2; ++rt)
#pragma unroll
    for (int ct = 0; ct < 4; ++ct) {
      int col = wc * 64 + ct * 16 + m;
#pragma unroll
      for (int r = 0; r < 4; ++r) {
        int gn = n0 + wr * 32 + rt * 16 + quad * 4 + r;
        if (gn < N_NODES) htb[(size_t)gn * H + col] = f2bf(acc[rt][ct][r]);
      }
    }
}

// ---------------- fused fill | mm_L0 ----------------
__global__ __launch_bounds__(256) void k_fillmm(
    const int* __restrict__ ei, const unsigned char* __restrict__ ranks,
    const int* __restrict__ offs, const float* __restrict__ dinv,
    int2* __restrict__ csr,
    const unsigned short* __restrict__ A, const unsigned short* __restrict__ WhiT,
    const unsigned short* __restrict__ WloT, unsigned short* __restrict__ htb) {
  __shared__ __align__(16) unsigned short sA[64 * 136];
  int t = threadIdx.x;
  if (blockIdx.x < FILL_BLKS) {
    int i = blockIdx.x * 256 + t;
    if (i < NEDGES / 4) {
      int4 s4 = *(const int4*)(ei + 4 * i);
      int4 d4 = *(const int4*)(ei + NEDGES + 4 * i);
      uchar4 r4 = ((const uchar4*)ranks)[i];
      int p0 = offs[d4.x] + r4.x;
      int p1 = offs[d4.y] + r4.y;
      int p2 = offs[d4.z] + r4.z;
      int p3 = offs[d4.w] + r4.w;
      csr[p0] = make_int2(s4.x, __float_as_int(dinv[s4.x] * dinv[d4.x]));
      csr[p1] = make_int2(s4.y, __float_as_int(dinv[s4.y] * dinv[d4.y]));
      csr[p2] = make_int2(s4.z, __float_as_int(dinv[s4.z] * dinv[d4.z]));
      csr[p3] = make_int2(s4.w, __float_as_int(dinv[s4.w] * dinv[d4.w]));
    }
  } else {
    mm_body(A, WhiT, WloT, htb, (blockIdx.x - FILL_BLKS) * 64, t, sA);
  }
}

__global__ __launch_bounds__(256) void k_mm(const unsigned short* __restrict__ A,
                                            const unsigned short* __restrict__ WhiT,
                                            const unsigned short* __restrict__ WloT,
                                            unsigned short* __restrict__ htb) {
  __shared__ __align__(16) unsigned short sA[64 * 136];
  mm_body(A, WhiT, WloT, htb, blockIdx.x * 64, threadIdx.x, sA);
}

// layer-2 fused: htb = bf16(A@Wc), resb = bf16(A@Wr + biasR)
__global__ __launch_bounds__(256) void k_mm2(const unsigned short* __restrict__ A,
    const unsigned short* __restrict__ WhiC, const unsigned short* __restrict__ WloC,
    const unsigned short* __restrict__ WhiR, const unsigned short* __restrict__ WloR,
    const float* __restrict__ biasR,
    unsigned short* __restrict__ htb, unsigned short* __restrict__ resb) {
  __shared__ __align__(16) unsigned short sA[64 * 136];
  int t = threadIdx.x;
  int n0 = blockIdx.x * 64;
#pragma unroll
  for (int p = 0; p < 4; ++p) {
    int fi = t + p * 256;
    int row = fi >> 4, c8 = (fi & 15) * 8;
    int gn = n0 + row; if (gn >= N_NODES) gn = N_NODES - 1;
    *(uint4*)(sA + row * 136 + c8) = *(const uint4*)(A + (size_t)gn * H + c8);
  }
  __syncthreads();
  int wave = t >> 6, lane = t & 63;
  int wr = wave >> 1, wc = wave & 1;
  int m = lane & 15, quad = (lane >> 4) & 3;
  f32x4 accC[2][4], accR[2][4];
#pragma unroll
  for (int i = 0; i < 2; ++i)
#pragma unroll
    for (int j = 0; j < 4; ++j) {
      accC[i][j] = (f32x4){0.f, 0.f, 0.f, 0.f};
      accR[i][j] = (f32x4){0.f, 0.f, 0.f, 0.f};
    }
#pragma unroll
  for (int q = 0; q < 4; ++q) {
    short8 ah[2];
#pragma unroll
    for (int rt = 0; rt < 2; ++rt)
      ah[rt] = *(const short8*)(sA + (wr * 32 + rt * 16 + m) * 136 + q * 32 + quad * 8);
#pragma unroll
    for (int ct = 0; ct < 4; ++ct) {
      int n = wc * 64 + ct * 16 + m;
      short8 bhC = *(const short8*)(WhiC + n * H + q * 32 + quad * 8);
      short8 blC = *(const short8*)(WloC + n * H + q * 32 + quad * 8);
      short8 bhR = *(const short8*)(WhiR + n * H + q * 32 + quad * 8);
      short8 blR = *(const short8*)(WloR + n * H + q * 32 + quad * 8);
#pragma unroll
      for (int rt = 0; rt < 2; ++rt) {
        accC[rt][ct] = __builtin_amdgcn_mfma_f32_16x16x32_bf16(ah[rt], bhC, accC[rt][ct], 0, 0, 0);
        accC[rt][ct] = __builtin_amdgcn_mfma_f32_16x16x32_bf16(ah[rt], blC, accC[rt][ct], 0, 0, 0);
        accR[rt][ct] = __builtin_amdgcn_mfma_f32_16x16x32_bf16(ah[rt], bhR, accR[rt][ct], 0, 0, 0);
        accR[rt][ct] = __builtin_amdgcn_mfma_f32_16x16x32_bf16(ah[rt], blR, accR[rt][ct], 0, 0, 0);
      }
    }
  }
#pragma unroll
  for (int rt = 0; rt < 2; ++rt)
#pragma unroll
    for (int ct = 0; ct < 4; ++ct) {
      int col = wc * 64 + ct * 16 + m;
      float bv = biasR[col];
#pragma unroll
      for (int r = 0; r < 4; ++r) {
        int gn = n0 + wr * 32 + rt * 16 + quad * 4 + r;
        if (gn < N_NODES) {
          htb[(size_t)gn * H + col]  = f2bf(accC[rt][ct][r]);
          resb[(size_t)gn * H + col] = f2bf(accR[rt][ct][r] + bv);
        }
      }
    }
}

// ---------------- aggregate + bias + LN + relu + residual (bf16 h) ----------------
__global__ __launch_bounds__(256) void k_agg(
    const unsigned short* __restrict__ htb, const unsigned short* __restrict__ res,
    const float* __restrict__ dinv, const int* __restrict__ offs,
    const int* __restrict__ deg, const int2* __restrict__ csr,
    const float* __restrict__ bias, const float* __restrict__ lng,
    const float* __restrict__ lnb, unsigned short* __restrict__ hout) {
  int wid = threadIdx.x >> 6, lane = threadIdx.x & 63;
  int node = blockIdx.x * 4 + wid;
  if (node >= N_NODES) return;
  int grp = lane >> 4, fl = lane & 15;
  int start = offs[node], cnt = deg[node];
  float di = dinv[node];
  const char* hb = (const char*)htb + fl * 16;
  float acc[8];
  {
    uint4 u = *(const uint4*)(hb + (size_t)node * 256);
    float sw = (grp == 0) ? di * di : 0.f;  // count self-loop once
    acc[0] = sw * bflo(u.x); acc[1] = sw * bfhi(u.x);
    acc[2] = sw * bflo(u.y); acc[3] = sw * bfhi(u.y);
    acc[4] = sw * bflo(u.z); acc[5] = sw * bfhi(u.z);
    acc[6] = sw * bflo(u.w); acc[7] = sw * bfhi(u.w);
  }
  for (int b0 = 0; b0 < cnt; b0 += 64) {
    int mm_ = min(64, cnt - b0);
    int s = 0; float w = 0.f;
    if (lane < mm_) {
      int2 ev = csr[start + b0 + lane];
      s = ev.x; w = __int_as_float(ev.y);
    }
#pragma unroll 2
    for (int e = 0; e < mm_; e += 4) {
      int ss = __shfl(s, e + grp, 64);
      float we = __shfl(w, e + grp, 64);
      uint4 u = *(const uint4*)(hb + (size_t)ss * 256);
      acc[0] = fmaf(we, bflo(u.x), acc[0]);
      acc[1] = fmaf(we, bfhi(u.x), acc[1]);
      acc[2] = fmaf(we, bflo(u.y), acc[2]);
      acc[3] = fmaf(we, bfhi(u.y), acc[3]);
      acc[4] = fmaf(we, bflo(u.z), acc[4]);
      acc[5] = fmaf(we, bfhi(u.z), acc[5]);
      acc[6] = fmaf(we, bflo(u.w), acc[6]);
      acc[7] = fmaf(we, bfhi(u.w), acc[7]);
    }
  }
#pragma unroll
  for (int j = 0; j < 8; ++j) {
    acc[j] += __shfl_xor(acc[j], 16, 64);
    acc[j] += __shfl_xor(acc[j], 32, 64);
  }
  float4 b0v = *(const float4*)(bias + fl * 8);
  float4 b1v = *(const float4*)(bias + fl * 8 + 4);
  acc[0] += b0v.x; acc[1] += b0v.y; acc[2] += b0v.z; acc[3] += b0v.w;
  acc[4] += b1v.x; acc[5] += b1v.y; acc[6] += b1v.z; acc[7] += b1v.w;
  float sl = ((acc[0] + acc[1]) + (acc[2] + acc[3])) +
             ((acc[4] + acc[5]) + (acc[6] + acc[7]));
#pragma unroll
  for (int mk = 1; mk <= 8; mk <<= 1) sl += __shfl_xor(sl, mk, 64);
  float mu = sl * (1.f / 128.f);
  float d[8];
  float vl = 0.f;
#pragma unroll
  for (int j = 0; j < 8; ++j) { d[j] = acc[j] - mu; vl = fmaf(d[j], d[j], vl); }
#pragma unroll
  for (int mk = 1; mk <= 8; mk <<= 1) vl += __shfl_xor(vl, mk, 64);
  float rs = rsqrtf(vl * (1.f / 128.f) + EPS);
  if (grp == 0) {
    float4 g0 = *(const float4*)(lng + fl * 8);
    float4 g1 = *(const float4*)(lng + fl * 8 + 4);
    float4 be0 = *(const float4*)(lnb + fl * 8);
    float4 be1 = *(const float4*)(lnb + fl * 8 + 4);
    uint4 rv = *(const uint4*)(res + (size_t)node * 128 + fl * 8);
    float o0 = fmaxf(fmaf(d[0] * rs, g0.x, be0.x), 0.f) + bflo(rv.x);
    float o1 = fmaxf(fmaf(d[1] * rs, g0.y, be0.y), 0.f) + bfhi(rv.x);
    float o2 = fmaxf(fmaf(d[2] * rs, g0.z, be0.z), 0.f) + bflo(rv.y);
    float o3 = fmaxf(fmaf(d[3] * rs, g0.w, be0.w), 0.f) + bfhi(rv.y);
    float o4 = fmaxf(fmaf(d[4] * rs, g1.x, be1.x), 0.f) + bflo(rv.z);
    float o5 = fmaxf(fmaf(d[5] * rs, g1.y, be1.y), 0.f) + bfhi(rv.z);
    float o6 = fmaxf(fmaf(d[6] * rs, g1.z, be1.z), 0.f) + bflo(rv.w);
    float o7 = fmaxf(fmaf(d[7] * rs, g1.w, be1.w), 0.f) + bfhi(rv.w);
    uint4 ov;
    ov.x = pack2(o0, o1); ov.y = pack2(o2, o3);
    ov.z = pack2(o4, o5); ov.w = pack2(o6, o7);
    *(uint4*)(hout + (size_t)node * 128 + fl * 8) = ov;
  }
}

// ---------------- mean pool (bf16 h) ----------------
__global__ void k_pool(const unsigned short* __restrict__ h, float* __restrict__ pool) {
  int f = threadIdx.x;  // 128
  float acc = 0.f;
  for (int n = blockIdx.x; n < N_NODES; n += gridDim.x)
    acc += bf2f(h[(size_t)n * H + f]);
  atomicAdd(&pool[f], acc);
}

// ---------------- head ----------------
__global__ void k_head(const float* __restrict__ pool, const float* __restrict__ Wfc1,
                       const float* __restrict__ bfc1, const float* __restrict__ g,
                       const float* __restrict__ bb, const float* __restrict__ Wfc2,
                       const float* __restrict__ bfc2, float* __restrict__ out) {
  __shared__ float sm[128], s1[128], stats[2];
  int t = threadIdx.x;
  if (t < 128) sm[t] = pool[t] * (1.f / (float)N_NODES);
  __syncthreads();
  if (t < 128) {
    float a = bfc1[t];
    for (int k = 0; k < 128; ++k) a = fmaf(sm[k], Wfc1[k * 128 + t], a);
    s1[t] = a;
  }
  __syncthreads();
  if (t == 0) {
    float mu = 0.f;
    for (int k = 0; k < 128; ++k) mu += s1[k];
    mu *= (1.f / 128.f);
    float var = 0.f;
    for (int k = 0; k < 128; ++k) { float d = s1[k] - mu; var += d * d; }
    var *= (1.f / 128.f);
    stats[0] = mu; stats[1] = rsqrtf(var + EPS);
  }
  __syncthreads();
  if (t < 128) s1[t] = fmaxf((s1[t] - stats[0]) * stats[1] * g[t] + bb[t], 0.f);
  __syncthreads();
  if (t < OUT_F) {
    float a = bfc2[t];
    for (int k = 0; k < 128; ++k) a = fmaf(s1[k], Wfc2[k * OUT_F + t], a);
    out[t] = a;
  }
}

extern "C" void kernel_launch(void* const* d_in, const int* in_sizes, int n_in,
                              void* d_out, int out_size, void* d_ws, size_t ws_size,
                              hipStream_t stream) {
  const float* x      = (const float*)d_in[0];
  const int*   ei     = (const int*)d_in[1];
  const float* W_emb  = (const float*)d_in[2];
  const float* b_emb  = (const float*)d_in[3];
  const float* W_conv = (const float*)d_in[4];
  const float* b_conv = (const float*)d_in[5];
  const float* ln_g   = (const float*)d_in[6];
  const float* ln_b   = (const float*)d_in[7];
  const float* W_res  = (const float*)d_in[8];
  const float* b_res  = (const float*)d_in[9];
  const float* W_fc1  = (const float*)d_in[10];
  const float* b_fc1  = (const float*)d_in[11];
  const float* fcn_g  = (const float*)d_in[12];
  const float* fcn_b  = (const float*)d_in[13];
  const float* W_fc2  = (const float*)d_in[14];
  const float* b_fc2  = (const float*)d_in[15];
  float* out = (float*)d_out;

  char* p = (char*)d_ws;
  auto take = [&](size_t bytes) {
    char* r = p; p += (bytes + 255) & ~(size_t)255; return r;
  };
  unsigned short* bufA = (unsigned short*)take((size_t)N_NODES * H * 2);
  unsigned short* bufB = (unsigned short*)take((size_t)N_NODES * H * 2);
  unsigned short* bufC = (unsigned short*)take((size_t)N_NODES * H * 2);
  unsigned short* htb  = (unsigned short*)take((size_t)N_NODES * H * 2);
  unsigned short* whiT = (unsigned short*)take((size_t)5 * H * H * 2);
  unsigned short* wloT = (unsigned short*)take((size_t)5 * H * H * 2);
  int*   deg  = (int*)take(N_NODES * 4);
  int*   offs = (int*)take(N_NODES * 4);
  int*   parts= (int*)take(512 * 4);
  float* dinv = (float*)take(N_NODES * 4);
  unsigned char* ranks = (unsigned char*)take(NEDGES);
  int2*  csr  = (int2*)take((size_t)NEDGES * 8);
  float* pool = (float*)take(128 * 4);

  hipMemsetAsync(deg, 0, N_NODES * 4, stream);
  hipMemsetAsync(pool, 0, 128 * 4, stream);

  k_hw<<<HIST8_BLKS + WS_BLKS, 256, 0, stream>>>(ei, deg, ranks, W_conv, W_res,
                                                 whiT, wloT);
  k_embed_scan<<<EMB_BLKS + NPARTS, 256, 0, stream>>>(x, W_emb, b_emb, bufA,
                                                      deg, offs, parts, dinv);
  k_scan_b<<<1, 512, 0, stream>>>(parts, NPARTS);
  k_scan_c<<<NPARTS, 256, 0, stream>>>(offs, parts);
  k_fillmm<<<FILL_BLKS + MM_BLKS, 256, 0, stream>>>(
      ei, ranks, offs, dinv, csr, bufA, whiT + 0 * H * H, wloT + 0 * H * H, htb);

  int aggg = (N_NODES + 3) / 4;
  // L0: res=A -> h1=C
  k_agg<<<aggg, 256, 0, stream>>>(htb, bufA, dinv, offs, deg, csr,
                                  b_conv + 0 * H, ln_g + 0 * H, ln_b + 0 * H, bufC);
  // L1: h1=C -> htb -> h2=A (res=C)
  k_mm<<<MM_BLKS, 256, 0, stream>>>(bufC, whiT + 1 * H * H, wloT + 1 * H * H, htb);
  k_agg<<<aggg, 256, 0, stream>>>(htb, bufC, dinv, offs, deg, csr,
                                  b_conv + 1 * H, ln_g + 1 * H, ln_b + 1 * H, bufA);
  // L2: h2=A; fused: htb=A@W2, B=bf16(A@Wres+bres); agg -> h3=C (res=B)
  k_mm2<<<MM_BLKS, 256, 0, stream>>>(bufA, whiT + 2 * H * H, wloT + 2 * H * H,
                                     whiT + 4 * H * H, wloT + 4 * H * H, b_res,
                                     htb, bufB);
  k_agg<<<aggg, 256, 0, stream>>>(htb, bufB, dinv, offs, deg, csr,
                                  b_conv + 2 * H, ln_g + 2 * H, ln_b + 2 * H, bufC);
  // L3: h3=C -> htb -> h4=A (res=C)
  k_mm<<<MM_BLKS, 256, 0, stream>>>(bufC, whiT + 3 * H * H, wloT + 3 * H * H, htb);
  k_agg<<<aggg, 256, 0, stream>>>(htb, bufC, dinv, offs, deg, csr,
                                  b_conv + 3 * H, ln_g + 3 * H, ln_b + 3 * H, bufA);

  k_pool<<<512, 128, 0, stream>>>(bufA, pool);
  k_head<<<1, 256, 0, stream>>>(pool, W_fc1, b_fc1, fcn_g, fcn_b,
                                W_fc2, b_fc2, out);
}

// Round 7
// 701.389 us; speedup vs baseline: 1.7293x; 1.0541x over previous
//
#include <hip/hip_runtime.h>

constexpr int N_NODES = 100000;
constexpr int F_IN    = 32;
constexpr int H       = 128;
constexpr int OUT_F   = 200;
constexpr int NEDGES  = 1600000;
constexpr float EPS   = 1e-5f;

constexpr int HIST8_BLKS = (NEDGES / 8 + 255) / 256;  // 782
constexpr int WS_BLKS    = 80;                        // 5*128*128/1024
constexpr int EMB_BLKS   = N_NODES / 32;              // 3125 (exact)
constexpr int NPARTS     = (N_NODES + 255) / 256;     // 391
constexpr int FILL_BLKS  = (NEDGES / 4 + 255) / 256;  // 1563
constexpr int MM_BLKS    = (N_NODES + 63) / 64;       // 1563

typedef __attribute__((ext_vector_type(8))) short  short8;
typedef __attribute__((ext_vector_type(4))) float  f32x4;
typedef __attribute__((ext_vector_type(2))) float  fv2;

__device__ __forceinline__ void fma4(float4& a, float s, const float4& w) {
  a.x = fmaf(s, w.x, a.x); a.y = fmaf(s, w.y, a.y);
  a.z = fmaf(s, w.z, a.z); a.w = fmaf(s, w.w, a.w);
}

__device__ __forceinline__ unsigned short f2bf(float f) {  // RNE
  union { float f; unsigned u; } v; v.f = f;
  unsigned r = v.u + 0x7fffu + ((v.u >> 16) & 1u);
  return (unsigned short)(r >> 16);
}
__device__ __forceinline__ float bf2f(unsigned short s) {
  union { unsigned u; float f; } v; v.u = ((unsigned)s) << 16;
  return v.f;
}
__device__ __forceinline__ float bflo(unsigned u) { return __uint_as_float(u << 16); }
__device__ __forceinline__ float bfhi(unsigned u) { return __uint_as_float(u & 0xffff0000u); }
__device__ __forceinline__ unsigned pack2(float lo, float hi) {
  return (unsigned)f2bf(lo) | ((unsigned)f2bf(hi) << 16);
}
__device__ __forceinline__ void st_bf4(unsigned short* p, float4 v) {
  uint2 o; o.x = pack2(v.x, v.y); o.y = pack2(v.z, v.w);
  *(uint2*)p = o;
}

// ---------------- fp8 e4m3fn helpers (native cvt, manual fallback) ----------------
#if __has_builtin(__builtin_amdgcn_cvt_pk_f32_fp8) && __has_builtin(__builtin_amdgcn_cvt_pk_fp8_f32)
#define HAVE_FP8_CVT 1
#endif

#ifndef HAVE_FP8_CVT
__device__ __forceinline__ float fp8_dec1(unsigned b) {
  unsigned s = (b >> 7) & 1u, E = (b >> 3) & 15u, m = b & 7u;
  float v;
  if (E) {
    union { unsigned u; float f; } t;
    t.u = (s << 31) | ((E + 120u) << 23) | (m << 20);
    v = t.f;
  } else {
    v = (s ? -1.f : 1.f) * (float)m * 0.001953125f;  // m * 2^-9
  }
  return v;
}
#endif

template <bool HI>
__device__ __forceinline__ fv2 fp8x2(unsigned u) {
#ifdef HAVE_FP8_CVT
  return __builtin_amdgcn_cvt_pk_f32_fp8((int)u, HI);  // word_sel is ICE via template
#else
  unsigned p = HI ? (u >> 16) : u;
  fv2 r; r.x = fp8_dec1(p & 0xffu); r.y = fp8_dec1((p >> 8) & 0xffu);
  return r;
#endif
}

__device__ __forceinline__ unsigned char f32_to_fp8(float f) {
#ifdef HAVE_FP8_CVT
  return (unsigned char)(__builtin_amdgcn_cvt_pk_fp8_f32(f, f, 0, false) & 0xff);
#else
  union { float f; unsigned u; } t; t.f = f;
  unsigned s = t.u >> 31;
  float a = fabsf(f);
  if (a > 448.f) a = 448.f;
  t.f = a;
  int e = (int)((t.u >> 23) & 0xff) - 127;
  unsigned char r;
  if (a == 0.f) {
    r = 0;
  } else if (e >= -6) {
    unsigned m = t.u & 0x7fffffu;
    unsigned keep = m >> 20, rest = m & 0xfffffu;
    keep += (rest > 0x80000u) || (rest == 0x80000u && (keep & 1u));
    int E = e + 7;
    if (keep == 8u) { keep = 0u; E += 1; }
    if (E >= 16) { E = 15; keep = 6u; }
    r = (unsigned char)((E << 3) | keep);
  } else {
    int mi = (int)(a * 512.f + 0.5f);
    r = (mi > 7) ? (unsigned char)(1u << 3) : (unsigned char)mi;
  }
  return (unsigned char)(r | (s << 7));
#endif
}

// ---------------- k_hw: hist(+ranks) | wsplit ----------------
__global__ __launch_bounds__(256) void k_hw(
    const int* __restrict__ ei, int* __restrict__ deg,
    unsigned char* __restrict__ ranks,
    const float* __restrict__ W_conv, const float* __restrict__ W_res,
    unsigned short* __restrict__ whiT, unsigned short* __restrict__ wloT) {
  int t = threadIdx.x;
  if (blockIdx.x < HIST8_BLKS) {
    int i = blockIdx.x * 256 + t;
    if (i < NEDGES / 8) {
      int4 a = *(const int4*)(ei + NEDGES + 8 * i);
      int4 b = *(const int4*)(ei + NEDGES + 8 * i + 4);
      union { unsigned char c[8]; uint2 u; } rr;
      rr.c[0] = (unsigned char)atomicAdd(&deg[a.x], 1);
      rr.c[1] = (unsigned char)atomicAdd(&deg[a.y], 1);
      rr.c[2] = (unsigned char)atomicAdd(&deg[a.z], 1);
      rr.c[3] = (unsigned char)atomicAdd(&deg[a.w], 1);
      rr.c[4] = (unsigned char)atomicAdd(&deg[b.x], 1);
      rr.c[5] = (unsigned char)atomicAdd(&deg[b.y], 1);
      rr.c[6] = (unsigned char)atomicAdd(&deg[b.z], 1);
      rr.c[7] = (unsigned char)atomicAdd(&deg[b.w], 1);
      ((uint2*)ranks)[i] = rr.u;
    }
  } else {
    int base = (blockIdx.x - HIST8_BLKS) * 1024;
#pragma unroll
    for (int j = 0; j < 4; ++j) {
      int idx = base + j * 256 + t;
      if (idx < 5 * H * H) {
        int m = idx >> 14, rr = idx & 16383;
        int k = rr >> 7, n = rr & 127;
        const float* src = (m < 4) ? (W_conv + m * H * H) : W_res;
        float w = src[k * H + n];
        unsigned short hi = f2bf(w);
        unsigned short lo = f2bf(w - bf2f(hi));
        whiT[m * H * H + n * H + k] = hi;
        wloT[m * H * H + n * H + k] = lo;
      }
    }
  }
}

// ---------------- k_embed_scan: embed(bf16 out) | scan_a ----------------
__global__ __launch_bounds__(256) void k_embed_scan(
    const float* __restrict__ x, const float* __restrict__ W_emb,
    const float* __restrict__ b_emb, unsigned short* __restrict__ h,
    const int* __restrict__ deg, int* __restrict__ offs,
    int* __restrict__ parts, float* __restrict__ dinv) {
  __shared__ __align__(16) float smem[F_IN * H + 32 * 36];
  int t = threadIdx.x;
  if (blockIdx.x < EMB_BLKS) {
    float* sW = smem;
    float* sX = smem + F_IN * H;
#pragma unroll
    for (int p = 0; p < 4; ++p)
      ((float4*)sW)[t + p * 256] = ((const float4*)W_emb)[t + p * 256];
    int n0 = blockIdx.x * 32;
    {
      int row = t >> 3, k4 = (t & 7) * 4;
      *(float4*)(sX + row * 36 + k4) =
          *(const float4*)(x + (size_t)(n0 + row) * F_IN + k4);
    }
    __syncthreads();
    int nr = t >> 3, c = (t & 7) * 4;
    float4 a0 = make_float4(0,0,0,0), a1 = a0, a2 = a0, a3 = a0;
#pragma unroll 4
    for (int k = 0; k < F_IN; ++k) {
      float xv = sX[nr * 36 + k];
      const float* wp = sW + k * H + c;
      fma4(a0, xv, *(const float4*)(wp));
      fma4(a1, xv, *(const float4*)(wp + 32));
      fma4(a2, xv, *(const float4*)(wp + 64));
      fma4(a3, xv, *(const float4*)(wp + 96));
    }
    float4 b0 = *(const float4*)(b_emb + c);
    float4 b1 = *(const float4*)(b_emb + c + 32);
    float4 b2 = *(const float4*)(b_emb + c + 64);
    float4 b3 = *(const float4*)(b_emb + c + 96);
    a0.x += b0.x; a0.y += b0.y; a0.z += b0.z; a0.w += b0.w;
    a1.x += b1.x; a1.y += b1.y; a1.z += b1.z; a1.w += b1.w;
    a2.x += b2.x; a2.y += b2.y; a2.z += b2.z; a2.w += b2.w;
    a3.x += b3.x; a3.y += b3.y; a3.z += b3.z; a3.w += b3.w;
    unsigned short* hr = h + (size_t)(n0 + nr) * H + c;
    st_bf4(hr, a0); st_bf4(hr + 32, a1);
    st_bf4(hr + 64, a2); st_bf4(hr + 96, a3);
  } else {
    int* s = (int*)smem;
    int i = (blockIdx.x - EMB_BLKS) * 256 + t;
    int d = (i < N_NODES) ? deg[i] : 0;
    s[t] = d;
    __syncthreads();
#pragma unroll
    for (int off = 1; off < 256; off <<= 1) {
      int v = (t >= off) ? s[t - off] : 0;
      __syncthreads();
      s[t] += v;
      __syncthreads();
    }
    if (i < N_NODES) {
      offs[i] = s[t] - d;
      dinv[i] = rsqrtf((float)(d + 1));  // +1 self-loop
    }
    if (t == 255) parts[blockIdx.x - EMB_BLKS] = s[255];
  }
}

__global__ void k_scan_b(int* __restrict__ parts, int nparts) {
  __shared__ int s[512];
  int t = threadIdx.x;
  int d = (t < nparts) ? parts[t] : 0;
  s[t] = d;
  __syncthreads();
#pragma unroll
  for (int off = 1; off < 512; off <<= 1) {
    int v = (t >= off) ? s[t - off] : 0;
    __syncthreads();
    s[t] += v;
    __syncthreads();
  }
  if (t < nparts) parts[t] = s[t] - d;
}

__global__ void k_scan_c(int* __restrict__ offs, const int* __restrict__ parts) {
  int i = blockIdx.x * 256 + threadIdx.x;
  if (i < N_NODES) offs[i] += parts[blockIdx.x];
}

// ---------------- mm body: ht8 = fp8(A(bf16) @ W), 2-pass split ----------------
__device__ __forceinline__ void mm_body(const unsigned short* __restrict__ A,
                                        const unsigned short* __restrict__ WhiT,
                                        const unsigned short* __restrict__ WloT,
                                        unsigned char* __restrict__ ht8,
                                        int n0, int t, unsigned short* sA) {
#pragma unroll
  for (int p = 0; p < 4; ++p) {
    int fi = t + p * 256;
    int row = fi >> 4, c8 = (fi & 15) * 8;
    int gn = n0 + row; if (gn >= N_NODES) gn = N_NODES - 1;
    *(uint4*)(sA + row * 136 + c8) = *(const uint4*)(A + (size_t)gn * H + c8);
  }
  __syncthreads();
  int wave = t >> 6, lane = t & 63;
  int wr = wave >> 1, wc = wave & 1;
  int m = lane & 15, quad = (lane >> 4) & 3;
  f32x4 acc[2][4];
#pragma unroll
  for (int i = 0; i < 2; ++i)
#pragma unroll
    for (int j = 0; j < 4; ++j) acc[i][j] = (f32x4){0.f, 0.f, 0.f, 0.f};
#pragma unroll
  for (int q = 0; q < 4; ++q) {
    short8 bh[4], bl[4];
#pragma unroll
    for (int ct = 0; ct < 4; ++ct) {
      int n = wc * 64 + ct * 16 + m;
      bh[ct] = *(const short8*)(WhiT + n * H + q * 32 + quad * 8);
      bl[ct] = *(const short8*)(WloT + n * H + q * 32 + quad * 8);
    }
    short8 ah[2];
#pragma unroll
    for (int rt = 0; rt < 2; ++rt)
      ah[rt] = *(const short8*)(sA + (wr * 32 + rt * 16 + m) * 136 + q * 32 + quad * 8);
#pragma unroll
    for (int rt = 0; rt < 2; ++rt)
#pragma unroll
      for (int ct = 0; ct < 4; ++ct) {
        acc[rt][ct] = __builtin_amdgcn_mfma_f32_16x16x32_bf16(ah[rt], bh[ct], acc[rt][ct], 0, 0, 0);
        acc[rt][ct] = __builtin_amdgcn_mfma_f32_16x16x32_bf16(ah[rt], bl[ct], acc[rt][ct], 0, 0, 0);
      }
  }
#pragma unroll
  for (int rt = 0; rt < 2; ++rt)
#pragma unroll
    for (int ct = 0; ct < 4; ++ct) {
      int col = wc * 64 + ct * 16 + m;
#pragma unroll
      for (int r = 0; r < 4; ++r) {
        int gn = n0 + wr * 32 + rt * 16 + quad * 4 + r;
        if (gn < N_NODES) ht8[(size_t)gn * H + col] = f32_to_fp8(acc[rt][ct][r]);
      }
    }
}

// ---------------- fused fill | mm_L0 ----------------
__global__ __launch_bounds__(256) void k_fillmm(
    const int* __restrict__ ei, const unsigned char* __restrict__ ranks,
    const int* __restrict__ offs, const float* __restrict__ dinv,
    unsigned* __restrict__ csr,
    const unsigned short* __restrict__ A, const unsigned short* __restrict__ WhiT,
    const unsigned short* __restrict__ WloT, unsigned char* __restrict__ ht8) {
  __shared__ __align__(16) unsigned short sA[64 * 136];
  int t = threadIdx.x;
  if (blockIdx.x < FILL_BLKS) {
    int i = blockIdx.x * 256 + t;
    if (i < NEDGES / 4) {
      int4 s4 = *(const int4*)(ei + 4 * i);
      int4 d4 = *(const int4*)(ei + NEDGES + 4 * i);
      uchar4 r4 = ((const uchar4*)ranks)[i];
      int p0 = offs[d4.x] + r4.x;
      int p1 = offs[d4.y] + r4.y;
      int p2 = offs[d4.z] + r4.z;
      int p3 = offs[d4.w] + r4.w;
      // entry = (src<<15) | round(dinv[src]*32767)
      csr[p0] = ((unsigned)s4.x << 15) | (unsigned)(dinv[s4.x] * 32767.f + 0.5f);
      csr[p1] = ((unsigned)s4.y << 15) | (unsigned)(dinv[s4.y] * 32767.f + 0.5f);
      csr[p2] = ((unsigned)s4.z << 15) | (unsigned)(dinv[s4.z] * 32767.f + 0.5f);
      csr[p3] = ((unsigned)s4.w << 15) | (unsigned)(dinv[s4.w] * 32767.f + 0.5f);
    }
  } else {
    mm_body(A, WhiT, WloT, ht8, (blockIdx.x - FILL_BLKS) * 64, t, sA);
  }
}

__global__ __launch_bounds__(256) void k_mm(const unsigned short* __restrict__ A,
                                            const unsigned short* __restrict__ WhiT,
                                            const unsigned short* __restrict__ WloT,
                                            unsigned char* __restrict__ ht8) {
  __shared__ __align__(16) unsigned short sA[64 * 136];
  mm_body(A, WhiT, WloT, ht8, blockIdx.x * 64, threadIdx.x, sA);
}

// layer-2 fused: ht8 = fp8(A@Wc), resb = bf16(A@Wr + biasR)
__global__ __launch_bounds__(256) void k_mm2(const unsigned short* __restrict__ A,
    const unsigned short* __restrict__ WhiC, const unsigned short* __restrict__ WloC,
    const unsigned short* __restrict__ WhiR, const unsigned short* __restrict__ WloR,
    const float* __restrict__ biasR,
    unsigned char* __restrict__ ht8, unsigned short* __restrict__ resb) {
  __shared__ __align__(16) unsigned short sA[64 * 136];
  int t = threadIdx.x;
  int n0 = blockIdx.x * 64;
#pragma unroll
  for (int p = 0; p < 4; ++p) {
    int fi = t + p * 256;
    int row = fi >> 4, c8 = (fi & 15) * 8;
    int gn = n0 + row; if (gn >= N_NODES) gn = N_NODES - 1;
    *(uint4*)(sA + row * 136 + c8) = *(const uint4*)(A + (size_t)gn * H + c8);
  }
  __syncthreads();
  int wave = t >> 6, lane = t & 63;
  int wr = wave >> 1, wc = wave & 1;
  int m = lane & 15, quad = (lane >> 4) & 3;
  f32x4 accC[2][4], accR[2][4];
#pragma unroll
  for (int i = 0; i < 2; ++i)
#pragma unroll
    for (int j = 0; j < 4; ++j) {
      accC[i][j] = (f32x4){0.f, 0.f, 0.f, 0.f};
      accR[i][j] = (f32x4){0.f, 0.f, 0.f, 0.f};
    }
#pragma unroll
  for (int q = 0; q < 4; ++q) {
    short8 ah[2];
#pragma unroll
    for (int rt = 0; rt < 2; ++rt)
      ah[rt] = *(const short8*)(sA + (wr * 32 + rt * 16 + m) * 136 + q * 32 + quad * 8);
#pragma unroll
    for (int ct = 0; ct < 4; ++ct) {
      int n = wc * 64 + ct * 16 + m;
      short8 bhC = *(const short8*)(WhiC + n * H + q * 32 + quad * 8);
      short8 blC = *(const short8*)(WloC + n * H + q * 32 + quad * 8);
      short8 bhR = *(const short8*)(WhiR + n * H + q * 32 + quad * 8);
      short8 blR = *(const short8*)(WloR + n * H + q * 32 + quad * 8);
#pragma unroll
      for (int rt = 0; rt < 2; ++rt) {
        accC[rt][ct] = __builtin_amdgcn_mfma_f32_16x16x32_bf16(ah[rt], bhC, accC[rt][ct], 0, 0, 0);
        accC[rt][ct] = __builtin_amdgcn_mfma_f32_16x16x32_bf16(ah[rt], blC, accC[rt][ct], 0, 0, 0);
        accR[rt][ct] = __builtin_amdgcn_mfma_f32_16x16x32_bf16(ah[rt], bhR, accR[rt][ct], 0, 0, 0);
        accR[rt][ct] = __builtin_amdgcn_mfma_f32_16x16x32_bf16(ah[rt], blR, accR[rt][ct], 0, 0, 0);
      }
    }
  }
#pragma unroll
  for (int rt = 0; rt < 2; ++rt)
#pragma unroll
    for (int ct = 0; ct < 4; ++ct) {
      int col = wc * 64 + ct * 16 + m;
      float bv = biasR[col];
#pragma unroll
      for (int r = 0; r < 4; ++r) {
        int gn = n0 + wr * 32 + rt * 16 + quad * 4 + r;
        if (gn < N_NODES) {
          ht8[(size_t)gn * H + col]  = f32_to_fp8(accC[rt][ct][r]);
          resb[(size_t)gn * H + col] = f2bf(accR[rt][ct][r] + bv);
        }
      }
    }
}

// ---------------- aggregate(fp8 ht) + bias + LN + relu + residual(bf16) ----------------
__global__ __launch_bounds__(256) void k_agg(
    const unsigned char* __restrict__ ht8, const unsigned short* __restrict__ res,
    const float* __restrict__ dinv, const int* __restrict__ offs,
    const int* __restrict__ deg, const unsigned* __restrict__ csr,
    const float* __restrict__ bias, const float* __restrict__ lng,
    const float* __restrict__ lnb, unsigned short* __restrict__ hout) {
  int wid = threadIdx.x >> 6, lane = threadIdx.x & 63;
  int node = blockIdx.x * 4 + wid;
  if (node >= N_NODES) return;
  int grp = lane >> 4, fl = lane & 15;
  int start = offs[node], cnt = deg[node];
  float di = dinv[node];
  const unsigned char* hb = ht8 + fl * 8;  // lane owns 8 fp8 feats
  float acc[8];
  {
    uint2 u = *(const uint2*)(hb + (size_t)node * 128);
    float sw = (grp == 0) ? di * di : 0.f;  // count self-loop once
    fv2 a = fp8x2<false>(u.x), b = fp8x2<true>(u.x);
    fv2 c = fp8x2<false>(u.y), d2 = fp8x2<true>(u.y);
    acc[0] = sw * a.x; acc[1] = sw * a.y;
    acc[2] = sw * b.x; acc[3] = sw * b.y;
    acc[4] = sw * c.x; acc[5] = sw * c.y;
    acc[6] = sw * d2.x; acc[7] = sw * d2.y;
  }
  float ddq = di * (1.f / 32767.f);
  for (int b0 = 0; b0 < cnt; b0 += 64) {
    int mm_ = min(64, cnt - b0);
    int s = 0; float w = 0.f;
    if (lane < mm_) {
      unsigned ev = csr[start + b0 + lane];
      s = (int)(ev >> 15);
      w = (float)(ev & 32767u) * ddq;
    }
#pragma unroll 2
    for (int e = 0; e < mm_; e += 4) {
      int ss = __shfl(s, e + grp, 64);
      float we = __shfl(w, e + grp, 64);
      uint2 u = *(const uint2*)(hb + (size_t)ss * 128);
      fv2 a = fp8x2<false>(u.x), b = fp8x2<true>(u.x);
      fv2 c = fp8x2<false>(u.y), d2 = fp8x2<true>(u.y);
      acc[0] = fmaf(we, a.x, acc[0]);
      acc[1] = fmaf(we, a.y, acc[1]);
      acc[2] = fmaf(we, b.x, acc[2]);
      acc[3] = fmaf(we, b.y, acc[3]);
      acc[4] = fmaf(we, c.x, acc[4]);
      acc[5] = fmaf(we, c.y, acc[5]);
      acc[6] = fmaf(we, d2.x, acc[6]);
      acc[7] = fmaf(we, d2.y, acc[7]);
    }
  }
#pragma unroll
  for (int j = 0; j < 8; ++j) {
    acc[j] += __shfl_xor(acc[j], 16, 64);
    acc[j] += __shfl_xor(acc[j], 32, 64);
  }
  float4 b0v = *(const float4*)(bias + fl * 8);
  float4 b1v = *(const float4*)(bias + fl * 8 + 4);
  acc[0] += b0v.x; acc[1] += b0v.y; acc[2] += b0v.z; acc[3] += b0v.w;
  acc[4] += b1v.x; acc[5] += b1v.y; acc[6] += b1v.z; acc[7] += b1v.w;
  float sl = ((acc[0] + acc[1]) + (acc[2] + acc[3])) +
             ((acc[4] + acc[5]) + (acc[6] + acc[7]));
#pragma unroll
  for (int mk = 1; mk <= 8; mk <<= 1) sl += __shfl_xor(sl, mk, 64);
  float mu = sl * (1.f / 128.f);
  float d[8];
  float vl = 0.f;
#pragma unroll
  for (int j = 0; j < 8; ++j) { d[j] = acc[j] - mu; vl = fmaf(d[j], d[j], vl); }
#pragma unroll
  for (int mk = 1; mk <= 8; mk <<= 1) vl += __shfl_xor(vl, mk, 64);
  float rs = rsqrtf(vl * (1.f / 128.f) + EPS);
  if (grp == 0) {
    float4 g0 = *(const float4*)(lng + fl * 8);
    float4 g1 = *(const float4*)(lng + fl * 8 + 4);
    float4 be0 = *(const float4*)(lnb + fl * 8);
    float4 be1 = *(const float4*)(lnb + fl * 8 + 4);
    uint4 rv = *(const uint4*)(res + (size_t)node * 128 + fl * 8);
    float o0 = fmaxf(fmaf(d[0] * rs, g0.x, be0.x), 0.f) + bflo(rv.x);
    float o1 = fmaxf(fmaf(d[1] * rs, g0.y, be0.y), 0.f) + bfhi(rv.x);
    float o2 = fmaxf(fmaf(d[2] * rs, g0.z, be0.z), 0.f) + bflo(rv.y);
    float o3 = fmaxf(fmaf(d[3] * rs, g0.w, be0.w), 0.f) + bfhi(rv.y);
    float o4 = fmaxf(fmaf(d[4] * rs, g1.x, be1.x), 0.f) + bflo(rv.z);
    float o5 = fmaxf(fmaf(d[5] * rs, g1.y, be1.y), 0.f) + bfhi(rv.z);
    float o6 = fmaxf(fmaf(d[6] * rs, g1.z, be1.z), 0.f) + bflo(rv.w);
    float o7 = fmaxf(fmaf(d[7] * rs, g1.w, be1.w), 0.f) + bfhi(rv.w);
    uint4 ov;
    ov.x = pack2(o0, o1); ov.y = pack2(o2, o3);
    ov.z = pack2(o4, o5); ov.w = pack2(o6, o7);
    *(uint4*)(hout + (size_t)node * 128 + fl * 8) = ov;
  }
}

// ---------------- mean pool (bf16 h) ----------------
__global__ void k_pool(const unsigned short* __restrict__ h, float* __restrict__ pool) {
  int f = threadIdx.x;  // 128
  float acc = 0.f;
  for (int n = blockIdx.x; n < N_NODES; n += gridDim.x)
    acc += bf2f(h[(size_t)n * H + f]);
  atomicAdd(&pool[f], acc);
}

// ---------------- head ----------------
__global__ void k_head(const float* __restrict__ pool, const float* __restrict__ Wfc1,
                       const float* __restrict__ bfc1, const float* __restrict__ g,
                       const float* __restrict__ bb, const float* __restrict__ Wfc2,
                       const float* __restrict__ bfc2, float* __restrict__ out) {
  __shared__ float sm[128], s1[128], stats[2];
  int t = threadIdx.x;
  if (t < 128) sm[t] = pool[t] * (1.f / (float)N_NODES);
  __syncthreads();
  if (t < 128) {
    float a = bfc1[t];
    for (int k = 0; k < 128; ++k) a = fmaf(sm[k], Wfc1[k * 128 + t], a);
    s1[t] = a;
  }
  __syncthreads();
  if (t == 0) {
    float mu = 0.f;
    for (int k = 0; k < 128; ++k) mu += s1[k];
    mu *= (1.f / 128.f);
    float var = 0.f;
    for (int k = 0; k < 128; ++k) { float d = s1[k] - mu; var += d * d; }
    var *= (1.f / 128.f);
    stats[0] = mu; stats[1] = rsqrtf(var + EPS);
  }
  __syncthreads();
  if (t < 128) s1[t] = fmaxf((s1[t] - stats[0]) * stats[1] * g[t] + bb[t], 0.f);
  __syncthreads();
  if (t < OUT_F) {
    float a = bfc2[t];
    for (int k = 0; k < 128; ++k) a = fmaf(s1[k], Wfc2[k * OUT_F + t], a);
    out[t] = a;
  }
}

extern "C" void kernel_launch(void* const* d_in, const int* in_sizes, int n_in,
                              void* d_out, int out_size, void* d_ws, size_t ws_size,
                              hipStream_t stream) {
  const float* x      = (const float*)d_in[0];
  const int*   ei     = (const int*)d_in[1];
  const float* W_emb  = (const float*)d_in[2];
  const float* b_emb  = (const float*)d_in[3];
  const float* W_conv = (const float*)d_in[4];
  const float* b_conv = (const float*)d_in[5];
  const float* ln_g   = (const float*)d_in[6];
  const float* ln_b   = (const float*)d_in[7];
  const float* W_res  = (const float*)d_in[8];
  const float* b_res  = (const float*)d_in[9];
  const float* W_fc1  = (const float*)d_in[10];
  const float* b_fc1  = (const float*)d_in[11];
  const float* fcn_g  = (const float*)d_in[12];
  const float* fcn_b  = (const float*)d_in[13];
  const float* W_fc2  = (const float*)d_in[14];
  const float* b_fc2  = (const float*)d_in[15];
  float* out = (float*)d_out;

  char* p = (char*)d_ws;
  auto take = [&](size_t bytes) {
    char* r = p; p += (bytes + 255) & ~(size_t)255; return r;
  };
  unsigned short* bufA = (unsigned short*)take((size_t)N_NODES * H * 2);
  unsigned short* bufB = (unsigned short*)take((size_t)N_NODES * H * 2);
  unsigned short* bufC = (unsigned short*)take((size_t)N_NODES * H * 2);
  unsigned char*  ht8  = (unsigned char*)take((size_t)N_NODES * H);
  unsigned short* whiT = (unsigned short*)take((size_t)5 * H * H * 2);
  unsigned short* wloT = (unsigned short*)take((size_t)5 * H * H * 2);
  int*   deg  = (int*)take(N_NODES * 4);
  int*   offs = (int*)take(N_NODES * 4);
  int*   parts= (int*)take(512 * 4);
  float* dinv = (float*)take(N_NODES * 4);
  unsigned char* ranks = (unsigned char*)take(NEDGES);
  unsigned* csr = (unsigned*)take((size_t)NEDGES * 4);
  float* pool = (float*)take(128 * 4);

  (void)hipMemsetAsync(deg, 0, N_NODES * 4, stream);
  (void)hipMemsetAsync(pool, 0, 128 * 4, stream);

  k_hw<<<HIST8_BLKS + WS_BLKS, 256, 0, stream>>>(ei, deg, ranks, W_conv, W_res,
                                                 whiT, wloT);
  k_embed_scan<<<EMB_BLKS + NPARTS, 256, 0, stream>>>(x, W_emb, b_emb, bufA,
                                                      deg, offs, parts, dinv);
  k_scan_b<<<1, 512, 0, stream>>>(parts, NPARTS);
  k_scan_c<<<NPARTS, 256, 0, stream>>>(offs, parts);
  k_fillmm<<<FILL_BLKS + MM_BLKS, 256, 0, stream>>>(
      ei, ranks, offs, dinv, csr, bufA, whiT + 0 * H * H, wloT + 0 * H * H, ht8);

  int aggg = (N_NODES + 3) / 4;
  // L0: res=A -> h1=C
  k_agg<<<aggg, 256, 0, stream>>>(ht8, bufA, dinv, offs, deg, csr,
                                  b_conv + 0 * H, ln_g + 0 * H, ln_b + 0 * H, bufC);
  // L1: h1=C -> ht8 -> h2=A (res=C)
  k_mm<<<MM_BLKS, 256, 0, stream>>>(bufC, whiT + 1 * H * H, wloT + 1 * H * H, ht8);
  k_agg<<<aggg, 256, 0, stream>>>(ht8, bufC, dinv, offs, deg, csr,
                                  b_conv + 1 * H, ln_g + 1 * H, ln_b + 1 * H, bufA);
  // L2: h2=A; fused: ht8=A@W2, B=bf16(A@Wres+bres); agg -> h3=C (res=B)
  k_mm2<<<MM_BLKS, 256, 0, stream>>>(bufA, whiT + 2 * H * H, wloT + 2 * H * H,
                                     whiT + 4 * H * H, wloT + 4 * H * H, b_res,
                                     ht8, bufB);
  k_agg<<<aggg, 256, 0, stream>>>(ht8, bufB, dinv, offs, deg, csr,
                                  b_conv + 2 * H, ln_g + 2 * H, ln_b + 2 * H, bufC);
  // L3: h3=C -> ht8 -> h4=A (res=C)
  k_mm<<<MM_BLKS, 256, 0, stream>>>(bufC, whiT + 3 * H * H, wloT + 3 * H * H, ht8);
  k_agg<<<aggg, 256, 0, stream>>>(ht8, bufC, dinv, offs, deg, csr,
                                  b_conv + 3 * H, ln_g + 3 * H, ln_b + 3 * H, bufA);

  k_pool<<<512, 128, 0, stream>>>(bufA, pool);
  k_head<<<1, 256, 0, stream>>>(pool, W_fc1, b_fc1, fcn_g, fcn_b,
                                W_fc2, b_fc2, out);
}

// Round 8
// 691.133 us; speedup vs baseline: 1.7550x; 1.0148x over previous
//
#include <hip/hip_runtime.h>

constexpr int N_NODES = 100000;
constexpr int F_IN    = 32;
constexpr int H       = 128;
constexpr int OUT_F   = 200;
constexpr int NEDGES  = 1600000;
constexpr float EPS   = 1e-5f;

constexpr int HIST8_BLKS = (NEDGES / 8 + 255) / 256;  // 782
constexpr int WS_BLKS    = 80;                        // 5*128*128/1024
constexpr int EMB_BLKS   = N_NODES / 32;              // 3125 (exact)
constexpr int NPARTS     = (N_NODES + 255) / 256;     // 391
constexpr int FILL_BLKS  = (NEDGES / 4 + 255) / 256;  // 1563
constexpr int MMROW_BLKS = (N_NODES + 63) / 64;       // 1563
constexpr int MM_BLKS    = MMROW_BLKS * 2;            // 3126 (64r x 64c tiles)

typedef __attribute__((ext_vector_type(8))) short  short8;
typedef __attribute__((ext_vector_type(4))) float  f32x4;
typedef __attribute__((ext_vector_type(2))) float  fv2;

__device__ __forceinline__ void fma4(float4& a, float s, const float4& w) {
  a.x = fmaf(s, w.x, a.x); a.y = fmaf(s, w.y, a.y);
  a.z = fmaf(s, w.z, a.z); a.w = fmaf(s, w.w, a.w);
}

__device__ __forceinline__ unsigned short f2bf(float f) {  // RNE
  union { float f; unsigned u; } v; v.f = f;
  unsigned r = v.u + 0x7fffu + ((v.u >> 16) & 1u);
  return (unsigned short)(r >> 16);
}
__device__ __forceinline__ float bf2f(unsigned short s) {
  union { unsigned u; float f; } v; v.u = ((unsigned)s) << 16;
  return v.f;
}
__device__ __forceinline__ float bflo(unsigned u) { return __uint_as_float(u << 16); }
__device__ __forceinline__ float bfhi(unsigned u) { return __uint_as_float(u & 0xffff0000u); }
__device__ __forceinline__ unsigned pack2(float lo, float hi) {
  return (unsigned)f2bf(lo) | ((unsigned)f2bf(hi) << 16);
}
__device__ __forceinline__ void st_bf4(unsigned short* p, float4 v) {
  uint2 o; o.x = pack2(v.x, v.y); o.y = pack2(v.z, v.w);
  *(uint2*)p = o;
}

// ---------------- fp8 e4m3fn helpers (native cvt, manual fallback) ----------------
#if __has_builtin(__builtin_amdgcn_cvt_pk_f32_fp8) && __has_builtin(__builtin_amdgcn_cvt_pk_fp8_f32)
#define HAVE_FP8_CVT 1
#endif

#ifndef HAVE_FP8_CVT
__device__ __forceinline__ float fp8_dec1(unsigned b) {
  unsigned s = (b >> 7) & 1u, E = (b >> 3) & 15u, m = b & 7u;
  float v;
  if (E) {
    union { unsigned u; float f; } t;
    t.u = (s << 31) | ((E + 120u) << 23) | (m << 20);
    v = t.f;
  } else {
    v = (s ? -1.f : 1.f) * (float)m * 0.001953125f;  // m * 2^-9
  }
  return v;
}
#endif

template <bool HI>
__device__ __forceinline__ fv2 fp8x2(unsigned u) {
#ifdef HAVE_FP8_CVT
  return __builtin_amdgcn_cvt_pk_f32_fp8((int)u, HI);  // word_sel is ICE via template
#else
  unsigned p = HI ? (u >> 16) : u;
  fv2 r; r.x = fp8_dec1(p & 0xffu); r.y = fp8_dec1((p >> 8) & 0xffu);
  return r;
#endif
}

__device__ __forceinline__ unsigned char f32_to_fp8(float f) {
#ifdef HAVE_FP8_CVT
  return (unsigned char)(__builtin_amdgcn_cvt_pk_fp8_f32(f, f, 0, false) & 0xff);
#else
  union { float f; unsigned u; } t; t.f = f;
  unsigned s = t.u >> 31;
  float a = fabsf(f);
  if (a > 448.f) a = 448.f;
  t.f = a;
  int e = (int)((t.u >> 23) & 0xff) - 127;
  unsigned char r;
  if (a == 0.f) {
    r = 0;
  } else if (e >= -6) {
    unsigned m = t.u & 0x7fffffu;
    unsigned keep = m >> 20, rest = m & 0xfffffu;
    keep += (rest > 0x80000u) || (rest == 0x80000u && (keep & 1u));
    int E = e + 7;
    if (keep == 8u) { keep = 0u; E += 1; }
    if (E >= 16) { E = 15; keep = 6u; }
    r = (unsigned char)((E << 3) | keep);
  } else {
    int mi = (int)(a * 512.f + 0.5f);
    r = (mi > 7) ? (unsigned char)(1u << 3) : (unsigned char)mi;
  }
  return (unsigned char)(r | (s << 7));
#endif
}

// ---------------- k_hw: hist(+ranks) | wsplit ----------------
__global__ __launch_bounds__(256) void k_hw(
    const int* __restrict__ ei, int* __restrict__ deg,
    unsigned char* __restrict__ ranks,
    const float* __restrict__ W_conv, const float* __restrict__ W_res,
    unsigned short* __restrict__ whiT, unsigned short* __restrict__ wloT) {
  int t = threadIdx.x;
  if (blockIdx.x < HIST8_BLKS) {
    int i = blockIdx.x * 256 + t;
    if (i < NEDGES / 8) {
      int4 a = *(const int4*)(ei + NEDGES + 8 * i);
      int4 b = *(const int4*)(ei + NEDGES + 8 * i + 4);
      union { unsigned char c[8]; uint2 u; } rr;
      rr.c[0] = (unsigned char)atomicAdd(&deg[a.x], 1);
      rr.c[1] = (unsigned char)atomicAdd(&deg[a.y], 1);
      rr.c[2] = (unsigned char)atomicAdd(&deg[a.z], 1);
      rr.c[3] = (unsigned char)atomicAdd(&deg[a.w], 1);
      rr.c[4] = (unsigned char)atomicAdd(&deg[b.x], 1);
      rr.c[5] = (unsigned char)atomicAdd(&deg[b.y], 1);
      rr.c[6] = (unsigned char)atomicAdd(&deg[b.z], 1);
      rr.c[7] = (unsigned char)atomicAdd(&deg[b.w], 1);
      ((uint2*)ranks)[i] = rr.u;
    }
  } else {
    int base = (blockIdx.x - HIST8_BLKS) * 1024;
#pragma unroll
    for (int j = 0; j < 4; ++j) {
      int idx = base + j * 256 + t;
      if (idx < 5 * H * H) {
        int m = idx >> 14, rr = idx & 16383;
        int k = rr >> 7, n = rr & 127;
        const float* src = (m < 4) ? (W_conv + m * H * H) : W_res;
        float w = src[k * H + n];
        unsigned short hi = f2bf(w);
        unsigned short lo = f2bf(w - bf2f(hi));
        whiT[m * H * H + n * H + k] = hi;
        wloT[m * H * H + n * H + k] = lo;
      }
    }
  }
}

// ---------------- k_embed_scan: embed(bf16 out) | scan_a ----------------
__global__ __launch_bounds__(256) void k_embed_scan(
    const float* __restrict__ x, const float* __restrict__ W_emb,
    const float* __restrict__ b_emb, unsigned short* __restrict__ h,
    const int* __restrict__ deg, int* __restrict__ offs,
    int* __restrict__ parts, float* __restrict__ dinv) {
  __shared__ __align__(16) float smem[F_IN * H + 32 * 36];
  int t = threadIdx.x;
  if (blockIdx.x < EMB_BLKS) {
    float* sW = smem;
    float* sX = smem + F_IN * H;
#pragma unroll
    for (int p = 0; p < 4; ++p)
      ((float4*)sW)[t + p * 256] = ((const float4*)W_emb)[t + p * 256];
    int n0 = blockIdx.x * 32;
    {
      int row = t >> 3, k4 = (t & 7) * 4;
      *(float4*)(sX + row * 36 + k4) =
          *(const float4*)(x + (size_t)(n0 + row) * F_IN + k4);
    }
    __syncthreads();
    int nr = t >> 3, c = (t & 7) * 4;
    float4 a0 = make_float4(0,0,0,0), a1 = a0, a2 = a0, a3 = a0;
#pragma unroll 4
    for (int k = 0; k < F_IN; ++k) {
      float xv = sX[nr * 36 + k];
      const float* wp = sW + k * H + c;
      fma4(a0, xv, *(const float4*)(wp));
      fma4(a1, xv, *(const float4*)(wp + 32));
      fma4(a2, xv, *(const float4*)(wp + 64));
      fma4(a3, xv, *(const float4*)(wp + 96));
    }
    float4 b0 = *(const float4*)(b_emb + c);
    float4 b1 = *(const float4*)(b_emb + c + 32);
    float4 b2 = *(const float4*)(b_emb + c + 64);
    float4 b3 = *(const float4*)(b_emb + c + 96);
    a0.x += b0.x; a0.y += b0.y; a0.z += b0.z; a0.w += b0.w;
    a1.x += b1.x; a1.y += b1.y; a1.z += b1.z; a1.w += b1.w;
    a2.x += b2.x; a2.y += b2.y; a2.z += b2.z; a2.w += b2.w;
    a3.x += b3.x; a3.y += b3.y; a3.z += b3.z; a3.w += b3.w;
    unsigned short* hr = h + (size_t)(n0 + nr) * H + c;
    st_bf4(hr, a0); st_bf4(hr + 32, a1);
    st_bf4(hr + 64, a2); st_bf4(hr + 96, a3);
  } else {
    int* s = (int*)smem;
    int i = (blockIdx.x - EMB_BLKS) * 256 + t;
    int d = (i < N_NODES) ? deg[i] : 0;
    s[t] = d;
    __syncthreads();
#pragma unroll
    for (int off = 1; off < 256; off <<= 1) {
      int v = (t >= off) ? s[t - off] : 0;
      __syncthreads();
      s[t] += v;
      __syncthreads();
    }
    if (i < N_NODES) {
      offs[i] = s[t] - d;
      dinv[i] = rsqrtf((float)(d + 1));  // +1 self-loop
    }
    if (t == 255) parts[blockIdx.x - EMB_BLKS] = s[255];
  }
}

__global__ void k_scan_b(int* __restrict__ parts, int nparts) {
  __shared__ int s[512];
  int t = threadIdx.x;
  int d = (t < nparts) ? parts[t] : 0;
  s[t] = d;
  __syncthreads();
#pragma unroll
  for (int off = 1; off < 512; off <<= 1) {
    int v = (t >= off) ? s[t - off] : 0;
    __syncthreads();
    s[t] += v;
    __syncthreads();
  }
  if (t < nparts) parts[t] = s[t] - d;
}

__global__ void k_scan_c(int* __restrict__ offs, const int* __restrict__ parts) {
  int i = blockIdx.x * 256 + threadIdx.x;
  if (i < N_NODES) offs[i] += parts[blockIdx.x];
}

// ---------------- mm core: 64r x 64c block tile, wave = 32r x 32c ----------------
// B fragments (4q x 2ct x hi/lo = 16 short8 = 64 VGPR) hoisted to registers
// up-front so all 16 global gathers are in flight together (one drain),
// instead of per-q load->waitcnt->MFMA serialization (r7: 27k cyc/block).
struct MMAcc { f32x4 a[2][2]; };

__device__ __forceinline__ MMAcc mm_core(const unsigned short* __restrict__ A,
                                         const unsigned short* __restrict__ WhiT,
                                         const unsigned short* __restrict__ WloT,
                                         int n0, int c0, int t,
                                         unsigned short* sA) {
  int wave = t >> 6, lane = t & 63;
  int wr = wave >> 1, wc = wave & 1;
  int m = lane & 15, quad = (lane >> 4) & 3;
  // hoist all B frags
  short8 bh[4][2], bl[4][2];
#pragma unroll
  for (int q = 0; q < 4; ++q)
#pragma unroll
    for (int ct = 0; ct < 2; ++ct) {
      int n = c0 + wc * 32 + ct * 16 + m;
      bh[q][ct] = *(const short8*)(WhiT + n * H + q * 32 + quad * 8);
      bl[q][ct] = *(const short8*)(WloT + n * H + q * 32 + quad * 8);
    }
  // stage A (64 rows x 128 k bf16, row stride 136)
#pragma unroll
  for (int p = 0; p < 4; ++p) {
    int fi = t + p * 256;
    int row = fi >> 4, c8 = (fi & 15) * 8;
    int gn = n0 + row; if (gn >= N_NODES) gn = N_NODES - 1;
    *(uint4*)(sA + row * 136 + c8) = *(const uint4*)(A + (size_t)gn * H + c8);
  }
  __syncthreads();
  MMAcc r;
#pragma unroll
  for (int i = 0; i < 2; ++i)
#pragma unroll
    for (int j = 0; j < 2; ++j) r.a[i][j] = (f32x4){0.f, 0.f, 0.f, 0.f};
#pragma unroll
  for (int q = 0; q < 4; ++q) {
    short8 ah[2];
#pragma unroll
    for (int rt = 0; rt < 2; ++rt)
      ah[rt] = *(const short8*)(sA + (wr * 32 + rt * 16 + m) * 136 + q * 32 + quad * 8);
#pragma unroll
    for (int rt = 0; rt < 2; ++rt)
#pragma unroll
      for (int ct = 0; ct < 2; ++ct) {
        r.a[rt][ct] = __builtin_amdgcn_mfma_f32_16x16x32_bf16(ah[rt], bh[q][ct], r.a[rt][ct], 0, 0, 0);
        r.a[rt][ct] = __builtin_amdgcn_mfma_f32_16x16x32_bf16(ah[rt], bl[q][ct], r.a[rt][ct], 0, 0, 0);
      }
  }
  return r;
}

__device__ __forceinline__ void mm_store_fp8(const MMAcc& r, unsigned char* ht8,
                                             int n0, int c0, int t) {
  int wave = t >> 6, lane = t & 63;
  int wr = wave >> 1, wc = wave & 1;
  int m = lane & 15, quad = (lane >> 4) & 3;
#pragma unroll
  for (int rt = 0; rt < 2; ++rt)
#pragma unroll
    for (int ct = 0; ct < 2; ++ct) {
      int col = c0 + wc * 32 + ct * 16 + m;
#pragma unroll
      for (int rr = 0; rr < 4; ++rr) {
        int gn = n0 + wr * 32 + rt * 16 + quad * 4 + rr;
        if (gn < N_NODES) ht8[(size_t)gn * H + col] = f32_to_fp8(r.a[rt][ct][rr]);
      }
    }
}

// ---------------- fused fill | mm_L0 ----------------
__global__ __launch_bounds__(256) void k_fillmm(
    const int* __restrict__ ei, const unsigned char* __restrict__ ranks,
    const int* __restrict__ offs, const float* __restrict__ dinv,
    unsigned* __restrict__ csr,
    const unsigned short* __restrict__ A, const unsigned short* __restrict__ WhiT,
    const unsigned short* __restrict__ WloT, unsigned char* __restrict__ ht8) {
  __shared__ __align__(16) unsigned short sA[64 * 136];
  int t = threadIdx.x;
  if (blockIdx.x < FILL_BLKS) {
    int i = blockIdx.x * 256 + t;
    if (i < NEDGES / 4) {
      int4 s4 = *(const int4*)(ei + 4 * i);
      int4 d4 = *(const int4*)(ei + NEDGES + 4 * i);
      uchar4 r4 = ((const uchar4*)ranks)[i];
      int p0 = offs[d4.x] + r4.x;
      int p1 = offs[d4.y] + r4.y;
      int p2 = offs[d4.z] + r4.z;
      int p3 = offs[d4.w] + r4.w;
      // entry = (src<<15) | round(dinv[src]*32767)
      csr[p0] = ((unsigned)s4.x << 15) | (unsigned)(dinv[s4.x] * 32767.f + 0.5f);
      csr[p1] = ((unsigned)s4.y << 15) | (unsigned)(dinv[s4.y] * 32767.f + 0.5f);
      csr[p2] = ((unsigned)s4.z << 15) | (unsigned)(dinv[s4.z] * 32767.f + 0.5f);
      csr[p3] = ((unsigned)s4.w << 15) | (unsigned)(dinv[s4.w] * 32767.f + 0.5f);
    }
  } else {
    int j = blockIdx.x - FILL_BLKS;
    int n0 = (j >> 1) * 64, c0 = (j & 1) * 64;
    MMAcc r = mm_core(A, WhiT, WloT, n0, c0, t, sA);
    mm_store_fp8(r, ht8, n0, c0, t);
  }
}

__global__ __launch_bounds__(256) void k_mm(const unsigned short* __restrict__ A,
                                            const unsigned short* __restrict__ WhiT,
                                            const unsigned short* __restrict__ WloT,
                                            unsigned char* __restrict__ ht8) {
  __shared__ __align__(16) unsigned short sA[64 * 136];
  int j = blockIdx.x;
  int n0 = (j >> 1) * 64, c0 = (j & 1) * 64;
  MMAcc r = mm_core(A, WhiT, WloT, n0, c0, threadIdx.x, sA);
  mm_store_fp8(r, ht8, n0, c0, threadIdx.x);
}

// residual GEMM: resb = bf16(A @ Wres + bias)
__global__ __launch_bounds__(256) void k_mmr(const unsigned short* __restrict__ A,
                                             const unsigned short* __restrict__ WhiT,
                                             const unsigned short* __restrict__ WloT,
                                             const float* __restrict__ bias,
                                             unsigned short* __restrict__ resb) {
  __shared__ __align__(16) unsigned short sA[64 * 136];
  int j = blockIdx.x;
  int n0 = (j >> 1) * 64, c0 = (j & 1) * 64;
  int t = threadIdx.x;
  MMAcc r = mm_core(A, WhiT, WloT, n0, c0, t, sA);
  int wave = t >> 6, lane = t & 63;
  int wr = wave >> 1, wc = wave & 1;
  int m = lane & 15, quad = (lane >> 4) & 3;
#pragma unroll
  for (int rt = 0; rt < 2; ++rt)
#pragma unroll
    for (int ct = 0; ct < 2; ++ct) {
      int col = c0 + wc * 32 + ct * 16 + m;
      float bv = bias[col];
#pragma unroll
      for (int rr = 0; rr < 4; ++rr) {
        int gn = n0 + wr * 32 + rt * 16 + quad * 4 + rr;
        if (gn < N_NODES) resb[(size_t)gn * H + col] = f2bf(r.a[rt][ct][rr] + bv);
      }
    }
}

// ---------------- aggregate(fp8 ht) + bias + LN + relu + residual(bf16) ----------------
__global__ __launch_bounds__(256) void k_agg(
    const unsigned char* __restrict__ ht8, const unsigned short* __restrict__ res,
    const float* __restrict__ dinv, const int* __restrict__ offs,
    const int* __restrict__ deg, const unsigned* __restrict__ csr,
    const float* __restrict__ bias, const float* __restrict__ lng,
    const float* __restrict__ lnb, unsigned short* __restrict__ hout) {
  int wid = threadIdx.x >> 6, lane = threadIdx.x & 63;
  int node = blockIdx.x * 4 + wid;
  if (node >= N_NODES) return;
  int grp = lane >> 4, fl = lane & 15;
  int start = offs[node], cnt = deg[node];
  float di = dinv[node];
  const unsigned char* hb = ht8 + fl * 8;  // lane owns 8 fp8 feats
  float acc[8];
  {
    uint2 u = *(const uint2*)(hb + (size_t)node * 128);
    float sw = (grp == 0) ? di * di : 0.f;  // count self-loop once
    fv2 a = fp8x2<false>(u.x), b = fp8x2<true>(u.x);
    fv2 c = fp8x2<false>(u.y), d2 = fp8x2<true>(u.y);
    acc[0] = sw * a.x; acc[1] = sw * a.y;
    acc[2] = sw * b.x; acc[3] = sw * b.y;
    acc[4] = sw * c.x; acc[5] = sw * c.y;
    acc[6] = sw * d2.x; acc[7] = sw * d2.y;
  }
  float ddq = di * (1.f / 32767.f);
  for (int b0 = 0; b0 < cnt; b0 += 64) {
    int mm_ = min(64, cnt - b0);
    int s = 0; float w = 0.f;
    if (lane < mm_) {
      unsigned ev = csr[start + b0 + lane];
      s = (int)(ev >> 15);
      w = (float)(ev & 32767u) * ddq;
    }
#pragma unroll 2
    for (int e = 0; e < mm_; e += 4) {
      int ss = __shfl(s, e + grp, 64);
      float we = __shfl(w, e + grp, 64);
      uint2 u = *(const uint2*)(hb + (size_t)ss * 128);
      fv2 a = fp8x2<false>(u.x), b = fp8x2<true>(u.x);
      fv2 c = fp8x2<false>(u.y), d2 = fp8x2<true>(u.y);
      acc[0] = fmaf(we, a.x, acc[0]);
      acc[1] = fmaf(we, a.y, acc[1]);
      acc[2] = fmaf(we, b.x, acc[2]);
      acc[3] = fmaf(we, b.y, acc[3]);
      acc[4] = fmaf(we, c.x, acc[4]);
      acc[5] = fmaf(we, c.y, acc[5]);
      acc[6] = fmaf(we, d2.x, acc[6]);
      acc[7] = fmaf(we, d2.y, acc[7]);
    }
  }
#pragma unroll
  for (int j = 0; j < 8; ++j) {
    acc[j] += __shfl_xor(acc[j], 16, 64);
    acc[j] += __shfl_xor(acc[j], 32, 64);
  }
  float4 b0v = *(const float4*)(bias + fl * 8);
  float4 b1v = *(const float4*)(bias + fl * 8 + 4);
  acc[0] += b0v.x; acc[1] += b0v.y; acc[2] += b0v.z; acc[3] += b0v.w;
  acc[4] += b1v.x; acc[5] += b1v.y; acc[6] += b1v.z; acc[7] += b1v.w;
  float sl = ((acc[0] + acc[1]) + (acc[2] + acc[3])) +
             ((acc[4] + acc[5]) + (acc[6] + acc[7]));
#pragma unroll
  for (int mk = 1; mk <= 8; mk <<= 1) sl += __shfl_xor(sl, mk, 64);
  float mu = sl * (1.f / 128.f);
  float d[8];
  float vl = 0.f;
#pragma unroll
  for (int j = 0; j < 8; ++j) { d[j] = acc[j] - mu; vl = fmaf(d[j], d[j], vl); }
#pragma unroll
  for (int mk = 1; mk <= 8; mk <<= 1) vl += __shfl_xor(vl, mk, 64);
  float rs = rsqrtf(vl * (1.f / 128.f) + EPS);
  if (grp == 0) {
    float4 g0 = *(const float4*)(lng + fl * 8);
    float4 g1 = *(const float4*)(lng + fl * 8 + 4);
    float4 be0 = *(const float4*)(lnb + fl * 8);
    float4 be1 = *(const float4*)(lnb + fl * 8 + 4);
    uint4 rv = *(const uint4*)(res + (size_t)node * 128 + fl * 8);
    float o0 = fmaxf(fmaf(d[0] * rs, g0.x, be0.x), 0.f) + bflo(rv.x);
    float o1 = fmaxf(fmaf(d[1] * rs, g0.y, be0.y), 0.f) + bfhi(rv.x);
    float o2 = fmaxf(fmaf(d[2] * rs, g0.z, be0.z), 0.f) + bflo(rv.y);
    float o3 = fmaxf(fmaf(d[3] * rs, g0.w, be0.w), 0.f) + bfhi(rv.y);
    float o4 = fmaxf(fmaf(d[4] * rs, g1.x, be1.x), 0.f) + bflo(rv.z);
    float o5 = fmaxf(fmaf(d[5] * rs, g1.y, be1.y), 0.f) + bfhi(rv.z);
    float o6 = fmaxf(fmaf(d[6] * rs, g1.z, be1.z), 0.f) + bflo(rv.w);
    float o7 = fmaxf(fmaf(d[7] * rs, g1.w, be1.w), 0.f) + bfhi(rv.w);
    uint4 ov;
    ov.x = pack2(o0, o1); ov.y = pack2(o2, o3);
    ov.z = pack2(o4, o5); ov.w = pack2(o6, o7);
    *(uint4*)(hout + (size_t)node * 128 + fl * 8) = ov;
  }
}

// ---------------- mean pool (bf16 h) ----------------
__global__ void k_pool(const unsigned short* __restrict__ h, float* __restrict__ pool) {
  int f = threadIdx.x;  // 128
  float acc = 0.f;
  for (int n = blockIdx.x; n < N_NODES; n += gridDim.x)
    acc += bf2f(h[(size_t)n * H + f]);
  atomicAdd(&pool[f], acc);
}

// ---------------- head ----------------
__global__ void k_head(const float* __restrict__ pool, const float* __restrict__ Wfc1,
                       const float* __restrict__ bfc1, const float* __restrict__ g,
                       const float* __restrict__ bb, const float* __restrict__ Wfc2,
                       const float* __restrict__ bfc2, float* __restrict__ out) {
  __shared__ float sm[128], s1[128], stats[2];
  int t = threadIdx.x;
  if (t < 128) sm[t] = pool[t] * (1.f / (float)N_NODES);
  __syncthreads();
  if (t < 128) {
    float a = bfc1[t];
    for (int k = 0; k < 128; ++k) a = fmaf(sm[k], Wfc1[k * 128 + t], a);
    s1[t] = a;
  }
  __syncthreads();
  if (t == 0) {
    float mu = 0.f;
    for (int k = 0; k < 128; ++k) mu += s1[k];
    mu *= (1.f / 128.f);
    float var = 0.f;
    for (int k = 0; k < 128; ++k) { float d = s1[k] - mu; var += d * d; }
    var *= (1.f / 128.f);
    stats[0] = mu; stats[1] = rsqrtf(var + EPS);
  }
  __syncthreads();
  if (t < 128) s1[t] = fmaxf((s1[t] - stats[0]) * stats[1] * g[t] + bb[t], 0.f);
  __syncthreads();
  if (t < OUT_F) {
    float a = bfc2[t];
    for (int k = 0; k < 128; ++k) a = fmaf(s1[k], Wfc2[k * OUT_F + t], a);
    out[t] = a;
  }
}

extern "C" void kernel_launch(void* const* d_in, const int* in_sizes, int n_in,
                              void* d_out, int out_size, void* d_ws, size_t ws_size,
                              hipStream_t stream) {
  const float* x      = (const float*)d_in[0];
  const int*   ei     = (const int*)d_in[1];
  const float* W_emb  = (const float*)d_in[2];
  const float* b_emb  = (const float*)d_in[3];
  const float* W_conv = (const float*)d_in[4];
  const float* b_conv = (const float*)d_in[5];
  const float* ln_g   = (const float*)d_in[6];
  const float* ln_b   = (const float*)d_in[7];
  const float* W_res  = (const float*)d_in[8];
  const float* b_res  = (const float*)d_in[9];
  const float* W_fc1  = (const float*)d_in[10];
  const float* b_fc1  = (const float*)d_in[11];
  const float* fcn_g  = (const float*)d_in[12];
  const float* fcn_b  = (const float*)d_in[13];
  const float* W_fc2  = (const float*)d_in[14];
  const float* b_fc2  = (const float*)d_in[15];
  float* out = (float*)d_out;

  char* p = (char*)d_ws;
  auto take = [&](size_t bytes) {
    char* r = p; p += (bytes + 255) & ~(size_t)255; return r;
  };
  unsigned short* bufA = (unsigned short*)take((size_t)N_NODES * H * 2);
  unsigned short* bufB = (unsigned short*)take((size_t)N_NODES * H * 2);
  unsigned short* bufC = (unsigned short*)take((size_t)N_NODES * H * 2);
  unsigned char*  ht8  = (unsigned char*)take((size_t)N_NODES * H);
  unsigned short* whiT = (unsigned short*)take((size_t)5 * H * H * 2);
  unsigned short* wloT = (unsigned short*)take((size_t)5 * H * H * 2);
  int*   deg  = (int*)take(N_NODES * 4);
  int*   offs = (int*)take(N_NODES * 4);
  int*   parts= (int*)take(512 * 4);
  float* dinv = (float*)take(N_NODES * 4);
  unsigned char* ranks = (unsigned char*)take(NEDGES);
  unsigned* csr = (unsigned*)take((size_t)NEDGES * 4);
  float* pool = (float*)take(128 * 4);

  (void)hipMemsetAsync(deg, 0, N_NODES * 4, stream);
  (void)hipMemsetAsync(pool, 0, 128 * 4, stream);

  k_hw<<<HIST8_BLKS + WS_BLKS, 256, 0, stream>>>(ei, deg, ranks, W_conv, W_res,
                                                 whiT, wloT);
  k_embed_scan<<<EMB_BLKS + NPARTS, 256, 0, stream>>>(x, W_emb, b_emb, bufA,
                                                      deg, offs, parts, dinv);
  k_scan_b<<<1, 512, 0, stream>>>(parts, NPARTS);
  k_scan_c<<<NPARTS, 256, 0, stream>>>(offs, parts);
  k_fillmm<<<FILL_BLKS + MM_BLKS, 256, 0, stream>>>(
      ei, ranks, offs, dinv, csr, bufA, whiT + 0 * H * H, wloT + 0 * H * H, ht8);

  int aggg = (N_NODES + 3) / 4;
  // L0: res=A -> h1=C
  k_agg<<<aggg, 256, 0, stream>>>(ht8, bufA, dinv, offs, deg, csr,
                                  b_conv + 0 * H, ln_g + 0 * H, ln_b + 0 * H, bufC);
  // L1: h1=C -> ht8 -> h2=A (res=C)
  k_mm<<<MM_BLKS, 256, 0, stream>>>(bufC, whiT + 1 * H * H, wloT + 1 * H * H, ht8);
  k_agg<<<aggg, 256, 0, stream>>>(ht8, bufC, dinv, offs, deg, csr,
                                  b_conv + 1 * H, ln_g + 1 * H, ln_b + 1 * H, bufA);
  // L2: h2=A; ht8=A@W2; B=bf16(A@Wres+bres); agg -> h3=C (res=B)
  k_mmr<<<MM_BLKS, 256, 0, stream>>>(bufA, whiT + 4 * H * H, wloT + 4 * H * H,
                                     b_res, bufB);
  k_mm<<<MM_BLKS, 256, 0, stream>>>(bufA, whiT + 2 * H * H, wloT + 2 * H * H, ht8);
  k_agg<<<aggg, 256, 0, stream>>>(ht8, bufB, dinv, offs, deg, csr,
                                  b_conv + 2 * H, ln_g + 2 * H, ln_b + 2 * H, bufC);
  // L3: h3=C -> ht8 -> h4=A (res=C)
  k_mm<<<MM_BLKS, 256, 0, stream>>>(bufC, whiT + 3 * H * H, wloT + 3 * H * H, ht8);
  k_agg<<<aggg, 256, 0, stream>>>(ht8, bufC, dinv, offs, deg, csr,
                                  b_conv + 3 * H, ln_g + 3 * H, ln_b + 3 * H, bufA);

  k_pool<<<512, 128, 0, stream>>>(bufA, pool);
  k_head<<<1, 256, 0, stream>>>(pool, W_fc1, b_fc1, fcn_g, fcn_b,
                                W_fc2, b_fc2, out);
}

// Round 9
// 630.101 us; speedup vs baseline: 1.9250x; 1.0969x over previous
//
#include <hip/hip_runtime.h>

constexpr int N_NODES = 100000;
constexpr int F_IN    = 32;
constexpr int H       = 128;
constexpr int OUT_F   = 200;
constexpr int NEDGES  = 1600000;
constexpr float EPS   = 1e-5f;

constexpr int HIST8_BLKS = (NEDGES / 8 + 255) / 256;  // 782
constexpr int WS_BLKS    = 80;                        // 5*128*128/1024
constexpr int EMB_BLKS   = N_NODES / 32;              // 3125 (exact)
constexpr int NPARTS     = (N_NODES + 255) / 256;     // 391
constexpr int FILL_BLKS  = (NEDGES / 4 + 255) / 256;  // 1563
constexpr int MMROW_BLKS = (N_NODES + 63) / 64;       // 1563
constexpr int MM_BLKS    = MMROW_BLKS * 2;            // 3126 (64r x 64c tiles)

typedef __attribute__((ext_vector_type(8))) short  short8;
typedef __attribute__((ext_vector_type(4))) float  f32x4;
typedef __attribute__((ext_vector_type(2))) float  fv2;

__device__ __forceinline__ void fma4(float4& a, float s, const float4& w) {
  a.x = fmaf(s, w.x, a.x); a.y = fmaf(s, w.y, a.y);
  a.z = fmaf(s, w.z, a.z); a.w = fmaf(s, w.w, a.w);
}

__device__ __forceinline__ unsigned short f2bf(float f) {  // RNE
  union { float f; unsigned u; } v; v.f = f;
  unsigned r = v.u + 0x7fffu + ((v.u >> 16) & 1u);
  return (unsigned short)(r >> 16);
}
__device__ __forceinline__ float bf2f(unsigned short s) {
  union { unsigned u; float f; } v; v.u = ((unsigned)s) << 16;
  return v.f;
}
__device__ __forceinline__ float bflo(unsigned u) { return __uint_as_float(u << 16); }
__device__ __forceinline__ float bfhi(unsigned u) { return __uint_as_float(u & 0xffff0000u); }
__device__ __forceinline__ unsigned pack2(float lo, float hi) {
  return (unsigned)f2bf(lo) | ((unsigned)f2bf(hi) << 16);
}
__device__ __forceinline__ void st_bf4(unsigned short* p, float4 v) {
  uint2 o; o.x = pack2(v.x, v.y); o.y = pack2(v.z, v.w);
  *(uint2*)p = o;
}

// ---------------- fp8 e4m3fn helpers (native cvt, manual fallback) ----------------
#if __has_builtin(__builtin_amdgcn_cvt_pk_f32_fp8) && __has_builtin(__builtin_amdgcn_cvt_pk_fp8_f32)
#define HAVE_FP8_CVT 1
#endif

#ifndef HAVE_FP8_CVT
__device__ __forceinline__ float fp8_dec1(unsigned b) {
  unsigned s = (b >> 7) & 1u, E = (b >> 3) & 15u, m = b & 7u;
  float v;
  if (E) {
    union { unsigned u; float f; } t;
    t.u = (s << 31) | ((E + 120u) << 23) | (m << 20);
    v = t.f;
  } else {
    v = (s ? -1.f : 1.f) * (float)m * 0.001953125f;  // m * 2^-9
  }
  return v;
}
#endif

template <bool HI>
__device__ __forceinline__ fv2 fp8x2(unsigned u) {
#ifdef HAVE_FP8_CVT
  return __builtin_amdgcn_cvt_pk_f32_fp8((int)u, HI);  // word_sel is ICE via template
#else
  unsigned p = HI ? (u >> 16) : u;
  fv2 r; r.x = fp8_dec1(p & 0xffu); r.y = fp8_dec1((p >> 8) & 0xffu);
  return r;
#endif
}

__device__ __forceinline__ unsigned char f32_to_fp8(float f) {
#ifdef HAVE_FP8_CVT
  return (unsigned char)(__builtin_amdgcn_cvt_pk_fp8_f32(f, f, 0, false) & 0xff);
#else
  union { float f; unsigned u; } t; t.f = f;
  unsigned s = t.u >> 31;
  float a = fabsf(f);
  if (a > 448.f) a = 448.f;
  t.f = a;
  int e = (int)((t.u >> 23) & 0xff) - 127;
  unsigned char r;
  if (a == 0.f) {
    r = 0;
  } else if (e >= -6) {
    unsigned m = t.u & 0x7fffffu;
    unsigned keep = m >> 20, rest = m & 0xfffffu;
    keep += (rest > 0x80000u) || (rest == 0x80000u && (keep & 1u));
    int E = e + 7;
    if (keep == 8u) { keep = 0u; E += 1; }
    if (E >= 16) { E = 15; keep = 6u; }
    r = (unsigned char)((E << 3) | keep);
  } else {
    int mi = (int)(a * 512.f + 0.5f);
    r = (mi > 7) ? (unsigned char)(1u << 3) : (unsigned char)mi;
  }
  return (unsigned char)(r | (s << 7));
#endif
}

// ---------------- k_pre2: hist(+ranks) | embed(bf16) | wsplit(hi only) ----------------
// hist blocks first (dispatch immediately); embed's 3125 blocks pack behind
// and keep the CU's wave slots full while the 1.6M returning atomics drain.
__global__ __launch_bounds__(256) void k_pre2(
    const int* __restrict__ ei, int* __restrict__ deg,
    unsigned char* __restrict__ ranks,
    const float* __restrict__ x, const float* __restrict__ W_emb,
    const float* __restrict__ b_emb, unsigned short* __restrict__ h,
    const float* __restrict__ W_conv, const float* __restrict__ W_res,
    unsigned short* __restrict__ whiT) {
  __shared__ __align__(16) float smem[F_IN * H + 32 * 36];
  int t = threadIdx.x;
  if (blockIdx.x < HIST8_BLKS) {
    int i = blockIdx.x * 256 + t;
    if (i < NEDGES / 8) {
      int4 a = *(const int4*)(ei + NEDGES + 8 * i);
      int4 b = *(const int4*)(ei + NEDGES + 8 * i + 4);
      union { unsigned char c[8]; uint2 u; } rr;
      rr.c[0] = (unsigned char)atomicAdd(&deg[a.x], 1);
      rr.c[1] = (unsigned char)atomicAdd(&deg[a.y], 1);
      rr.c[2] = (unsigned char)atomicAdd(&deg[a.z], 1);
      rr.c[3] = (unsigned char)atomicAdd(&deg[a.w], 1);
      rr.c[4] = (unsigned char)atomicAdd(&deg[b.x], 1);
      rr.c[5] = (unsigned char)atomicAdd(&deg[b.y], 1);
      rr.c[6] = (unsigned char)atomicAdd(&deg[b.z], 1);
      rr.c[7] = (unsigned char)atomicAdd(&deg[b.w], 1);
      ((uint2*)ranks)[i] = rr.u;
    }
  } else if (blockIdx.x < HIST8_BLKS + EMB_BLKS) {
    float* sW = smem;
    float* sX = smem + F_IN * H;
#pragma unroll
    for (int p = 0; p < 4; ++p)
      ((float4*)sW)[t + p * 256] = ((const float4*)W_emb)[t + p * 256];
    int n0 = (blockIdx.x - HIST8_BLKS) * 32;
    {
      int row = t >> 3, k4 = (t & 7) * 4;
      *(float4*)(sX + row * 36 + k4) =
          *(const float4*)(x + (size_t)(n0 + row) * F_IN + k4);
    }
    __syncthreads();
    int nr = t >> 3, c = (t & 7) * 4;
    float4 a0 = make_float4(0,0,0,0), a1 = a0, a2 = a0, a3 = a0;
#pragma unroll 4
    for (int k = 0; k < F_IN; ++k) {
      float xv = sX[nr * 36 + k];
      const float* wp = sW + k * H + c;
      fma4(a0, xv, *(const float4*)(wp));
      fma4(a1, xv, *(const float4*)(wp + 32));
      fma4(a2, xv, *(const float4*)(wp + 64));
      fma4(a3, xv, *(const float4*)(wp + 96));
    }
    float4 b0 = *(const float4*)(b_emb + c);
    float4 b1 = *(const float4*)(b_emb + c + 32);
    float4 b2 = *(const float4*)(b_emb + c + 64);
    float4 b3 = *(const float4*)(b_emb + c + 96);
    a0.x += b0.x; a0.y += b0.y; a0.z += b0.z; a0.w += b0.w;
    a1.x += b1.x; a1.y += b1.y; a1.z += b1.z; a1.w += b1.w;
    a2.x += b2.x; a2.y += b2.y; a2.z += b2.z; a2.w += b2.w;
    a3.x += b3.x; a3.y += b3.y; a3.z += b3.z; a3.w += b3.w;
    unsigned short* hr = h + (size_t)(n0 + nr) * H + c;
    st_bf4(hr, a0); st_bf4(hr + 32, a1);
    st_bf4(hr + 64, a2); st_bf4(hr + 96, a3);
  } else {
    int base = (blockIdx.x - HIST8_BLKS - EMB_BLKS) * 1024;
#pragma unroll
    for (int j = 0; j < 4; ++j) {
      int idx = base + j * 256 + t;
      if (idx < 5 * H * H) {
        int m = idx >> 14, rr = idx & 16383;
        int k = rr >> 7, n = rr & 127;
        const float* src = (m < 4) ? (W_conv + m * H * H) : W_res;
        whiT[m * H * H + n * H + k] = f2bf(src[k * H + n]);
      }
    }
  }
}

// ---------------- scans ----------------
__global__ void k_scan_a(const int* __restrict__ deg, int* __restrict__ offs,
                         int* __restrict__ parts, float* __restrict__ dinv) {
  __shared__ int s[256];
  int i = blockIdx.x * 256 + threadIdx.x;
  int d = (i < N_NODES) ? deg[i] : 0;
  s[threadIdx.x] = d;
  __syncthreads();
#pragma unroll
  for (int off = 1; off < 256; off <<= 1) {
    int v = (threadIdx.x >= off) ? s[threadIdx.x - off] : 0;
    __syncthreads();
    s[threadIdx.x] += v;
    __syncthreads();
  }
  if (i < N_NODES) {
    offs[i] = s[threadIdx.x] - d;
    dinv[i] = rsqrtf((float)(d + 1));  // +1 self-loop
  }
  if (threadIdx.x == 255) parts[blockIdx.x] = s[255];
}

__global__ void k_scan_b(int* __restrict__ parts, int nparts) {
  __shared__ int s[512];
  int t = threadIdx.x;
  int d = (t < nparts) ? parts[t] : 0;
  s[t] = d;
  __syncthreads();
#pragma unroll
  for (int off = 1; off < 512; off <<= 1) {
    int v = (t >= off) ? s[t - off] : 0;
    __syncthreads();
    s[t] += v;
    __syncthreads();
  }
  if (t < nparts) parts[t] = s[t] - d;
}

__global__ void k_scan_c(int* __restrict__ offs, const int* __restrict__ parts) {
  int i = blockIdx.x * 256 + threadIdx.x;
  if (i < N_NODES) offs[i] += parts[blockIdx.x];
}

// ---------------- mm core: 64r x 64c tile, wave = 32r x 32c, single-pass bf16 ----------------
// W is RNE bf16 (err <= 2^-9 rel, an order below the fp8 message quantization
// already in the loop). B frags hoisted (8 short8 = 32 VGPR, one drain).
struct MMAcc { f32x4 a[2][2]; };

__device__ __forceinline__ MMAcc mm_core(const unsigned short* __restrict__ A,
                                         const unsigned short* __restrict__ WhiT,
                                         int n0, int c0, int t,
                                         unsigned short* sA) {
  int wave = t >> 6, lane = t & 63;
  int wr = wave >> 1, wc = wave & 1;
  int m = lane & 15, quad = (lane >> 4) & 3;
  short8 bh[4][2];
#pragma unroll
  for (int q = 0; q < 4; ++q)
#pragma unroll
    for (int ct = 0; ct < 2; ++ct) {
      int n = c0 + wc * 32 + ct * 16 + m;
      bh[q][ct] = *(const short8*)(WhiT + n * H + q * 32 + quad * 8);
    }
#pragma unroll
  for (int p = 0; p < 4; ++p) {
    int fi = t + p * 256;
    int row = fi >> 4, c8 = (fi & 15) * 8;
    int gn = n0 + row; if (gn >= N_NODES) gn = N_NODES - 1;
    *(uint4*)(sA + row * 136 + c8) = *(const uint4*)(A + (size_t)gn * H + c8);
  }
  __syncthreads();
  MMAcc r;
#pragma unroll
  for (int i = 0; i < 2; ++i)
#pragma unroll
    for (int j = 0; j < 2; ++j) r.a[i][j] = (f32x4){0.f, 0.f, 0.f, 0.f};
#pragma unroll
  for (int q = 0; q < 4; ++q) {
    short8 ah[2];
#pragma unroll
    for (int rt = 0; rt < 2; ++rt)
      ah[rt] = *(const short8*)(sA + (wr * 32 + rt * 16 + m) * 136 + q * 32 + quad * 8);
#pragma unroll
    for (int rt = 0; rt < 2; ++rt)
#pragma unroll
      for (int ct = 0; ct < 2; ++ct)
        r.a[rt][ct] = __builtin_amdgcn_mfma_f32_16x16x32_bf16(ah[rt], bh[q][ct], r.a[rt][ct], 0, 0, 0);
  }
  return r;
}

__device__ __forceinline__ void mm_store_fp8(const MMAcc& r, unsigned char* ht8,
                                             int n0, int c0, int t) {
  int wave = t >> 6, lane = t & 63;
  int wr = wave >> 1, wc = wave & 1;
  int m = lane & 15, quad = (lane >> 4) & 3;
#pragma unroll
  for (int rt = 0; rt < 2; ++rt)
#pragma unroll
    for (int ct = 0; ct < 2; ++ct) {
      int col = c0 + wc * 32 + ct * 16 + m;
#pragma unroll
      for (int rr = 0; rr < 4; ++rr) {
        int gn = n0 + wr * 32 + rt * 16 + quad * 4 + rr;
        if (gn < N_NODES) ht8[(size_t)gn * H + col] = f32_to_fp8(r.a[rt][ct][rr]);
      }
    }
}

// ---------------- fused fill | mm_L0 ----------------
__global__ __launch_bounds__(256) void k_fillmm(
    const int* __restrict__ ei, const unsigned char* __restrict__ ranks,
    const int* __restrict__ offs, const float* __restrict__ dinv,
    unsigned* __restrict__ csr,
    const unsigned short* __restrict__ A, const unsigned short* __restrict__ WhiT,
    unsigned char* __restrict__ ht8) {
  __shared__ __align__(16) unsigned short sA[64 * 136];
  int t = threadIdx.x;
  if (blockIdx.x < FILL_BLKS) {
    int i = blockIdx.x * 256 + t;
    if (i < NEDGES / 4) {
      int4 s4 = *(const int4*)(ei + 4 * i);
      int4 d4 = *(const int4*)(ei + NEDGES + 4 * i);
      uchar4 r4 = ((const uchar4*)ranks)[i];
      int p0 = offs[d4.x] + r4.x;
      int p1 = offs[d4.y] + r4.y;
      int p2 = offs[d4.z] + r4.z;
      int p3 = offs[d4.w] + r4.w;
      // entry = (src<<15) | round(dinv[src]*32767)
      csr[p0] = ((unsigned)s4.x << 15) | (unsigned)(dinv[s4.x] * 32767.f + 0.5f);
      csr[p1] = ((unsigned)s4.y << 15) | (unsigned)(dinv[s4.y] * 32767.f + 0.5f);
      csr[p2] = ((unsigned)s4.z << 15) | (unsigned)(dinv[s4.z] * 32767.f + 0.5f);
      csr[p3] = ((unsigned)s4.w << 15) | (unsigned)(dinv[s4.w] * 32767.f + 0.5f);
    }
  } else {
    int j = blockIdx.x - FILL_BLKS;
    int n0 = (j >> 1) * 64, c0 = (j & 1) * 64;
    MMAcc r = mm_core(A, WhiT, n0, c0, t, sA);
    mm_store_fp8(r, ht8, n0, c0, t);
  }
}

__global__ __launch_bounds__(256) void k_mm(const unsigned short* __restrict__ A,
                                            const unsigned short* __restrict__ WhiT,
                                            unsigned char* __restrict__ ht8) {
  __shared__ __align__(16) unsigned short sA[64 * 136];
  int j = blockIdx.x;
  int n0 = (j >> 1) * 64, c0 = (j & 1) * 64;
  MMAcc r = mm_core(A, WhiT, n0, c0, threadIdx.x, sA);
  mm_store_fp8(r, ht8, n0, c0, threadIdx.x);
}

// residual GEMM: resb = bf16(A @ Wres + bias)
__global__ __launch_bounds__(256) void k_mmr(const unsigned short* __restrict__ A,
                                             const unsigned short* __restrict__ WhiT,
                                             const float* __restrict__ bias,
                                             unsigned short* __restrict__ resb) {
  __shared__ __align__(16) unsigned short sA[64 * 136];
  int j = blockIdx.x;
  int n0 = (j >> 1) * 64, c0 = (j & 1) * 64;
  int t = threadIdx.x;
  MMAcc r = mm_core(A, WhiT, n0, c0, t, sA);
  int wave = t >> 6, lane = t & 63;
  int wr = wave >> 1, wc = wave & 1;
  int m = lane & 15, quad = (lane >> 4) & 3;
#pragma unroll
  for (int rt = 0; rt < 2; ++rt)
#pragma unroll
    for (int ct = 0; ct < 2; ++ct) {
      int col = c0 + wc * 32 + ct * 16 + m;
      float bv = bias[col];
#pragma unroll
      for (int rr = 0; rr < 4; ++rr) {
        int gn = n0 + wr * 32 + rt * 16 + quad * 4 + rr;
        if (gn < N_NODES) resb[(size_t)gn * H + col] = f2bf(r.a[rt][ct][rr] + bv);
      }
    }
}

// ---------------- aggregate(fp8 ht) + bias + LN + relu + residual(bf16) ----------------
__global__ __launch_bounds__(256) void k_agg(
    const unsigned char* __restrict__ ht8, const unsigned short* __restrict__ res,
    const float* __restrict__ dinv, const int* __restrict__ offs,
    const int* __restrict__ deg, const unsigned* __restrict__ csr,
    const float* __restrict__ bias, const float* __restrict__ lng,
    const float* __restrict__ lnb, unsigned short* __restrict__ hout) {
  int wid = threadIdx.x >> 6, lane = threadIdx.x & 63;
  int node = blockIdx.x * 4 + wid;
  if (node >= N_NODES) return;
  int grp = lane >> 4, fl = lane & 15;
  int start = offs[node], cnt = deg[node];
  float di = dinv[node];
  const unsigned char* hb = ht8 + fl * 8;  // lane owns 8 fp8 feats
  float acc[8];
  {
    uint2 u = *(const uint2*)(hb + (size_t)node * 128);
    float sw = (grp == 0) ? di * di : 0.f;  // count self-loop once
    fv2 a = fp8x2<false>(u.x), b = fp8x2<true>(u.x);
    fv2 c = fp8x2<false>(u.y), d2 = fp8x2<true>(u.y);
    acc[0] = sw * a.x; acc[1] = sw * a.y;
    acc[2] = sw * b.x; acc[3] = sw * b.y;
    acc[4] = sw * c.x; acc[5] = sw * c.y;
    acc[6] = sw * d2.x; acc[7] = sw * d2.y;
  }
  float ddq = di * (1.f / 32767.f);
  for (int b0 = 0; b0 < cnt; b0 += 64) {
    int mm_ = min(64, cnt - b0);
    int s = 0; float w = 0.f;
    if (lane < mm_) {
      unsigned ev = csr[start + b0 + lane];
      s = (int)(ev >> 15);
      w = (float)(ev & 32767u) * ddq;
    }
#pragma unroll 2
    for (int e = 0; e < mm_; e += 4) {
      int ss = __shfl(s, e + grp, 64);
      float we = __shfl(w, e + grp, 64);
      uint2 u = *(const uint2*)(hb + (size_t)ss * 128);
      fv2 a = fp8x2<false>(u.x), b = fp8x2<true>(u.x);
      fv2 c = fp8x2<false>(u.y), d2 = fp8x2<true>(u.y);
      acc[0] = fmaf(we, a.x, acc[0]);
      acc[1] = fmaf(we, a.y, acc[1]);
      acc[2] = fmaf(we, b.x, acc[2]);
      acc[3] = fmaf(we, b.y, acc[3]);
      acc[4] = fmaf(we, c.x, acc[4]);
      acc[5] = fmaf(we, c.y, acc[5]);
      acc[6] = fmaf(we, d2.x, acc[6]);
      acc[7] = fmaf(we, d2.y, acc[7]);
    }
  }
#pragma unroll
  for (int j = 0; j < 8; ++j) {
    acc[j] += __shfl_xor(acc[j], 16, 64);
    acc[j] += __shfl_xor(acc[j], 32, 64);
  }
  float4 b0v = *(const float4*)(bias + fl * 8);
  float4 b1v = *(const float4*)(bias + fl * 8 + 4);
  acc[0] += b0v.x; acc[1] += b0v.y; acc[2] += b0v.z; acc[3] += b0v.w;
  acc[4] += b1v.x; acc[5] += b1v.y; acc[6] += b1v.z; acc[7] += b1v.w;
  float sl = ((acc[0] + acc[1]) + (acc[2] + acc[3])) +
             ((acc[4] + acc[5]) + (acc[6] + acc[7]));
#pragma unroll
  for (int mk = 1; mk <= 8; mk <<= 1) sl += __shfl_xor(sl, mk, 64);
  float mu = sl * (1.f / 128.f);
  float d[8];
  float vl = 0.f;
#pragma unroll
  for (int j = 0; j < 8; ++j) { d[j] = acc[j] - mu; vl = fmaf(d[j], d[j], vl); }
#pragma unroll
  for (int mk = 1; mk <= 8; mk <<= 1) vl += __shfl_xor(vl, mk, 64);
  float rs = rsqrtf(vl * (1.f / 128.f) + EPS);
  if (grp == 0) {
    float4 g0 = *(const float4*)(lng + fl * 8);
    float4 g1 = *(const float4*)(lng + fl * 8 + 4);
    float4 be0 = *(const float4*)(lnb + fl * 8);
    float4 be1 = *(const float4*)(lnb + fl * 8 + 4);
    uint4 rv = *(const uint4*)(res + (size_t)node * 128 + fl * 8);
    float o0 = fmaxf(fmaf(d[0] * rs, g0.x, be0.x), 0.f) + bflo(rv.x);
    float o1 = fmaxf(fmaf(d[1] * rs, g0.y, be0.y), 0.f) + bfhi(rv.x);
    float o2 = fmaxf(fmaf(d[2] * rs, g0.z, be0.z), 0.f) + bflo(rv.y);
    float o3 = fmaxf(fmaf(d[3] * rs, g0.w, be0.w), 0.f) + bfhi(rv.y);
    float o4 = fmaxf(fmaf(d[4] * rs, g1.x, be1.x), 0.f) + bflo(rv.z);
    float o5 = fmaxf(fmaf(d[5] * rs, g1.y, be1.y), 0.f) + bfhi(rv.z);
    float o6 = fmaxf(fmaf(d[6] * rs, g1.z, be1.z), 0.f) + bflo(rv.w);
    float o7 = fmaxf(fmaf(d[7] * rs, g1.w, be1.w), 0.f) + bfhi(rv.w);
    uint4 ov;
    ov.x = pack2(o0, o1); ov.y = pack2(o2, o3);
    ov.z = pack2(o4, o5); ov.w = pack2(o6, o7);
    *(uint4*)(hout + (size_t)node * 128 + fl * 8) = ov;
  }
}

// ---------------- mean pool (bf16 h) ----------------
__global__ void k_pool(const unsigned short* __restrict__ h, float* __restrict__ pool) {
  int f = threadIdx.x;  // 128
  float acc = 0.f;
  for (int n = blockIdx.x; n < N_NODES; n += gridDim.x)
    acc += bf2f(h[(size_t)n * H + f]);
  atomicAdd(&pool[f], acc);
}

// ---------------- head ----------------
__global__ void k_head(const float* __restrict__ pool, const float* __restrict__ Wfc1,
                       const float* __restrict__ bfc1, const float* __restrict__ g,
                       const float* __restrict__ bb, const float* __restrict__ Wfc2,
                       const float* __restrict__ bfc2, float* __restrict__ out) {
  __shared__ float sm[128], s1[128], stats[2];
  int t = threadIdx.x;
  if (t < 128) sm[t] = pool[t] * (1.f / (float)N_NODES);
  __syncthreads();
  if (t < 128) {
    float a = bfc1[t];
    for (int k = 0; k < 128; ++k) a = fmaf(sm[k], Wfc1[k * 128 + t], a);
    s1[t] = a;
  }
  __syncthreads();
  if (t == 0) {
    float mu = 0.f;
    for (int k = 0; k < 128; ++k) mu += s1[k];
    mu *= (1.f / 128.f);
    float var = 0.f;
    for (int k = 0; k < 128; ++k) { float d = s1[k] - mu; var += d * d; }
    var *= (1.f / 128.f);
    stats[0] = mu; stats[1] = rsqrtf(var + EPS);
  }
  __syncthreads();
  if (t < 128) s1[t] = fmaxf((s1[t] - stats[0]) * stats[1] * g[t] + bb[t], 0.f);
  __syncthreads();
  if (t < OUT_F) {
    float a = bfc2[t];
    for (int k = 0; k < 128; ++k) a = fmaf(s1[k], Wfc2[k * OUT_F + t], a);
    out[t] = a;
  }
}

extern "C" void kernel_launch(void* const* d_in, const int* in_sizes, int n_in,
                              void* d_out, int out_size, void* d_ws, size_t ws_size,
                              hipStream_t stream) {
  const float* x      = (const float*)d_in[0];
  const int*   ei     = (const int*)d_in[1];
  const float* W_emb  = (const float*)d_in[2];
  const float* b_emb  = (const float*)d_in[3];
  const float* W_conv = (const float*)d_in[4];
  const float* b_conv = (const float*)d_in[5];
  const float* ln_g   = (const float*)d_in[6];
  const float* ln_b   = (const float*)d_in[7];
  const float* W_res  = (const float*)d_in[8];
  const float* b_res  = (const float*)d_in[9];
  const float* W_fc1  = (const float*)d_in[10];
  const float* b_fc1  = (const float*)d_in[11];
  const float* fcn_g  = (const float*)d_in[12];
  const float* fcn_b  = (const float*)d_in[13];
  const float* W_fc2  = (const float*)d_in[14];
  const float* b_fc2  = (const float*)d_in[15];
  float* out = (float*)d_out;

  char* p = (char*)d_ws;
  auto take = [&](size_t bytes) {
    char* r = p; p += (bytes + 255) & ~(size_t)255; return r;
  };
  unsigned short* bufA = (unsigned short*)take((size_t)N_NODES * H * 2);
  unsigned short* bufB = (unsigned short*)take((size_t)N_NODES * H * 2);
  unsigned short* bufC = (unsigned short*)take((size_t)N_NODES * H * 2);
  unsigned char*  ht8  = (unsigned char*)take((size_t)N_NODES * H);
  unsigned short* whiT = (unsigned short*)take((size_t)5 * H * H * 2);
  int*   deg  = (int*)take(N_NODES * 4);
  int*   offs = (int*)take(N_NODES * 4);
  int*   parts= (int*)take(512 * 4);
  float* dinv = (float*)take(N_NODES * 4);
  unsigned char* ranks = (unsigned char*)take(NEDGES);
  unsigned* csr = (unsigned*)take((size_t)NEDGES * 4);
  float* pool = (float*)take(128 * 4);

  (void)hipMemsetAsync(deg, 0, N_NODES * 4, stream);
  (void)hipMemsetAsync(pool, 0, 128 * 4, stream);

  k_pre2<<<HIST8_BLKS + EMB_BLKS + WS_BLKS, 256, 0, stream>>>(
      ei, deg, ranks, x, W_emb, b_emb, bufA, W_conv, W_res, whiT);
  k_scan_a<<<NPARTS, 256, 0, stream>>>(deg, offs, parts, dinv);
  k_scan_b<<<1, 512, 0, stream>>>(parts, NPARTS);
  k_scan_c<<<NPARTS, 256, 0, stream>>>(offs, parts);
  k_fillmm<<<FILL_BLKS + MM_BLKS, 256, 0, stream>>>(
      ei, ranks, offs, dinv, csr, bufA, whiT + 0 * H * H, ht8);

  int aggg = (N_NODES + 3) / 4;
  // L0: res=A -> h1=C
  k_agg<<<aggg, 256, 0, stream>>>(ht8, bufA, dinv, offs, deg, csr,
                                  b_conv + 0 * H, ln_g + 0 * H, ln_b + 0 * H, bufC);
  // L1: h1=C -> ht8 -> h2=A (res=C)
  k_mm<<<MM_BLKS, 256, 0, stream>>>(bufC, whiT + 1 * H * H, ht8);
  k_agg<<<aggg, 256, 0, stream>>>(ht8, bufC, dinv, offs, deg, csr,
                                  b_conv + 1 * H, ln_g + 1 * H, ln_b + 1 * H, bufA);
  // L2: h2=A; ht8=A@W2; B=bf16(A@Wres+bres); agg -> h3=C (res=B)
  k_mmr<<<MM_BLKS, 256, 0, stream>>>(bufA, whiT + 4 * H * H, b_res, bufB);
  k_mm<<<MM_BLKS, 256, 0, stream>>>(bufA, whiT + 2 * H * H, ht8);
  k_agg<<<aggg, 256, 0, stream>>>(ht8, bufB, dinv, offs, deg, csr,
                                  b_conv + 2 * H, ln_g + 2 * H, ln_b + 2 * H, bufC);
  // L3: h3=C -> ht8 -> h4=A (res=C)
  k_mm<<<MM_BLKS, 256, 0, stream>>>(bufC, whiT + 3 * H * H, ht8);
  k_agg<<<aggg, 256, 0, stream>>>(ht8, bufC, dinv, offs, deg, csr,
                                  b_conv + 3 * H, ln_g + 3 * H, ln_b + 3 * H, bufA);

  k_pool<<<512, 128, 0, stream>>>(bufA, pool);
  k_head<<<1, 256, 0, stream>>>(pool, W_fc1, b_fc1, fcn_g, fcn_b,
                                W_fc2, b_fc2, out);
}

// Round 10
// 627.107 us; speedup vs baseline: 1.9341x; 1.0048x over previous
//
#include <hip/hip_runtime.h>

constexpr int N_NODES = 100000;
constexpr int F_IN    = 32;
constexpr int H       = 128;
constexpr int OUT_F   = 200;
constexpr int NEDGES  = 1600000;
constexpr float EPS   = 1e-5f;

constexpr int HIST8_BLKS = (NEDGES / 8 + 255) / 256;  // 782
constexpr int WS_BLKS    = 80;                        // 5*128*128/1024
constexpr int EMB_BLKS   = N_NODES / 32;              // 3125 (exact)
constexpr int PRE_BLKS   = HIST8_BLKS + EMB_BLKS + WS_BLKS;  // 3987
constexpr int NPARTS     = (N_NODES + 255) / 256;     // 391
constexpr int FILL_BLKS  = (NEDGES / 4 + 255) / 256;  // 1563
constexpr int MMROW_BLKS = (N_NODES + 63) / 64;       // 1563
constexpr int MM_BLKS    = MMROW_BLKS * 2;            // 3126 (64r x 64c tiles)

typedef __attribute__((ext_vector_type(8))) short  short8;
typedef __attribute__((ext_vector_type(4))) float  f32x4;
typedef __attribute__((ext_vector_type(2))) float  fv2;

__device__ __forceinline__ void fma4(float4& a, float s, const float4& w) {
  a.x = fmaf(s, w.x, a.x); a.y = fmaf(s, w.y, a.y);
  a.z = fmaf(s, w.z, a.z); a.w = fmaf(s, w.w, a.w);
}

__device__ __forceinline__ unsigned short f2bf(float f) {  // RNE
  union { float f; unsigned u; } v; v.f = f;
  unsigned r = v.u + 0x7fffu + ((v.u >> 16) & 1u);
  return (unsigned short)(r >> 16);
}
__device__ __forceinline__ float bf2f(unsigned short s) {
  union { unsigned u; float f; } v; v.u = ((unsigned)s) << 16;
  return v.f;
}
__device__ __forceinline__ float bflo(unsigned u) { return __uint_as_float(u << 16); }
__device__ __forceinline__ float bfhi(unsigned u) { return __uint_as_float(u & 0xffff0000u); }
__device__ __forceinline__ unsigned pack2(float lo, float hi) {
  return (unsigned)f2bf(lo) | ((unsigned)f2bf(hi) << 16);
}
__device__ __forceinline__ void st_bf4(unsigned short* p, float4 v) {
  uint2 o; o.x = pack2(v.x, v.y); o.y = pack2(v.z, v.w);
  *(uint2*)p = o;
}

// ---------------- fp8 e4m3fn helpers (native cvt, manual fallback) ----------------
#if __has_builtin(__builtin_amdgcn_cvt_pk_f32_fp8) && __has_builtin(__builtin_amdgcn_cvt_pk_fp8_f32)
#define HAVE_FP8_CVT 1
#endif

#ifndef HAVE_FP8_CVT
__device__ __forceinline__ float fp8_dec1(unsigned b) {
  unsigned s = (b >> 7) & 1u, E = (b >> 3) & 15u, m = b & 7u;
  float v;
  if (E) {
    union { unsigned u; float f; } t;
    t.u = (s << 31) | ((E + 120u) << 23) | (m << 20);
    v = t.f;
  } else {
    v = (s ? -1.f : 1.f) * (float)m * 0.001953125f;  // m * 2^-9
  }
  return v;
}
#endif

template <bool HI>
__device__ __forceinline__ fv2 fp8x2(unsigned u) {
#ifdef HAVE_FP8_CVT
  return __builtin_amdgcn_cvt_pk_f32_fp8((int)u, HI);  // word_sel is ICE via template
#else
  unsigned p = HI ? (u >> 16) : u;
  fv2 r; r.x = fp8_dec1(p & 0xffu); r.y = fp8_dec1((p >> 8) & 0xffu);
  return r;
#endif
}

__device__ __forceinline__ unsigned char f32_to_fp8(float f) {
#ifdef HAVE_FP8_CVT
  return (unsigned char)(__builtin_amdgcn_cvt_pk_fp8_f32(f, f, 0, false) & 0xff);
#else
  union { float f; unsigned u; } t; t.f = f;
  unsigned s = t.u >> 31;
  float a = fabsf(f);
  if (a > 448.f) a = 448.f;
  t.f = a;
  int e = (int)((t.u >> 23) & 0xff) - 127;
  unsigned char r;
  if (a == 0.f) {
    r = 0;
  } else if (e >= -6) {
    unsigned m = t.u & 0x7fffffu;
    unsigned keep = m >> 20, rest = m & 0xfffffu;
    keep += (rest > 0x80000u) || (rest == 0x80000u && (keep & 1u));
    int E = e + 7;
    if (keep == 8u) { keep = 0u; E += 1; }
    if (E >= 16) { E = 15; keep = 6u; }
    r = (unsigned char)((E << 3) | keep);
  } else {
    int mi = (int)(a * 512.f + 0.5f);
    r = (mi > 7) ? (unsigned char)(1u << 3) : (unsigned char)mi;
  }
  return (unsigned char)(r | (s << 7));
#endif
}

// ---------------- k_pre2: hist | embed | wsplit, INTERLEAVED ----------------
// Every 5th block is a hist block so each CU holds a mix of latency-bound
// (atomic) and compute (embed) waves throughout -- co-scheduling hides the
// atomic latency (r9: hist-first layout left VALUBusy at 17%, occ 54%).
__global__ __launch_bounds__(256) void k_pre2(
    const int* __restrict__ ei, int* __restrict__ deg,
    unsigned char* __restrict__ ranks,
    const float* __restrict__ x, const float* __restrict__ W_emb,
    const float* __restrict__ b_emb, unsigned short* __restrict__ h,
    const float* __restrict__ W_conv, const float* __restrict__ W_res,
    unsigned short* __restrict__ whiT) {
  __shared__ __align__(16) float smem[F_IN * H + 32 * 36];
  int t = threadIdx.x;
  int id = blockIdx.x;
  int q = id / 5, r = id - q * 5;
  bool is_hist = (r == 0) && (q < HIST8_BLKS);
  int hcount = (r == 0) ? q : (q + 1);
  if (hcount > HIST8_BLKS) hcount = HIST8_BLKS;
  int rest = id - hcount;  // index among embed+ws blocks

  if (is_hist) {
    int i = q * 256 + t;
    if (i < NEDGES / 8) {
      int4 a = *(const int4*)(ei + NEDGES + 8 * i);
      int4 b = *(const int4*)(ei + NEDGES + 8 * i + 4);
      union { unsigned char c[8]; uint2 u; } rr;
      rr.c[0] = (unsigned char)atomicAdd(&deg[a.x], 1);
      rr.c[1] = (unsigned char)atomicAdd(&deg[a.y], 1);
      rr.c[2] = (unsigned char)atomicAdd(&deg[a.z], 1);
      rr.c[3] = (unsigned char)atomicAdd(&deg[a.w], 1);
      rr.c[4] = (unsigned char)atomicAdd(&deg[b.x], 1);
      rr.c[5] = (unsigned char)atomicAdd(&deg[b.y], 1);
      rr.c[6] = (unsigned char)atomicAdd(&deg[b.z], 1);
      rr.c[7] = (unsigned char)atomicAdd(&deg[b.w], 1);
      ((uint2*)ranks)[i] = rr.u;
    }
  } else if (rest < EMB_BLKS) {
    float* sW = smem;
    float* sX = smem + F_IN * H;
#pragma unroll
    for (int p = 0; p < 4; ++p)
      ((float4*)sW)[t + p * 256] = ((const float4*)W_emb)[t + p * 256];
    int n0 = rest * 32;
    {
      int row = t >> 3, k4 = (t & 7) * 4;
      *(float4*)(sX + row * 36 + k4) =
          *(const float4*)(x + (size_t)(n0 + row) * F_IN + k4);
    }
    __syncthreads();
    int nr = t >> 3, c = (t & 7) * 4;
    float4 a0 = make_float4(0,0,0,0), a1 = a0, a2 = a0, a3 = a0;
#pragma unroll 4
    for (int k = 0; k < F_IN; ++k) {
      float xv = sX[nr * 36 + k];
      const float* wp = sW + k * H + c;
      fma4(a0, xv, *(const float4*)(wp));
      fma4(a1, xv, *(const float4*)(wp + 32));
      fma4(a2, xv, *(const float4*)(wp + 64));
      fma4(a3, xv, *(const float4*)(wp + 96));
    }
    float4 b0 = *(const float4*)(b_emb + c);
    float4 b1 = *(const float4*)(b_emb + c + 32);
    float4 b2 = *(const float4*)(b_emb + c + 64);
    float4 b3 = *(const float4*)(b_emb + c + 96);
    a0.x += b0.x; a0.y += b0.y; a0.z += b0.z; a0.w += b0.w;
    a1.x += b1.x; a1.y += b1.y; a1.z += b1.z; a1.w += b1.w;
    a2.x += b2.x; a2.y += b2.y; a2.z += b2.z; a2.w += b2.w;
    a3.x += b3.x; a3.y += b3.y; a3.z += b3.z; a3.w += b3.w;
    unsigned short* hr = h + (size_t)(n0 + nr) * H + c;
    st_bf4(hr, a0); st_bf4(hr + 32, a1);
    st_bf4(hr + 64, a2); st_bf4(hr + 96, a3);
  } else {
    int base = (rest - EMB_BLKS) * 1024;
#pragma unroll
    for (int j = 0; j < 4; ++j) {
      int idx = base + j * 256 + t;
      if (idx < 5 * H * H) {
        int m = idx >> 14, rr2 = idx & 16383;
        int k = rr2 >> 7, n = rr2 & 127;
        const float* src = (m < 4) ? (W_conv + m * H * H) : W_res;
        whiT[m * H * H + n * H + k] = f2bf(src[k * H + n]);
      }
    }
  }
}

// ---------------- scans ----------------
__global__ void k_scan_a(const int* __restrict__ deg, int* __restrict__ offs,
                         int* __restrict__ parts, float* __restrict__ dinv) {
  __shared__ int s[256];
  int i = blockIdx.x * 256 + threadIdx.x;
  int d = (i < N_NODES) ? deg[i] : 0;
  s[threadIdx.x] = d;
  __syncthreads();
#pragma unroll
  for (int off = 1; off < 256; off <<= 1) {
    int v = (threadIdx.x >= off) ? s[threadIdx.x - off] : 0;
    __syncthreads();
    s[threadIdx.x] += v;
    __syncthreads();
  }
  if (i < N_NODES) {
    offs[i] = s[threadIdx.x] - d;
    dinv[i] = rsqrtf((float)(d + 1));  // +1 self-loop
  }
  if (threadIdx.x == 255) parts[blockIdx.x] = s[255];
}

__global__ void k_scan_b(int* __restrict__ parts, int nparts) {
  __shared__ int s[512];
  int t = threadIdx.x;
  int d = (t < nparts) ? parts[t] : 0;
  s[t] = d;
  __syncthreads();
#pragma unroll
  for (int off = 1; off < 512; off <<= 1) {
    int v = (t >= off) ? s[t - off] : 0;
    __syncthreads();
    s[t] += v;
    __syncthreads();
  }
  if (t < nparts) parts[t] = s[t] - d;
}

__global__ void k_scan_c(int* __restrict__ offs, const int* __restrict__ parts) {
  int i = blockIdx.x * 256 + threadIdx.x;
  if (i < N_NODES) offs[i] += parts[blockIdx.x];
}

// ---------------- mm core: 64r x 64c tile, wave = 32r x 32c, single-pass bf16 ----------------
struct MMAcc { f32x4 a[2][2]; };

__device__ __forceinline__ MMAcc mm_core(const unsigned short* __restrict__ A,
                                         const unsigned short* __restrict__ WhiT,
                                         int n0, int c0, int t,
                                         unsigned short* sA) {
  int wave = t >> 6, lane = t & 63;
  int wr = wave >> 1, wc = wave & 1;
  int m = lane & 15, quad = (lane >> 4) & 3;
  short8 bh[4][2];
#pragma unroll
  for (int q = 0; q < 4; ++q)
#pragma unroll
    for (int ct = 0; ct < 2; ++ct) {
      int n = c0 + wc * 32 + ct * 16 + m;
      bh[q][ct] = *(const short8*)(WhiT + n * H + q * 32 + quad * 8);
    }
#pragma unroll
  for (int p = 0; p < 4; ++p) {
    int fi = t + p * 256;
    int row = fi >> 4, c8 = (fi & 15) * 8;
    int gn = n0 + row; if (gn >= N_NODES) gn = N_NODES - 1;
    *(uint4*)(sA + row * 136 + c8) = *(const uint4*)(A + (size_t)gn * H + c8);
  }
  __syncthreads();
  MMAcc r;
#pragma unroll
  for (int i = 0; i < 2; ++i)
#pragma unroll
    for (int j = 0; j < 2; ++j) r.a[i][j] = (f32x4){0.f, 0.f, 0.f, 0.f};
#pragma unroll
  for (int q = 0; q < 4; ++q) {
    short8 ah[2];
#pragma unroll
    for (int rt = 0; rt < 2; ++rt)
      ah[rt] = *(const short8*)(sA + (wr * 32 + rt * 16 + m) * 136 + q * 32 + quad * 8);
#pragma unroll
    for (int rt = 0; rt < 2; ++rt)
#pragma unroll
      for (int ct = 0; ct < 2; ++ct)
        r.a[rt][ct] = __builtin_amdgcn_mfma_f32_16x16x32_bf16(ah[rt], bh[q][ct], r.a[rt][ct], 0, 0, 0);
  }
  return r;
}

__device__ __forceinline__ void mm_store_fp8(const MMAcc& r, unsigned char* ht8,
                                             int n0, int c0, int t) {
  int wave = t >> 6, lane = t & 63;
  int wr = wave >> 1, wc = wave & 1;
  int m = lane & 15, quad = (lane >> 4) & 3;
#pragma unroll
  for (int rt = 0; rt < 2; ++rt)
#pragma unroll
    for (int ct = 0; ct < 2; ++ct) {
      int col = c0 + wc * 32 + ct * 16 + m;
#pragma unroll
      for (int rr = 0; rr < 4; ++rr) {
        int gn = n0 + wr * 32 + rt * 16 + quad * 4 + rr;
        if (gn < N_NODES) ht8[(size_t)gn * H + col] = f32_to_fp8(r.a[rt][ct][rr]);
      }
    }
}

// ---------------- fused fill | mm_L0, INTERLEAVED 1:2 ----------------
__global__ __launch_bounds__(256) void k_fillmm(
    const int* __restrict__ ei, const unsigned char* __restrict__ ranks,
    const int* __restrict__ offs, const float* __restrict__ dinv,
    unsigned* __restrict__ csr,
    const unsigned short* __restrict__ A, const unsigned short* __restrict__ WhiT,
    unsigned char* __restrict__ ht8) {
  __shared__ __align__(16) unsigned short sA[64 * 136];
  int t = threadIdx.x;
  int id = blockIdx.x;
  int q3 = id / 3, r3 = id - q3 * 3;
  if (r3 == 0) {  // fill block (1563 of 4689, exact)
    int i = q3 * 256 + t;
    if (i < NEDGES / 4) {
      int4 s4 = *(const int4*)(ei + 4 * i);
      int4 d4 = *(const int4*)(ei + NEDGES + 4 * i);
      uchar4 r4 = ((const uchar4*)ranks)[i];
      int p0 = offs[d4.x] + r4.x;
      int p1 = offs[d4.y] + r4.y;
      int p2 = offs[d4.z] + r4.z;
      int p3 = offs[d4.w] + r4.w;
      // entry = (src<<15) | round(dinv[src]*32767)
      csr[p0] = ((unsigned)s4.x << 15) | (unsigned)(dinv[s4.x] * 32767.f + 0.5f);
      csr[p1] = ((unsigned)s4.y << 15) | (unsigned)(dinv[s4.y] * 32767.f + 0.5f);
      csr[p2] = ((unsigned)s4.z << 15) | (unsigned)(dinv[s4.z] * 32767.f + 0.5f);
      csr[p3] = ((unsigned)s4.w << 15) | (unsigned)(dinv[s4.w] * 32767.f + 0.5f);
    }
  } else {
    int j = q3 * 2 + (r3 - 1);  // mm tile index in [0, 3126)
    int n0 = (j >> 1) * 64, c0 = (j & 1) * 64;
    MMAcc r = mm_core(A, WhiT, n0, c0, t, sA);
    mm_store_fp8(r, ht8, n0, c0, t);
  }
}

__global__ __launch_bounds__(256) void k_mm(const unsigned short* __restrict__ A,
                                            const unsigned short* __restrict__ WhiT,
                                            unsigned char* __restrict__ ht8) {
  __shared__ __align__(16) unsigned short sA[64 * 136];
  int j = blockIdx.x;
  int n0 = (j >> 1) * 64, c0 = (j & 1) * 64;
  MMAcc r = mm_core(A, WhiT, n0, c0, threadIdx.x, sA);
  mm_store_fp8(r, ht8, n0, c0, threadIdx.x);
}

// residual GEMM: resb = bf16(A @ Wres + bias)
__global__ __launch_bounds__(256) void k_mmr(const unsigned short* __restrict__ A,
                                             const unsigned short* __restrict__ WhiT,
                                             const float* __restrict__ bias,
                                             unsigned short* __restrict__ resb) {
  __shared__ __align__(16) unsigned short sA[64 * 136];
  int j = blockIdx.x;
  int n0 = (j >> 1) * 64, c0 = (j & 1) * 64;
  int t = threadIdx.x;
  MMAcc r = mm_core(A, WhiT, n0, c0, t, sA);
  int wave = t >> 6, lane = t & 63;
  int wr = wave >> 1, wc = wave & 1;
  int m = lane & 15, quad = (lane >> 4) & 3;
#pragma unroll
  for (int rt = 0; rt < 2; ++rt)
#pragma unroll
    for (int ct = 0; ct < 2; ++ct) {
      int col = c0 + wc * 32 + ct * 16 + m;
      float bv = bias[col];
#pragma unroll
      for (int rr = 0; rr < 4; ++rr) {
        int gn = n0 + wr * 32 + rt * 16 + quad * 4 + rr;
        if (gn < N_NODES) resb[(size_t)gn * H + col] = f2bf(r.a[rt][ct][rr] + bv);
      }
    }
}

// ---------------- aggregate(fp8 ht) + bias + LN + relu + residual(bf16) ----------------
__global__ __launch_bounds__(256) void k_agg(
    const unsigned char* __restrict__ ht8, const unsigned short* __restrict__ res,
    const float* __restrict__ dinv, const int* __restrict__ offs,
    const int* __restrict__ deg, const unsigned* __restrict__ csr,
    const float* __restrict__ bias, const float* __restrict__ lng,
    const float* __restrict__ lnb, unsigned short* __restrict__ hout) {
  int wid = threadIdx.x >> 6, lane = threadIdx.x & 63;
  int node = blockIdx.x * 4 + wid;
  if (node >= N_NODES) return;
  int grp = lane >> 4, fl = lane & 15;
  int start = offs[node], cnt = deg[node];
  float di = dinv[node];
  const unsigned char* hb = ht8 + fl * 8;  // lane owns 8 fp8 feats
  float acc[8];
  {
    uint2 u = *(const uint2*)(hb + (size_t)node * 128);
    float sw = (grp == 0) ? di * di : 0.f;  // count self-loop once
    fv2 a = fp8x2<false>(u.x), b = fp8x2<true>(u.x);
    fv2 c = fp8x2<false>(u.y), d2 = fp8x2<true>(u.y);
    acc[0] = sw * a.x; acc[1] = sw * a.y;
    acc[2] = sw * b.x; acc[3] = sw * b.y;
    acc[4] = sw * c.x; acc[5] = sw * c.y;
    acc[6] = sw * d2.x; acc[7] = sw * d2.y;
  }
  float ddq = di * (1.f / 32767.f);
  for (int b0 = 0; b0 < cnt; b0 += 64) {
    int mm_ = min(64, cnt - b0);
    int s = 0; float w = 0.f;
    if (lane < mm_) {
      unsigned ev = csr[start + b0 + lane];
      s = (int)(ev >> 15);
      w = (float)(ev & 32767u) * ddq;
    }
#pragma unroll 2
    for (int e = 0; e < mm_; e += 4) {
      int ss = __shfl(s, e + grp, 64);
      float we = __shfl(w, e + grp, 64);
      uint2 u = *(const uint2*)(hb + (size_t)ss * 128);
      fv2 a = fp8x2<false>(u.x), b = fp8x2<true>(u.x);
      fv2 c = fp8x2<false>(u.y), d2 = fp8x2<true>(u.y);
      acc[0] = fmaf(we, a.x, acc[0]);
      acc[1] = fmaf(we, a.y, acc[1]);
      acc[2] = fmaf(we, b.x, acc[2]);
      acc[3] = fmaf(we, b.y, acc[3]);
      acc[4] = fmaf(we, c.x, acc[4]);
      acc[5] = fmaf(we, c.y, acc[5]);
      acc[6] = fmaf(we, d2.x, acc[6]);
      acc[7] = fmaf(we, d2.y, acc[7]);
    }
  }
#pragma unroll
  for (int j = 0; j < 8; ++j) {
    acc[j] += __shfl_xor(acc[j], 16, 64);
    acc[j] += __shfl_xor(acc[j], 32, 64);
  }
  float4 b0v = *(const float4*)(bias + fl * 8);
  float4 b1v = *(const float4*)(bias + fl * 8 + 4);
  acc[0] += b0v.x; acc[1] += b0v.y; acc[2] += b0v.z; acc[3] += b0v.w;
  acc[4] += b1v.x; acc[5] += b1v.y; acc[6] += b1v.z; acc[7] += b1v.w;
  float sl = ((acc[0] + acc[1]) + (acc[2] + acc[3])) +
             ((acc[4] + acc[5]) + (acc[6] + acc[7]));
#pragma unroll
  for (int mk = 1; mk <= 8; mk <<= 1) sl += __shfl_xor(sl, mk, 64);
  float mu = sl * (1.f / 128.f);
  float d[8];
  float vl = 0.f;
#pragma unroll
  for (int j = 0; j < 8; ++j) { d[j] = acc[j] - mu; vl = fmaf(d[j], d[j], vl); }
#pragma unroll
  for (int mk = 1; mk <= 8; mk <<= 1) vl += __shfl_xor(vl, mk, 64);
  float rs = rsqrtf(vl * (1.f / 128.f) + EPS);
  if (grp == 0) {
    float4 g0 = *(const float4*)(lng + fl * 8);
    float4 g1 = *(const float4*)(lng + fl * 8 + 4);
    float4 be0 = *(const float4*)(lnb + fl * 8);
    float4 be1 = *(const float4*)(lnb + fl * 8 + 4);
    uint4 rv = *(const uint4*)(res + (size_t)node * 128 + fl * 8);
    float o0 = fmaxf(fmaf(d[0] * rs, g0.x, be0.x), 0.f) + bflo(rv.x);
    float o1 = fmaxf(fmaf(d[1] * rs, g0.y, be0.y), 0.f) + bfhi(rv.x);
    float o2 = fmaxf(fmaf(d[2] * rs, g0.z, be0.z), 0.f) + bflo(rv.y);
    float o3 = fmaxf(fmaf(d[3] * rs, g0.w, be0.w), 0.f) + bfhi(rv.y);
    float o4 = fmaxf(fmaf(d[4] * rs, g1.x, be1.x), 0.f) + bflo(rv.z);
    float o5 = fmaxf(fmaf(d[5] * rs, g1.y, be1.y), 0.f) + bfhi(rv.z);
    float o6 = fmaxf(fmaf(d[6] * rs, g1.z, be1.z), 0.f) + bflo(rv.w);
    float o7 = fmaxf(fmaf(d[7] * rs, g1.w, be1.w), 0.f) + bfhi(rv.w);
    uint4 ov;
    ov.x = pack2(o0, o1); ov.y = pack2(o2, o3);
    ov.z = pack2(o4, o5); ov.w = pack2(o6, o7);
    *(uint4*)(hout + (size_t)node * 128 + fl * 8) = ov;
  }
}

// ---------------- mean pool (bf16 h) ----------------
__global__ void k_pool(const unsigned short* __restrict__ h, float* __restrict__ pool) {
  int f = threadIdx.x;  // 128
  float acc = 0.f;
  for (int n = blockIdx.x; n < N_NODES; n += gridDim.x)
    acc += bf2f(h[(size_t)n * H + f]);
  atomicAdd(&pool[f], acc);
}

// ---------------- head ----------------
__global__ void k_head(const float* __restrict__ pool, const float* __restrict__ Wfc1,
                       const float* __restrict__ bfc1, const float* __restrict__ g,
                       const float* __restrict__ bb, const float* __restrict__ Wfc2,
                       const float* __restrict__ bfc2, float* __restrict__ out) {
  __shared__ float sm[128], s1[128], stats[2];
  int t = threadIdx.x;
  if (t < 128) sm[t] = pool[t] * (1.f / (float)N_NODES);
  __syncthreads();
  if (t < 128) {
    float a = bfc1[t];
    for (int k = 0; k < 128; ++k) a = fmaf(sm[k], Wfc1[k * 128 + t], a);
    s1[t] = a;
  }
  __syncthreads();
  if (t == 0) {
    float mu = 0.f;
    for (int k = 0; k < 128; ++k) mu += s1[k];
    mu *= (1.f / 128.f);
    float var = 0.f;
    for (int k = 0; k < 128; ++k) { float d = s1[k] - mu; var += d * d; }
    var *= (1.f / 128.f);
    stats[0] = mu; stats[1] = rsqrtf(var + EPS);
  }
  __syncthreads();
  if (t < 128) s1[t] = fmaxf((s1[t] - stats[0]) * stats[1] * g[t] + bb[t], 0.f);
  __syncthreads();
  if (t < OUT_F) {
    float a = bfc2[t];
    for (int k = 0; k < 128; ++k) a = fmaf(s1[k], Wfc2[k * OUT_F + t], a);
    out[t] = a;
  }
}

extern "C" void kernel_launch(void* const* d_in, const int* in_sizes, int n_in,
                              void* d_out, int out_size, void* d_ws, size_t ws_size,
                              hipStream_t stream) {
  const float* x      = (const float*)d_in[0];
  const int*   ei     = (const int*)d_in[1];
  const float* W_emb  = (const float*)d_in[2];
  const float* b_emb  = (const float*)d_in[3];
  const float* W_conv = (const float*)d_in[4];
  const float* b_conv = (const float*)d_in[5];
  const float* ln_g   = (const float*)d_in[6];
  const float* ln_b   = (const float*)d_in[7];
  const float* W_res  = (const float*)d_in[8];
  const float* b_res  = (const float*)d_in[9];
  const float* W_fc1  = (const float*)d_in[10];
  const float* b_fc1  = (const float*)d_in[11];
  const float* fcn_g  = (const float*)d_in[12];
  const float* fcn_b  = (const float*)d_in[13];
  const float* W_fc2  = (const float*)d_in[14];
  const float* b_fc2  = (const float*)d_in[15];
  float* out = (float*)d_out;

  char* p = (char*)d_ws;
  auto take = [&](size_t bytes) {
    char* r = p; p += (bytes + 255) & ~(size_t)255; return r;
  };
  unsigned short* bufA = (unsigned short*)take((size_t)N_NODES * H * 2);
  unsigned short* bufB = (unsigned short*)take((size_t)N_NODES * H * 2);
  unsigned short* bufC = (unsigned short*)take((size_t)N_NODES * H * 2);
  unsigned char*  ht8  = (unsigned char*)take((size_t)N_NODES * H);
  unsigned short* whiT = (unsigned short*)take((size_t)5 * H * H * 2);
  int*   deg  = (int*)take(N_NODES * 4);
  int*   offs = (int*)take(N_NODES * 4);
  int*   parts= (int*)take(512 * 4);
  float* dinv = (float*)take(N_NODES * 4);
  unsigned char* ranks = (unsigned char*)take(NEDGES);
  unsigned* csr = (unsigned*)take((size_t)NEDGES * 4);
  float* pool = (float*)take(128 * 4);

  (void)hipMemsetAsync(deg, 0, N_NODES * 4, stream);
  (void)hipMemsetAsync(pool, 0, 128 * 4, stream);

  k_pre2<<<PRE_BLKS, 256, 0, stream>>>(
      ei, deg, ranks, x, W_emb, b_emb, bufA, W_conv, W_res, whiT);
  k_scan_a<<<NPARTS, 256, 0, stream>>>(deg, offs, parts, dinv);
  k_scan_b<<<1, 512, 0, stream>>>(parts, NPARTS);
  k_scan_c<<<NPARTS, 256, 0, stream>>>(offs, parts);
  k_fillmm<<<FILL_BLKS + MM_BLKS, 256, 0, stream>>>(
      ei, ranks, offs, dinv, csr, bufA, whiT + 0 * H * H, ht8);

  int aggg = (N_NODES + 3) / 4;
  // L0: res=A -> h1=C
  k_agg<<<aggg, 256, 0, stream>>>(ht8, bufA, dinv, offs, deg, csr,
                                  b_conv + 0 * H, ln_g + 0 * H, ln_b + 0 * H, bufC);
  // L1: h1=C -> ht8 -> h2=A (res=C)
  k_mm<<<MM_BLKS, 256, 0, stream>>>(bufC, whiT + 1 * H * H, ht8);
  k_agg<<<aggg, 256, 0, stream>>>(ht8, bufC, dinv, offs, deg, csr,
                                  b_conv + 1 * H, ln_g + 1 * H, ln_b + 1 * H, bufA);
  // L2: h2=A; ht8=A@W2; B=bf16(A@Wres+bres); agg -> h3=C (res=B)
  k_mmr<<<MM_BLKS, 256, 0, stream>>>(bufA, whiT + 4 * H * H, b_res, bufB);
  k_mm<<<MM_BLKS, 256, 0, stream>>>(bufA, whiT + 2 * H * H, ht8);
  k_agg<<<aggg, 256, 0, stream>>>(ht8, bufB, dinv, offs, deg, csr,
                                  b_conv + 2 * H, ln_g + 2 * H, ln_b + 2 * H, bufC);
  // L3: h3=C -> ht8 -> h4=A (res=C)
  k_mm<<<MM_BLKS, 256, 0, stream>>>(bufC, whiT + 3 * H * H, ht8);
  k_agg<<<aggg, 256, 0, stream>>>(ht8, bufC, dinv, offs, deg, csr,
                                  b_conv + 3 * H, ln_g + 3 * H, ln_b + 3 * H, bufA);

  k_pool<<<512, 128, 0, stream>>>(bufA, pool);
  k_head<<<1, 256, 0, stream>>>(pool, W_fc1, b_fc1, fcn_g, fcn_b,
                                W_fc2, b_fc2, out);
}